// Round 3
// baseline (831.826 us; speedup 1.0000x reference)
//
#include <hip/hip_runtime.h>
#include <math.h>

#define DIM   1024
#define NTOK  4096
#define TSEQ  1024
#define NHEAD 16
#define MPROT 256
#define EPSR  1.1920929e-07f
#define SA    64.0f
#define SW    256.0f
#define SPC   64.0f

typedef __attribute__((ext_vector_type(8))) short          short8;
typedef __attribute__((ext_vector_type(8))) _Float16       half8;
typedef __attribute__((ext_vector_type(4))) _Float16       half4;
typedef __attribute__((ext_vector_type(4))) float          f32x4;
typedef __attribute__((ext_vector_type(4))) unsigned short us4;

static __device__ __forceinline__ float bf2f(unsigned short s) {
  union { unsigned int u; float f; } c; c.u = ((unsigned int)s) << 16; return c.f;
}
static __device__ __forceinline__ unsigned short f2bf(float f) {
  union { float f; unsigned int u; } c; c.f = f;
  return (unsigned short)((c.u + 0x7fffu + ((c.u >> 16) & 1u)) >> 16);
}
static __device__ __forceinline__ void gload16(void* lds, const void* g) {
  __builtin_amdgcn_global_load_lds(
      (__attribute__((address_space(1))) void*)const_cast<void*>(g),
      (__attribute__((address_space(3))) void*)lds, 16, 0, 0);
}

// ---------------- conversions ----------------
// 4 attention weights split-converted in one launch into [4][1M] half planes
__global__ __launch_bounds__(256) void cvt_attn4_k(const float* __restrict__ wq,
                                                   const float* __restrict__ wk,
                                                   const float* __restrict__ wv,
                                                   const float* __restrict__ wo,
                                                   _Float16* __restrict__ dh,
                                                   _Float16* __restrict__ dl) {
  const int wi = blockIdx.y;
  const float* s = (wi == 0) ? wq : (wi == 1) ? wk : (wi == 2) ? wv : wo;
  const int i = blockIdx.x * 256 + threadIdx.x;
  const size_t off4 = ((size_t)wi << 20) >> 2;
  const float4 v = ((const float4*)s)[i];
  float a0 = v.x * SW, a1 = v.y * SW, a2 = v.z * SW, a3 = v.w * SW;
  half4 hv, lv;
  _Float16 h0 = (_Float16)a0; hv[0] = h0; lv[0] = (_Float16)(a0 - (float)h0);
  _Float16 h1 = (_Float16)a1; hv[1] = h1; lv[1] = (_Float16)(a1 - (float)h1);
  _Float16 h2 = (_Float16)a2; hv[2] = h2; lv[2] = (_Float16)(a2 - (float)h2);
  _Float16 h3 = (_Float16)a3; hv[3] = h3; lv[3] = (_Float16)(a3 - (float)h3);
  ((half4*)dh)[off4 + i] = hv; ((half4*)dl)[off4 + i] = lv;
}

// all 12 MoE weights -> bf16, one launch
__global__ __launch_bounds__(256) void cvt_moe_all_k(
    const float* s0, const float* s1, const float* s2, const float* s3,
    const float* s4, const float* s5, const float* s6, const float* s7,
    const float* s8, const float* s9, const float* s10, const float* s11,
    unsigned short* __restrict__ dst) {
  const int n4tab[12] = {524288, 524288, 524288, 524288, 524288, 524288,
                         1048576, 1048576, 524288, 262144, 524288, 524288};
  const size_t offtab[12] = {0, 2097152, 4194304, 6291456, 8388608, 10485760,
                             12582912, 16777216, 20971520, 23068672, 24117248, 26214400};
  const int wi = blockIdx.y;
  const int i = blockIdx.x * 256 + threadIdx.x;
  if (i >= n4tab[wi]) return;
  const float* s;
  switch (wi) {
    case 0: s = s0; break; case 1: s = s1; break; case 2: s = s2; break;
    case 3: s = s3; break; case 4: s = s4; break; case 5: s = s5; break;
    case 6: s = s6; break; case 7: s = s7; break; case 8: s = s8; break;
    case 9: s = s9; break; case 10: s = s10; break; default: s = s11; break;
  }
  const float4 v = ((const float4*)s)[i];
  us4 o; o[0] = f2bf(v.x); o[1] = f2bf(v.y); o[2] = f2bf(v.z); o[3] = f2bf(v.w);
  ((us4*)(dst + offtab[wi]))[i] = o;
}

// ---------------- RMS norms ----------------
__global__ __launch_bounds__(256) void rms_split_k(const float* __restrict__ in,
                                                   const float* __restrict__ wgt,
                                                   _Float16* __restrict__ oh,
                                                   _Float16* __restrict__ ol) {
  const int row = blockIdx.x, tid = threadIdx.x;
  const float4 v = ((const float4*)(in + (size_t)row * DIM))[tid];
  float ss = v.x * v.x + v.y * v.y + v.z * v.z + v.w * v.w;
#pragma unroll
  for (int o = 32; o; o >>= 1) ss += __shfl_xor(ss, o);
  __shared__ float red[4];
  if ((tid & 63) == 0) red[tid >> 6] = ss;
  __syncthreads();
  const float sc = rsqrtf((red[0] + red[1] + red[2] + red[3]) * (1.0f / DIM) + EPSR) * SA;
  const float4 wv = ((const float4*)wgt)[tid];
  float a[4] = {v.x * sc * wv.x, v.y * sc * wv.y, v.z * sc * wv.z, v.w * sc * wv.w};
  half4 hv, lv;
#pragma unroll
  for (int j = 0; j < 4; ++j) {
    _Float16 hh = (_Float16)a[j]; hv[j] = hh; lv[j] = (_Float16)(a[j] - (float)hh);
  }
  ((half4*)(oh + (size_t)row * DIM))[tid] = hv;
  ((half4*)(ol + (size_t)row * DIM))[tid] = lv;
}

// fused RMSNorm(bf16 out) + gate logits/softmax/top-2 + moe buffer zeroing
__global__ __launch_bounds__(256) void rmsgate_k(const float* __restrict__ x2,
                                                 const float* __restrict__ n2w,
                                                 const float* __restrict__ gw,
                                                 unsigned short* __restrict__ xfb,
                                                 float* __restrict__ wts,
                                                 float* __restrict__ moe) {
  const int row = blockIdx.x, tid = threadIdx.x;
  ((float4*)(moe + (size_t)row * DIM))[tid] = (float4){0.f, 0.f, 0.f, 0.f};
  const float4 v = ((const float4*)(x2 + (size_t)row * DIM))[tid];
  float ss = v.x * v.x + v.y * v.y + v.z * v.z + v.w * v.w;
#pragma unroll
  for (int o = 32; o; o >>= 1) ss += __shfl_xor(ss, o);
  __shared__ float red[4];
  __shared__ float redE[4][4];
  const int w = tid >> 6, lane = tid & 63;
  if (lane == 0) red[w] = ss;
  __syncthreads();
  const float sc = rsqrtf((red[0] + red[1] + red[2] + red[3]) * (1.0f / DIM) + EPSR);
  const float4 nw = ((const float4*)n2w)[tid];
  const float xn0 = v.x * sc * nw.x, xn1 = v.y * sc * nw.y;
  const float xn2 = v.z * sc * nw.z, xn3 = v.w * sc * nw.w;
  us4 ob; ob[0] = f2bf(xn0); ob[1] = f2bf(xn1); ob[2] = f2bf(xn2); ob[3] = f2bf(xn3);
  ((us4*)(xfb + (size_t)row * DIM))[tid] = ob;
#pragma unroll
  for (int e = 0; e < 4; ++e) {
    const float4 g = ((const float4*)(gw + (size_t)e * DIM))[tid];
    float d = xn0 * g.x + xn1 * g.y + xn2 * g.z + xn3 * g.w;
#pragma unroll
    for (int o = 32; o; o >>= 1) d += __shfl_xor(d, o);
    if (lane == 0) redE[w][e] = d;
  }
  __syncthreads();
  if (tid == 0) {
    float lg[4];
#pragma unroll
    for (int e = 0; e < 4; ++e) lg[e] = redE[0][e] + redE[1][e] + redE[2][e] + redE[3][e];
    const float mx = fmaxf(fmaxf(lg[0], lg[1]), fmaxf(lg[2], lg[3]));
    float pe[4]; float sum = 0.0f;
#pragma unroll
    for (int e = 0; e < 4; ++e) { pe[e] = __expf(lg[e] - mx); sum += pe[e]; }
#pragma unroll
    for (int e = 0; e < 4; ++e) pe[e] /= sum;
    int i1 = 0;
    for (int e = 1; e < 4; ++e) if (pe[e] > pe[i1]) i1 = e;
    int i2 = -1;
    for (int e = 0; e < 4; ++e) { if (e == i1) continue; if (i2 < 0 || pe[e] > pe[i2]) i2 = e; }
    const float s2 = pe[i1] + pe[i2] + 1e-8f;
    float o[4] = {0.f, 0.f, 0.f, 0.f};
    o[i1] = pe[i1] / s2; o[i2] = pe[i2] / s2;
    float4 r; r.x = o[0]; r.y = o[1]; r.z = o[2]; r.w = o[3];
    *(float4*)(wts + (size_t)row * 4) = r;
  }
}

// per (token,head) RMS over 64 dims; y=0 -> Q planes, y=1 -> K planes
__global__ __launch_bounds__(256) void qknorm2_k(_Float16* __restrict__ qh,
                                                 _Float16* __restrict__ ql,
                                                 _Float16* __restrict__ kh,
                                                 _Float16* __restrict__ kl,
                                                 const float* __restrict__ qnw,
                                                 const float* __restrict__ knw) {
  _Float16* ph; _Float16* pl; const float* wgt;
  if (blockIdx.y == 0) { ph = qh; pl = ql; wgt = qnw; }
  else { ph = kh; pl = kl; wgt = knw; }
  const int idx = (blockIdx.x << 2) + (threadIdx.x >> 6);
  const int lane = threadIdx.x & 63;
  const size_t off = ((size_t)idx << 6) + lane;
  const float v = (float)ph[off] + (float)pl[off];
  float ss = v * v;
#pragma unroll
  for (int o = 32; o; o >>= 1) ss += __shfl_xor(ss, o);
  const float sc = rsqrtf(ss * (1.0f / (64.0f * SA * SA)) + EPSR);
  const float nv = v * sc * wgt[lane];
  _Float16 hh = (_Float16)nv;
  ph[off] = hh; pl[off] = (_Float16)(nv - (float)hh);
}

// ---------------- deterministic order-preserving per-expert compaction ----------------
__global__ __launch_bounds__(256) void route_k(const float* __restrict__ wts,
                                               int* __restrict__ idxE,
                                               int* __restrict__ cnts) {
  const int e = blockIdx.x;
  const int tid = threadIdx.x, w = tid >> 6, lane = tid & 63;
  __shared__ int wsum[4];
  __shared__ int baseS;
  if (tid == 0) baseS = 0;
  __syncthreads();
  for (int c = 0; c < 16; ++c) {
    const int tok = (c << 8) + tid;
    const bool pred = wts[(size_t)tok * 4 + e] > 0.0f;
    const unsigned long long m = __ballot(pred);
    const int lanepre = __popcll(m & ((1ull << lane) - 1ull));
    if (lane == 0) wsum[w] = __popcll(m);
    __syncthreads();
    int wpre = 0;
#pragma unroll
    for (int i = 0; i < 4; ++i) wpre += (i < w) ? wsum[i] : 0;
    const int tot = wsum[0] + wsum[1] + wsum[2] + wsum[3];
    if (pred) idxE[(e << 12) + baseS + wpre + lanepre] = tok;
    __syncthreads();
    if (tid == 0) baseS += tot;
    __syncthreads();
  }
  const int cnt = baseS;
  if (tid == 0) cnts[e] = cnt;
  for (int j = cnt + tid; j < 4096; j += 256) idxE[(e << 12) + j] = 0;
}

// ---------------- bf16 GEMM: out = epilogue(A[M,K] @ W[F,K]^T), sparse rows ----------------
// ACT: 0=none 1=gelu
// EP: 0=store bf16, 1=silu(v)*other->bf16, 2=scatter moe[tok] += wt*v
// GATH: 1 = A rows gathered via gidx during staging
template <int ACT, int EP, int GATH>
__global__ __launch_bounds__(256, 2) void gemm_bf16_k(
    const unsigned short* __restrict__ A, const unsigned short* __restrict__ Bw,
    int K, int F,
    unsigned short* __restrict__ outb, const unsigned short* __restrict__ other,
    float* __restrict__ outf, const float* __restrict__ wts, int expert,
    const int* __restrict__ gidx, const int* __restrict__ cntp) {
  __shared__ unsigned short As[2][128][64];
  __shared__ unsigned short Bs[2][128][64];
  const int tid = threadIdx.x;
  const int w = tid >> 6, lane = tid & 63;
  const int wr = ((w >> 1) << 6), wc = ((w & 1) << 6);
  // bijective XCD-chunked swizzle (tot % 8 == 0 for all our grids)
  int nlin = blockIdx.y * gridDim.x + blockIdx.x;
  const int tot = gridDim.x * gridDim.y;
  nlin = (nlin & 7) * (tot >> 3) + (nlin >> 3);
  const int mb = nlin / gridDim.x;
  const int m0 = mb << 7, n0 = (nlin - mb * gridDim.x) << 7;
  const int cnt = cntp ? cntp[expert] : (1 << 30);
  if (m0 >= cnt) return;
  const int rr = lane & 15, kgl = lane >> 4;
  const int srow = tid >> 3, sslot = tid & 7;

  int grow[4];
#pragma unroll
  for (int i = 0; i < 4; ++i) {
    const int r = (i << 5) + srow;
    grow[i] = GATH ? gidx[m0 + r] : (m0 + r);
  }

  f32x4 acc[4][4];
#pragma unroll
  for (int a_ = 0; a_ < 4; ++a_)
#pragma unroll
    for (int b_ = 0; b_ < 4; ++b_) acc[a_][b_] = (f32x4){0.f, 0.f, 0.f, 0.f};

  const int KT = K >> 6;
  auto stage = [&](int buf, int kt) {
    const int k0 = kt << 6;
#pragma unroll
    for (int i = 0; i < 4; ++i) {
      const int r = (i << 5) + srow;
      const int ls = sslot ^ (r & 7);
      gload16(&As[buf][(i << 5) + (w << 3)][0], A + (size_t)grow[i] * K + k0 + (ls << 3));
      gload16(&Bs[buf][(i << 5) + (w << 3)][0], Bw + (size_t)(n0 + r) * K + k0 + (ls << 3));
    }
  };
  stage(0, 0);
  __syncthreads();
  for (int kt = 0; kt < KT; ++kt) {
    const int cur = kt & 1;
    if (kt + 1 < KT) stage(cur ^ 1, kt + 1);
    short8 af[4][2], bfr[4][2];
#pragma unroll
    for (int f = 0; f < 4; ++f) {
#pragma unroll
      for (int ks = 0; ks < 2; ++ks) {
        const int row = wr + (f << 4) + rr;
        const int kg = (ks << 2) + kgl;
        af[f][ks] = *(const short8*)&As[cur][row][(kg ^ (row & 7)) << 3];
        const int col = wc + (f << 4) + rr;
        bfr[f][ks] = *(const short8*)&Bs[cur][col][(kg ^ (col & 7)) << 3];
      }
    }
#pragma unroll
    for (int fi = 0; fi < 4; ++fi)
#pragma unroll
      for (int fj = 0; fj < 4; ++fj)
#pragma unroll
        for (int ks = 0; ks < 2; ++ks)
          acc[fi][fj] = __builtin_amdgcn_mfma_f32_16x16x32_bf16(
              af[fi][ks], bfr[fj][ks], acc[fi][fj], 0, 0, 0);
    __syncthreads();
  }
#pragma unroll
  for (int fi = 0; fi < 4; ++fi)
#pragma unroll
    for (int fj = 0; fj < 4; ++fj) {
      const int col = n0 + wc + (fj << 4) + rr;
#pragma unroll
      for (int r = 0; r < 4; ++r) {
        const int row = m0 + wr + (fi << 4) + (kgl << 2) + r;
        if (row >= cnt) continue;
        float v = acc[fi][fj][r];
        if (ACT == 1) v = 0.5f * v * (1.0f + erff(v * 0.70710678118654752f));
        if (EP == 0) {
          outb[(size_t)row * F + col] = f2bf(v);
        } else if (EP == 1) {
          const size_t off = (size_t)row * F + col;
          const float sv = v / (1.0f + __expf(-v));
          outb[off] = f2bf(sv * bf2f(other[off]));
        } else {
          const int tok = gidx[row];
          outf[(size_t)tok * DIM + col] += wts[(size_t)tok * 4 + expert] * v;
        }
      }
    }
}

// ---------------- fp16x2 split GEMM (3-term) ----------------
// EP: 1 = fp32: resid + masked(v); 3 = fused QKV epilogue (q/k planes + V^T planes)
template <int EP>
__global__ __launch_bounds__(256, 2) void gemm_split_k(
    const _Float16* __restrict__ Ah, const _Float16* __restrict__ Al,
    const _Float16* __restrict__ Bh, const _Float16* __restrict__ Bl,
    int K, int F,
    _Float16* __restrict__ Oh, _Float16* __restrict__ Ol, float oscale,
    const float* __restrict__ resid, float* __restrict__ outf,
    _Float16* __restrict__ K2h, _Float16* __restrict__ K2l,
    _Float16* __restrict__ V2h, _Float16* __restrict__ V2l) {
  __shared__ _Float16 AsH[2][128][32], AsL[2][128][32];
  __shared__ _Float16 BsH[2][128][32], BsL[2][128][32];
  const int tid = threadIdx.x;
  const int w = tid >> 6, lane = tid & 63;
  const int wr = ((w >> 1) << 6), wc = ((w & 1) << 6);
  int nlin = blockIdx.y * gridDim.x + blockIdx.x;
  const int tot = gridDim.x * gridDim.y;
  nlin = (nlin & 7) * (tot >> 3) + (nlin >> 3);
  const int mb = nlin / gridDim.x;
  const int m0 = mb << 7, n0 = (nlin - mb * gridDim.x) << 7;
  const int rr = lane & 15, kgl = lane >> 4;
  const int srow = tid >> 2, sslot = tid & 3;

  f32x4 acc[4][4];
#pragma unroll
  for (int a_ = 0; a_ < 4; ++a_)
#pragma unroll
    for (int b_ = 0; b_ < 4; ++b_) acc[a_][b_] = (f32x4){0.f, 0.f, 0.f, 0.f};

  const int KT = K >> 5;
  auto stage = [&](int buf, int kt) {
    const int k0 = kt << 5;
#pragma unroll
    for (int i = 0; i < 2; ++i) {
      const int r = (i << 6) + srow;
      const int ls = sslot ^ ((r >> 1) & 3);
      const size_t ga = (size_t)(m0 + r) * K + k0 + (ls << 3);
      const size_t gb = (size_t)(n0 + r) * K + k0 + (ls << 3);
      const int lr = (i << 6) + (w << 4);
      gload16(&AsH[buf][lr][0], Ah + ga);
      gload16(&AsL[buf][lr][0], Al + ga);
      gload16(&BsH[buf][lr][0], Bh + gb);
      gload16(&BsL[buf][lr][0], Bl + gb);
    }
  };
  stage(0, 0);
  __syncthreads();
  for (int kt = 0; kt < KT; ++kt) {
    const int cur = kt & 1;
    if (kt + 1 < KT) stage(cur ^ 1, kt + 1);
    half8 ah[4], al[4], bh[4], bl[4];
#pragma unroll
    for (int f = 0; f < 4; ++f) {
      const int row = wr + (f << 4) + rr;
      const int pa = (kgl ^ ((row >> 1) & 3)) << 3;
      ah[f] = *(const half8*)&AsH[cur][row][pa];
      al[f] = *(const half8*)&AsL[cur][row][pa];
      const int col = wc + (f << 4) + rr;
      const int pb = (kgl ^ ((col >> 1) & 3)) << 3;
      bh[f] = *(const half8*)&BsH[cur][col][pb];
      bl[f] = *(const half8*)&BsL[cur][col][pb];
    }
#pragma unroll
    for (int fi = 0; fi < 4; ++fi)
#pragma unroll
      for (int fj = 0; fj < 4; ++fj) {
        acc[fi][fj] = __builtin_amdgcn_mfma_f32_16x16x32_f16(ah[fi], bh[fj], acc[fi][fj], 0, 0, 0);
        acc[fi][fj] = __builtin_amdgcn_mfma_f32_16x16x32_f16(ah[fi], bl[fj], acc[fi][fj], 0, 0, 0);
        acc[fi][fj] = __builtin_amdgcn_mfma_f32_16x16x32_f16(al[fi], bh[fj], acc[fi][fj], 0, 0, 0);
      }
    __syncthreads();
  }
#pragma unroll
  for (int fi = 0; fi < 4; ++fi)
#pragma unroll
    for (int fj = 0; fj < 4; ++fj) {
      const int col = n0 + wc + (fj << 4) + rr;
      const int rowb = m0 + wr + (fi << 4) + (kgl << 2);
      if (EP == 3) {
        if (col < 2048) {
          _Float16* ph = (col < 1024) ? Oh : K2h;
          _Float16* pl = (col < 1024) ? Ol : K2l;
          const int c = col & 1023;
#pragma unroll
          for (int r = 0; r < 4; ++r) {
            const float v = acc[fi][fj][r] * oscale;
            const _Float16 hh2 = (_Float16)v;
            const size_t off = (size_t)(rowb + r) * DIM + c;
            ph[off] = hh2; pl[off] = (_Float16)(v - (float)hh2);
          }
        } else {
          const int c2 = col - 2048;
          half4 h4, l4;
#pragma unroll
          for (int r = 0; r < 4; ++r) {
            const float v = acc[fi][fj][r] * oscale;
            const _Float16 hh2 = (_Float16)v;
            h4[r] = hh2; l4[r] = (_Float16)(v - (float)hh2);
          }
          const size_t vt = ((size_t)((rowb >> 10) << 4) + (size_t)(c2 >> 6)) * 65536 +
                            (size_t)(c2 & 63) * 1024 + (size_t)(rowb & 1023);
          *(half4*)&V2h[vt] = h4;
          *(half4*)&V2l[vt] = l4;
        }
      } else {
#pragma unroll
        for (int r = 0; r < 4; ++r) {
          const size_t off = (size_t)(rowb + r) * F + col;
          const float v = acc[fi][fj][r] * oscale;
          outf[off] = resid[off] + (col >= MPROT ? v : 0.0f);
        }
      }
    }
}

// ---------------- flash attention, causal, fp16x2 split, swapped-QK ----------------
__global__ __launch_bounds__(256, 2) void attn_k(
    const _Float16* __restrict__ Qh, const _Float16* __restrict__ Ql,
    const _Float16* __restrict__ Kh, const _Float16* __restrict__ Kl,
    const _Float16* __restrict__ Vth, const _Float16* __restrict__ Vtl,
    _Float16* __restrict__ Oh, _Float16* __restrict__ Ol) {
  __shared__ _Float16 Ksh[2][32][64], Ksl[2][32][64];
  __shared__ _Float16 Vsh[2][64][40], Vsl[2][64][40];
  __shared__ _Float16 Plh[4][16][40], Pll[4][16][40];
  const int n = blockIdx.x;
  const int qt = n >> 6;
  const int bh = ((n & 7) << 3) | ((n >> 3) & 7);
  const int b = bh >> 4, h = bh & 15;
  const int tid = threadIdx.x, w = tid >> 6, lane = tid & 63;
  const int rr = lane & 15, rg = lane >> 4;
  const size_t tokbase = (size_t)b * TSEQ;
  const int hcol = h << 6;
  const size_t vtbase = (size_t)bh << 16;
  const int q0w = (qt << 7) + (w << 5);
  const float sscale = 0.125f / (SA * SA);

  half8 qfh[2][2], qfl[2][2];
#pragma unroll
  for (int qf = 0; qf < 2; ++qf)
#pragma unroll
    for (int ks = 0; ks < 2; ++ks) {
      const size_t off = (tokbase + q0w + (qf << 4) + rr) * DIM + hcol + (ks << 5) + (rg << 3);
      qfh[qf][ks] = *(const half8*)&Qh[off];
      qfl[qf][ks] = *(const half8*)&Ql[off];
    }

  f32x4 oacc[2][4];
#pragma unroll
  for (int qf = 0; qf < 2; ++qf)
#pragma unroll
    for (int dg = 0; dg < 4; ++dg) oacc[qf][dg] = (f32x4){0.f, 0.f, 0.f, 0.f};
  float mreg[2] = {-INFINITY, -INFINITY}, lreg[2] = {0.f, 0.f};

  const int kr = (w << 3) + (lane >> 3);
  const int kswz = ((lane & 7) ^ (kr & 7)) << 3;
  const int vr = tid >> 2;
  const int vs = (tid & 3) << 3;

  const int ntiles = (qt + 1) << 2;

  {
    gload16(&Ksh[0][w << 3][0], &Kh[(tokbase + kr) * DIM + hcol + kswz]);
    gload16(&Ksl[0][w << 3][0], &Kl[(tokbase + kr) * DIM + hcol + kswz]);
    const half8 vvh = *(const half8*)&Vth[vtbase + (size_t)vr * TSEQ + vs];
    const half8 vvl = *(const half8*)&Vtl[vtbase + (size_t)vr * TSEQ + vs];
    *(half8*)&Vsh[0][vr][vs] = vvh;
    *(half8*)&Vsl[0][vr][vs] = vvl;
    __syncthreads();
  }

  for (int t = 0; t < ntiles; ++t) {
    const int cur = t & 1;
    const int kv0 = t << 5;
    const bool havenext = (t + 1 < ntiles);
    half8 nvh, nvl;
    if (havenext) {
      const int kn = kv0 + 32;
      gload16(&Ksh[cur ^ 1][w << 3][0], &Kh[(tokbase + kn + kr) * DIM + hcol + kswz]);
      gload16(&Ksl[cur ^ 1][w << 3][0], &Kl[(tokbase + kn + kr) * DIM + hcol + kswz]);
      nvh = *(const half8*)&Vth[vtbase + (size_t)vr * TSEQ + kn + vs];
      nvl = *(const half8*)&Vtl[vtbase + (size_t)vr * TSEQ + kn + vs];
    }
    if (kv0 <= q0w + 31) {
      half8 kfh[2][2], kfl[2][2];
#pragma unroll
      for (int kt = 0; kt < 2; ++kt)
#pragma unroll
        for (int ks = 0; ks < 2; ++ks) {
          const int row = (kt << 4) + rr;
          const int sw = ((((ks << 2) + rg)) ^ (row & 7)) << 3;
          kfh[kt][ks] = *(const half8*)&Ksh[cur][row][sw];
          kfl[kt][ks] = *(const half8*)&Ksl[cur][row][sw];
        }
#pragma unroll
      for (int qf = 0; qf < 2; ++qf) {
        if (kv0 > q0w + (qf << 4) + 15) continue;
        f32x4 st[2];
        st[0] = (f32x4){0.f, 0.f, 0.f, 0.f};
        st[1] = (f32x4){0.f, 0.f, 0.f, 0.f};
#pragma unroll
        for (int kt = 0; kt < 2; ++kt)
#pragma unroll
          for (int ks = 0; ks < 2; ++ks) {
            st[kt] = __builtin_amdgcn_mfma_f32_16x16x32_f16(kfh[kt][ks], qfh[qf][ks], st[kt], 0, 0, 0);
            st[kt] = __builtin_amdgcn_mfma_f32_16x16x32_f16(kfh[kt][ks], qfl[qf][ks], st[kt], 0, 0, 0);
            st[kt] = __builtin_amdgcn_mfma_f32_16x16x32_f16(kfl[kt][ks], qfh[qf][ks], st[kt], 0, 0, 0);
          }
        const int qg = q0w + (qf << 4) + rr;
        float s[2][4]; float mx = -INFINITY;
#pragma unroll
        for (int kt = 0; kt < 2; ++kt)
#pragma unroll
          for (int r = 0; r < 4; ++r) {
            float sv = st[kt][r] * sscale;
            if (kv0 + (kt << 4) + (rg << 2) + r > qg) sv = -INFINITY;
            s[kt][r] = sv; mx = fmaxf(mx, sv);
          }
        mx = fmaxf(mx, __shfl_xor(mx, 16));
        mx = fmaxf(mx, __shfl_xor(mx, 32));
        const float mn = fmaxf(mreg[qf], mx);
        const float al = __expf(mreg[qf] - mn);
        mreg[qf] = mn;
        float p[2][4]; float rs = 0.f;
#pragma unroll
        for (int kt = 0; kt < 2; ++kt)
#pragma unroll
          for (int r = 0; r < 4; ++r) { p[kt][r] = __expf(s[kt][r] - mn); rs += p[kt][r]; }
        rs += __shfl_xor(rs, 16);
        rs += __shfl_xor(rs, 32);
        lreg[qf] = lreg[qf] * al + rs;
#pragma unroll
        for (int kt = 0; kt < 2; ++kt) {
          half4 h4, l4;
#pragma unroll
          for (int r = 0; r < 4; ++r) {
            const float pv = p[kt][r] * SPC;
            const _Float16 ph = (_Float16)pv;
            h4[r] = ph; l4[r] = (_Float16)(pv - (float)ph);
          }
          *(half4*)&Plh[w][rr][(kt << 4) + (rg << 2)] = h4;
          *(half4*)&Pll[w][rr][(kt << 4) + (rg << 2)] = l4;
        }
        float alr[4];
#pragma unroll
        for (int r = 0; r < 4; ++r) alr[r] = __shfl(al, (lane & 48) | ((rg << 2) + r));
#pragma unroll
        for (int dg = 0; dg < 4; ++dg)
#pragma unroll
          for (int r = 0; r < 4; ++r) oacc[qf][dg][r] *= alr[r];
        const half8 pah = *(const half8*)&Plh[w][rr][rg << 3];
        const half8 pal = *(const half8*)&Pll[w][rr][rg << 3];
#pragma unroll
        for (int dg = 0; dg < 4; ++dg) {
          const half8 vfh2 = *(const half8*)&Vsh[cur][(dg << 4) + rr][rg << 3];
          const half8 vfl2 = *(const half8*)&Vsl[cur][(dg << 4) + rr][rg << 3];
          oacc[qf][dg] = __builtin_amdgcn_mfma_f32_16x16x32_f16(pah, vfh2, oacc[qf][dg], 0, 0, 0);
          oacc[qf][dg] = __builtin_amdgcn_mfma_f32_16x16x32_f16(pah, vfl2, oacc[qf][dg], 0, 0, 0);
          oacc[qf][dg] = __builtin_amdgcn_mfma_f32_16x16x32_f16(pal, vfh2, oacc[qf][dg], 0, 0, 0);
        }
      }
    }
    if (havenext) {
      *(half8*)&Vsh[cur ^ 1][vr][vs] = nvh;
      *(half8*)&Vsl[cur ^ 1][vr][vs] = nvl;
    }
    __syncthreads();
  }
#pragma unroll
  for (int qf = 0; qf < 2; ++qf) {
    float li[4];
#pragma unroll
    for (int r = 0; r < 4; ++r)
      li[r] = __shfl(lreg[qf], (lane & 48) | ((rg << 2) + r));
#pragma unroll
    for (int dg = 0; dg < 4; ++dg)
#pragma unroll
      for (int r = 0; r < 4; ++r) {
        const int qloc = (rg << 2) + r;
        const float ov = oacc[qf][dg][r] / (li[r] * SPC);
        const _Float16 hh2 = (_Float16)ov;
        const size_t off = (tokbase + q0w + (qf << 4) + qloc) * DIM + hcol + (dg << 4) + rr;
        Oh[off] = hh2;
        Ol[off] = (_Float16)(ov - (float)hh2);
      }
  }
}

// ---------------- final combine: outp += mask(moe) ----------------
__global__ __launch_bounds__(256) void comb_k(float* __restrict__ outp,
                                              const float* __restrict__ moe) {
  const size_t i = (size_t)blockIdx.x * 256 + threadIdx.x;
  const int c4 = (int)(i & 255);
  if (c4 >= 64) {
    float4 o = ((float4*)outp)[i];
    const float4 m = ((const float4*)moe)[i];
    o.x += m.x; o.y += m.y; o.z += m.z; o.w += m.w;
    ((float4*)outp)[i] = o;
  }
}

extern "C" void kernel_launch(void* const* d_in, const int* in_sizes, int n_in,
                              void* d_out, int out_size, void* d_ws, size_t ws_size,
                              hipStream_t stream) {
  (void)in_sizes; (void)n_in; (void)out_size; (void)ws_size;
  const float* x    = (const float*)d_in[0];
  const float* n1w  = (const float*)d_in[1];
  const float* n2w  = (const float*)d_in[2];
  const float* wq   = (const float*)d_in[3];
  const float* wk   = (const float*)d_in[4];
  const float* wv   = (const float*)d_in[5];
  const float* wo   = (const float*)d_in[6];
  const float* qnw  = (const float*)d_in[7];
  const float* knw  = (const float*)d_in[8];
  const float* gw   = (const float*)d_in[9];
  const float* moesrc[12] = {
    (const float*)d_in[10], (const float*)d_in[11],
    (const float*)d_in[12], (const float*)d_in[13], (const float*)d_in[14],
    (const float*)d_in[15], (const float*)d_in[16], (const float*)d_in[17], (const float*)d_in[18],
    (const float*)d_in[19], (const float*)d_in[20], (const float*)d_in[21]
  };
  float* outp = (float*)d_out;

  char* p = (char*)d_ws;
  auto alloc = [&](size_t bytes) { void* r = (void*)p; p += (bytes + 255) & ~(size_t)255; return r; };
  const size_t NC = (size_t)NTOK * DIM;
  const size_t NH2 = (size_t)NTOK * 2048;
  _Float16* hh = (_Float16*)alloc(NC * 2);
  _Float16* hl = (_Float16*)alloc(NC * 2);
  _Float16* qh = (_Float16*)alloc(NC * 2);
  _Float16* ql = (_Float16*)alloc(NC * 2);
  _Float16* kh = (_Float16*)alloc(NC * 2);
  _Float16* kl = (_Float16*)alloc(NC * 2);
  _Float16* vth = (_Float16*)alloc(NC * 2);
  _Float16* vtl = (_Float16*)alloc(NC * 2);
  unsigned short* xfb = (unsigned short*)alloc(NC * 2);
  unsigned short* t0  = (unsigned short*)alloc(NH2 * 2);
  unsigned short* t1  = (unsigned short*)alloc(NH2 * 2);
  float* moe = (float*)alloc(NC * 4);
  float* wts = (float*)alloc((size_t)NTOK * 4 * 4);
  _Float16* awh = (_Float16*)alloc((size_t)4 * 1024 * 1024 * 2);
  _Float16* awl = (_Float16*)alloc((size_t)4 * 1024 * 1024 * 2);
  unsigned short* moeW = (unsigned short*)alloc((size_t)28311552 * 2);
  int* idxE = (int*)alloc((size_t)4 * 4096 * 4);
  int* cnts = (int*)alloc(64);

  const size_t moff[12] = {0, 2097152, 4194304, 6291456, 8388608, 10485760,
                           12582912, 16777216, 20971520, 23068672, 24117248, 26214400};

  // ---- weight conversions ----
  cvt_attn4_k<<<dim3(1024, 4), dim3(256), 0, stream>>>(wq, wk, wv, wo, awh, awl);
  cvt_moe_all_k<<<dim3(4096, 12), dim3(256), 0, stream>>>(
      moesrc[0], moesrc[1], moesrc[2], moesrc[3], moesrc[4], moesrc[5],
      moesrc[6], moesrc[7], moesrc[8], moesrc[9], moesrc[10], moesrc[11], moeW);
  const _Float16* woh = awh + (3 << 20); const _Float16* wol = awl + (3 << 20);

  // ---- attention path (fp16x2) ----
  rms_split_k<<<dim3(NTOK), dim3(256), 0, stream>>>(x, n1w, hh, hl);

  // fused QKV: B = [wq|wk|wv] rows of the converted plane, N=3072
  gemm_split_k<3><<<dim3(24, 32), dim3(256), 0, stream>>>(
      hh, hl, awh, awl, 1024, 3072, qh, ql, 1.0f / SW, nullptr, nullptr,
      kh, kl, vth, vtl);

  qknorm2_k<<<dim3(NTOK * NHEAD / 4, 2), dim3(256), 0, stream>>>(qh, ql, kh, kl, qnw, knw);

  attn_k<<<dim3(512), dim3(256), 0, stream>>>(qh, ql, kh, kl, vth, vtl, hh, hl);

  gemm_split_k<1><<<dim3(8, 32), dim3(256), 0, stream>>>(
      hh, hl, woh, wol, 1024, 1024, nullptr, nullptr, 1.0f / (SA * SW), x, outp,
      nullptr, nullptr, nullptr, nullptr);

  // ---- MoE (sparse top-2) ----
  rmsgate_k<<<dim3(NTOK), dim3(256), 0, stream>>>(outp, n2w, gw, xfb, wts, moe);
  route_k<<<dim3(4), dim3(256), 0, stream>>>(wts, idxE, cnts);

  auto mw = [&](int i) -> const unsigned short* { return moeW + moff[i]; };
  const int* g0 = idxE;           const int* g1 = idxE + 4096;
  const int* g2 = idxE + 8192;    const int* g3 = idxE + 12288;

  // expert 0: gelu(x@up^T)@down^T
  gemm_bf16_k<1, 0, 1><<<dim3(16, 32), dim3(256), 0, stream>>>(
      xfb, mw(0), 1024, 2048, t0, nullptr, nullptr, nullptr, 0, g0, cnts);
  gemm_bf16_k<0, 2, 0><<<dim3(8, 32), dim3(256), 0, stream>>>(
      t0, mw(1), 2048, 1024, nullptr, nullptr, moe, wts, 0, g0, cnts);
  // expert 1: (silu(x@w1^T) * (x@w2^T)) @ down^T
  gemm_bf16_k<0, 0, 1><<<dim3(16, 32), dim3(256), 0, stream>>>(
      xfb, mw(3), 1024, 2048, t0, nullptr, nullptr, nullptr, 1, g1, cnts);
  gemm_bf16_k<0, 1, 1><<<dim3(16, 32), dim3(256), 0, stream>>>(
      xfb, mw(2), 1024, 2048, t1, t0, nullptr, nullptr, 1, g1, cnts);
  gemm_bf16_k<0, 2, 0><<<dim3(8, 32), dim3(256), 0, stream>>>(
      t1, mw(4), 2048, 1024, nullptr, nullptr, moe, wts, 1, g1, cnts);
  // expert 2: gelu(gelu(gelu(x@l1)@l2)@l3)@l4
  gemm_bf16_k<1, 0, 1><<<dim3(16, 32), dim3(256), 0, stream>>>(
      xfb, mw(5), 1024, 2048, t0, nullptr, nullptr, nullptr, 2, g2, cnts);
  gemm_bf16_k<1, 0, 0><<<dim3(16, 32), dim3(256), 0, stream>>>(
      t0, mw(6), 2048, 2048, t1, nullptr, nullptr, nullptr, 2, g2, cnts);
  gemm_bf16_k<1, 0, 0><<<dim3(16, 32), dim3(256), 0, stream>>>(
      t1, mw(7), 2048, 2048, t0, nullptr, nullptr, nullptr, 2, g2, cnts);
  gemm_bf16_k<0, 2, 0><<<dim3(8, 32), dim3(256), 0, stream>>>(
      t0, mw(8), 2048, 1024, nullptr, nullptr, moe, wts, 2, g2, cnts);
  // expert 3: gelu(gelu(x@down)@up)@out
  gemm_bf16_k<1, 0, 1><<<dim3(8, 32), dim3(256), 0, stream>>>(
      xfb, mw(9), 1024, 1024, t1, nullptr, nullptr, nullptr, 3, g3, cnts);
  gemm_bf16_k<1, 0, 0><<<dim3(16, 32), dim3(256), 0, stream>>>(
      t1, mw(10), 1024, 2048, t0, nullptr, nullptr, nullptr, 3, g3, cnts);
  gemm_bf16_k<0, 2, 0><<<dim3(8, 32), dim3(256), 0, stream>>>(
      t0, mw(11), 2048, 1024, nullptr, nullptr, moe, wts, 3, g3, cnts);

  comb_k<<<dim3(4096), dim3(256), 0, stream>>>(outp, moe);
}

// Round 4
// 818.042 us; speedup vs baseline: 1.0169x; 1.0169x over previous
//
#include <hip/hip_runtime.h>
#include <math.h>

#define DIM   1024
#define NTOK  4096
#define TSEQ  1024
#define NHEAD 16
#define MPROT 256
#define EPSR  1.1920929e-07f
#define SA    64.0f
#define SW    256.0f
#define SPC   64.0f

typedef __attribute__((ext_vector_type(8))) short          short8;
typedef __attribute__((ext_vector_type(8))) _Float16       half8;
typedef __attribute__((ext_vector_type(4))) _Float16       half4;
typedef __attribute__((ext_vector_type(4))) float          f32x4;
typedef __attribute__((ext_vector_type(4))) unsigned short us4;

static __device__ __forceinline__ float bf2f(unsigned short s) {
  union { unsigned int u; float f; } c; c.u = ((unsigned int)s) << 16; return c.f;
}
static __device__ __forceinline__ unsigned short f2bf(float f) {
  union { float f; unsigned int u; } c; c.f = f;
  return (unsigned short)((c.u + 0x7fffu + ((c.u >> 16) & 1u)) >> 16);
}
static __device__ __forceinline__ void gload16(void* lds, const void* g) {
  __builtin_amdgcn_global_load_lds(
      (__attribute__((address_space(1))) void*)const_cast<void*>(g),
      (__attribute__((address_space(3))) void*)lds, 16, 0, 0);
}

// XCD swizzle: stripe m-blocks across XCDs (mb%8 == xcd), keep all n-blocks of an
// m-panel on one XCD for A-panel L2 reuse. Requires gridDim.y % 8 == 0.
// Returns (m0, n0) in units of 128.
static __device__ __forceinline__ void tile_swz(int& m0, int& n0) {
  const int gx = gridDim.x;
  const int L = blockIdx.y * gx + blockIdx.x;
  const int xcd = L & 7;
  const int j = L >> 3;
  const int mbq = j / gx;
  const int nb = j - mbq * gx;
  m0 = ((mbq << 3) | xcd) << 7;
  n0 = nb << 7;
}

// ---------------- conversions ----------------
// 4 attention weights split-converted in one launch into [4][1M] half planes
__global__ __launch_bounds__(256) void cvt_attn4_k(const float* __restrict__ wq,
                                                   const float* __restrict__ wk,
                                                   const float* __restrict__ wv,
                                                   const float* __restrict__ wo,
                                                   _Float16* __restrict__ dh,
                                                   _Float16* __restrict__ dl) {
  const int wi = blockIdx.y;
  const float* s = (wi == 0) ? wq : (wi == 1) ? wk : (wi == 2) ? wv : wo;
  const int i = blockIdx.x * 256 + threadIdx.x;
  const size_t off4 = ((size_t)wi << 20) >> 2;
  const float4 v = ((const float4*)s)[i];
  float a0 = v.x * SW, a1 = v.y * SW, a2 = v.z * SW, a3 = v.w * SW;
  half4 hv, lv;
  _Float16 h0 = (_Float16)a0; hv[0] = h0; lv[0] = (_Float16)(a0 - (float)h0);
  _Float16 h1 = (_Float16)a1; hv[1] = h1; lv[1] = (_Float16)(a1 - (float)h1);
  _Float16 h2 = (_Float16)a2; hv[2] = h2; lv[2] = (_Float16)(a2 - (float)h2);
  _Float16 h3 = (_Float16)a3; hv[3] = h3; lv[3] = (_Float16)(a3 - (float)h3);
  ((half4*)dh)[off4 + i] = hv; ((half4*)dl)[off4 + i] = lv;
}

// all 12 MoE weights -> bf16, one launch
__global__ __launch_bounds__(256) void cvt_moe_all_k(
    const float* s0, const float* s1, const float* s2, const float* s3,
    const float* s4, const float* s5, const float* s6, const float* s7,
    const float* s8, const float* s9, const float* s10, const float* s11,
    unsigned short* __restrict__ dst) {
  const int n4tab[12] = {524288, 524288, 524288, 524288, 524288, 524288,
                         1048576, 1048576, 524288, 262144, 524288, 524288};
  const size_t offtab[12] = {0, 2097152, 4194304, 6291456, 8388608, 10485760,
                             12582912, 16777216, 20971520, 23068672, 24117248, 26214400};
  const int wi = blockIdx.y;
  const int i = blockIdx.x * 256 + threadIdx.x;
  if (i >= n4tab[wi]) return;
  const float* s;
  switch (wi) {
    case 0: s = s0; break; case 1: s = s1; break; case 2: s = s2; break;
    case 3: s = s3; break; case 4: s = s4; break; case 5: s = s5; break;
    case 6: s = s6; break; case 7: s = s7; break; case 8: s = s8; break;
    case 9: s = s9; break; case 10: s = s10; break; default: s = s11; break;
  }
  const float4 v = ((const float4*)s)[i];
  us4 o; o[0] = f2bf(v.x); o[1] = f2bf(v.y); o[2] = f2bf(v.z); o[3] = f2bf(v.w);
  ((us4*)(dst + offtab[wi]))[i] = o;
}

// ---------------- RMS norms ----------------
__global__ __launch_bounds__(256) void rms_split_k(const float* __restrict__ in,
                                                   const float* __restrict__ wgt,
                                                   _Float16* __restrict__ oh,
                                                   _Float16* __restrict__ ol) {
  const int row = blockIdx.x, tid = threadIdx.x;
  const float4 v = ((const float4*)(in + (size_t)row * DIM))[tid];
  float ss = v.x * v.x + v.y * v.y + v.z * v.z + v.w * v.w;
#pragma unroll
  for (int o = 32; o; o >>= 1) ss += __shfl_xor(ss, o);
  __shared__ float red[4];
  if ((tid & 63) == 0) red[tid >> 6] = ss;
  __syncthreads();
  const float sc = rsqrtf((red[0] + red[1] + red[2] + red[3]) * (1.0f / DIM) + EPSR) * SA;
  const float4 wv = ((const float4*)wgt)[tid];
  float a[4] = {v.x * sc * wv.x, v.y * sc * wv.y, v.z * sc * wv.z, v.w * sc * wv.w};
  half4 hv, lv;
#pragma unroll
  for (int j = 0; j < 4; ++j) {
    _Float16 hh = (_Float16)a[j]; hv[j] = hh; lv[j] = (_Float16)(a[j] - (float)hh);
  }
  ((half4*)(oh + (size_t)row * DIM))[tid] = hv;
  ((half4*)(ol + (size_t)row * DIM))[tid] = lv;
}

// fused RMSNorm(bf16 out) + gate logits/softmax/top-2 + moe buffer zeroing
__global__ __launch_bounds__(256) void rmsgate_k(const float* __restrict__ x2,
                                                 const float* __restrict__ n2w,
                                                 const float* __restrict__ gw,
                                                 unsigned short* __restrict__ xfb,
                                                 float* __restrict__ wts,
                                                 float* __restrict__ moe) {
  const int row = blockIdx.x, tid = threadIdx.x;
  ((float4*)(moe + (size_t)row * DIM))[tid] = (float4){0.f, 0.f, 0.f, 0.f};
  const float4 v = ((const float4*)(x2 + (size_t)row * DIM))[tid];
  float ss = v.x * v.x + v.y * v.y + v.z * v.z + v.w * v.w;
#pragma unroll
  for (int o = 32; o; o >>= 1) ss += __shfl_xor(ss, o);
  __shared__ float red[4];
  __shared__ float redE[4][4];
  const int w = tid >> 6, lane = tid & 63;
  if (lane == 0) red[w] = ss;
  __syncthreads();
  const float sc = rsqrtf((red[0] + red[1] + red[2] + red[3]) * (1.0f / DIM) + EPSR);
  const float4 nw = ((const float4*)n2w)[tid];
  const float xn0 = v.x * sc * nw.x, xn1 = v.y * sc * nw.y;
  const float xn2 = v.z * sc * nw.z, xn3 = v.w * sc * nw.w;
  us4 ob; ob[0] = f2bf(xn0); ob[1] = f2bf(xn1); ob[2] = f2bf(xn2); ob[3] = f2bf(xn3);
  ((us4*)(xfb + (size_t)row * DIM))[tid] = ob;
#pragma unroll
  for (int e = 0; e < 4; ++e) {
    const float4 g = ((const float4*)(gw + (size_t)e * DIM))[tid];
    float d = xn0 * g.x + xn1 * g.y + xn2 * g.z + xn3 * g.w;
#pragma unroll
    for (int o = 32; o; o >>= 1) d += __shfl_xor(d, o);
    if (lane == 0) redE[w][e] = d;
  }
  __syncthreads();
  if (tid == 0) {
    float lg[4];
#pragma unroll
    for (int e = 0; e < 4; ++e) lg[e] = redE[0][e] + redE[1][e] + redE[2][e] + redE[3][e];
    const float mx = fmaxf(fmaxf(lg[0], lg[1]), fmaxf(lg[2], lg[3]));
    float pe[4]; float sum = 0.0f;
#pragma unroll
    for (int e = 0; e < 4; ++e) { pe[e] = __expf(lg[e] - mx); sum += pe[e]; }
#pragma unroll
    for (int e = 0; e < 4; ++e) pe[e] /= sum;
    int i1 = 0;
    for (int e = 1; e < 4; ++e) if (pe[e] > pe[i1]) i1 = e;
    int i2 = -1;
    for (int e = 0; e < 4; ++e) { if (e == i1) continue; if (i2 < 0 || pe[e] > pe[i2]) i2 = e; }
    const float s2 = pe[i1] + pe[i2] + 1e-8f;
    float o[4] = {0.f, 0.f, 0.f, 0.f};
    o[i1] = pe[i1] / s2; o[i2] = pe[i2] / s2;
    float4 r; r.x = o[0]; r.y = o[1]; r.z = o[2]; r.w = o[3];
    *(float4*)(wts + (size_t)row * 4) = r;
  }
}

// per (token,head) RMS over 64 dims; y=0 -> Q planes, y=1 -> K planes
__global__ __launch_bounds__(256) void qknorm2_k(_Float16* __restrict__ qh,
                                                 _Float16* __restrict__ ql,
                                                 _Float16* __restrict__ kh,
                                                 _Float16* __restrict__ kl,
                                                 const float* __restrict__ qnw,
                                                 const float* __restrict__ knw) {
  _Float16* ph; _Float16* pl; const float* wgt;
  if (blockIdx.y == 0) { ph = qh; pl = ql; wgt = qnw; }
  else { ph = kh; pl = kl; wgt = knw; }
  const int idx = (blockIdx.x << 2) + (threadIdx.x >> 6);
  const int lane = threadIdx.x & 63;
  const size_t off = ((size_t)idx << 6) + lane;
  const float v = (float)ph[off] + (float)pl[off];
  float ss = v * v;
#pragma unroll
  for (int o = 32; o; o >>= 1) ss += __shfl_xor(ss, o);
  const float sc = rsqrtf(ss * (1.0f / (64.0f * SA * SA)) + EPSR);
  const float nv = v * sc * wgt[lane];
  _Float16 hh = (_Float16)nv;
  ph[off] = hh; pl[off] = (_Float16)(nv - (float)hh);
}

// ---------------- deterministic order-preserving per-expert compaction ----------------
__global__ __launch_bounds__(256) void route_k(const float* __restrict__ wts,
                                               int* __restrict__ idxE,
                                               int* __restrict__ cnts) {
  const int e = blockIdx.x;
  const int tid = threadIdx.x, w = tid >> 6, lane = tid & 63;
  __shared__ int wsum[4];
  __shared__ int baseS;
  if (tid == 0) baseS = 0;
  __syncthreads();
  for (int c = 0; c < 16; ++c) {
    const int tok = (c << 8) + tid;
    const bool pred = wts[(size_t)tok * 4 + e] > 0.0f;
    const unsigned long long m = __ballot(pred);
    const int lanepre = __popcll(m & ((1ull << lane) - 1ull));
    if (lane == 0) wsum[w] = __popcll(m);
    __syncthreads();
    int wpre = 0;
#pragma unroll
    for (int i = 0; i < 4; ++i) wpre += (i < w) ? wsum[i] : 0;
    const int tot = wsum[0] + wsum[1] + wsum[2] + wsum[3];
    if (pred) idxE[(e << 12) + baseS + wpre + lanepre] = tok;
    __syncthreads();
    if (tid == 0) baseS += tot;
    __syncthreads();
  }
  const int cnt = baseS;
  if (tid == 0) cnts[e] = cnt;
  for (int j = cnt + tid; j < 4096; j += 256) idxE[(e << 12) + j] = 0;
}

// ---------------- bf16 GEMM: out = epilogue(A[M,K] @ W[F,K]^T), sparse rows ----------------
// ACT: 0=none 1=gelu
// EP: 0=store bf16, 1=silu(v)*other->bf16, 2=scatter moe[tok] += wt*v
// GATH: 1 = A rows gathered via gidx during staging
template <int ACT, int EP, int GATH>
__global__ __launch_bounds__(256, 2) void gemm_bf16_k(
    const unsigned short* __restrict__ A, const unsigned short* __restrict__ Bw,
    int K, int F,
    unsigned short* __restrict__ outb, const unsigned short* __restrict__ other,
    float* __restrict__ outf, const float* __restrict__ wts, int expert,
    const int* __restrict__ gidx, const int* __restrict__ cntp) {
  __shared__ unsigned short As[2][128][64];
  __shared__ unsigned short Bs[2][128][64];
  const int tid = threadIdx.x;
  const int w = tid >> 6, lane = tid & 63;
  const int wr = ((w >> 1) << 6), wc = ((w & 1) << 6);
  int m0, n0;
  tile_swz(m0, n0);
  const int cnt = cntp ? cntp[expert] : (1 << 30);
  if (m0 >= cnt) return;
  const int rr = lane & 15, kgl = lane >> 4;
  const int srow = tid >> 3, sslot = tid & 7;

  int grow[4];
#pragma unroll
  for (int i = 0; i < 4; ++i) {
    const int r = (i << 5) + srow;
    grow[i] = GATH ? gidx[m0 + r] : (m0 + r);
  }

  f32x4 acc[4][4];
#pragma unroll
  for (int a_ = 0; a_ < 4; ++a_)
#pragma unroll
    for (int b_ = 0; b_ < 4; ++b_) acc[a_][b_] = (f32x4){0.f, 0.f, 0.f, 0.f};

  const int KT = K >> 6;
  auto stage = [&](int buf, int kt) {
    const int k0 = kt << 6;
#pragma unroll
    for (int i = 0; i < 4; ++i) {
      const int r = (i << 5) + srow;
      const int ls = sslot ^ (r & 7);
      gload16(&As[buf][(i << 5) + (w << 3)][0], A + (size_t)grow[i] * K + k0 + (ls << 3));
      gload16(&Bs[buf][(i << 5) + (w << 3)][0], Bw + (size_t)(n0 + r) * K + k0 + (ls << 3));
    }
  };
  stage(0, 0);
  __syncthreads();
  for (int kt = 0; kt < KT; ++kt) {
    const int cur = kt & 1;
    if (kt + 1 < KT) stage(cur ^ 1, kt + 1);
    short8 af[4][2], bfr[4][2];
#pragma unroll
    for (int f = 0; f < 4; ++f) {
#pragma unroll
      for (int ks = 0; ks < 2; ++ks) {
        const int row = wr + (f << 4) + rr;
        const int kg = (ks << 2) + kgl;
        af[f][ks] = *(const short8*)&As[cur][row][(kg ^ (row & 7)) << 3];
        const int col = wc + (f << 4) + rr;
        bfr[f][ks] = *(const short8*)&Bs[cur][col][(kg ^ (col & 7)) << 3];
      }
    }
#pragma unroll
    for (int fi = 0; fi < 4; ++fi)
#pragma unroll
      for (int fj = 0; fj < 4; ++fj)
#pragma unroll
        for (int ks = 0; ks < 2; ++ks)
          acc[fi][fj] = __builtin_amdgcn_mfma_f32_16x16x32_bf16(
              af[fi][ks], bfr[fj][ks], acc[fi][fj], 0, 0, 0);
    __syncthreads();
  }
#pragma unroll
  for (int fi = 0; fi < 4; ++fi)
#pragma unroll
    for (int fj = 0; fj < 4; ++fj) {
      const int col = n0 + wc + (fj << 4) + rr;
#pragma unroll
      for (int r = 0; r < 4; ++r) {
        const int row = m0 + wr + (fi << 4) + (kgl << 2) + r;
        if (row >= cnt) continue;
        float v = acc[fi][fj][r];
        if (ACT == 1) v = 0.5f * v * (1.0f + erff(v * 0.70710678118654752f));
        if (EP == 0) {
          outb[(size_t)row * F + col] = f2bf(v);
        } else if (EP == 1) {
          const size_t off = (size_t)row * F + col;
          const float sv = v / (1.0f + __expf(-v));
          outb[off] = f2bf(sv * bf2f(other[off]));
        } else {
          const int tok = gidx[row];
          outf[(size_t)tok * DIM + col] += wts[(size_t)tok * 4 + expert] * v;
        }
      }
    }
}

// ---------------- fp16x2 split GEMM (3-term) ----------------
// EP: 1 = fp32: resid + masked(v); 3 = fused QKV epilogue (q/k planes + V^T planes)
template <int EP>
__global__ __launch_bounds__(256, 2) void gemm_split_k(
    const _Float16* __restrict__ Ah, const _Float16* __restrict__ Al,
    const _Float16* __restrict__ Bh, const _Float16* __restrict__ Bl,
    int K, int F,
    _Float16* __restrict__ Oh, _Float16* __restrict__ Ol, float oscale,
    const float* __restrict__ resid, float* __restrict__ outf,
    _Float16* __restrict__ K2h, _Float16* __restrict__ K2l,
    _Float16* __restrict__ V2h, _Float16* __restrict__ V2l) {
  __shared__ _Float16 AsH[2][128][32], AsL[2][128][32];
  __shared__ _Float16 BsH[2][128][32], BsL[2][128][32];
  const int tid = threadIdx.x;
  const int w = tid >> 6, lane = tid & 63;
  const int wr = ((w >> 1) << 6), wc = ((w & 1) << 6);
  int m0, n0;
  tile_swz(m0, n0);
  const int rr = lane & 15, kgl = lane >> 4;
  const int srow = tid >> 2, sslot = tid & 3;

  f32x4 acc[4][4];
#pragma unroll
  for (int a_ = 0; a_ < 4; ++a_)
#pragma unroll
    for (int b_ = 0; b_ < 4; ++b_) acc[a_][b_] = (f32x4){0.f, 0.f, 0.f, 0.f};

  const int KT = K >> 5;
  auto stage = [&](int buf, int kt) {
    const int k0 = kt << 5;
#pragma unroll
    for (int i = 0; i < 2; ++i) {
      const int r = (i << 6) + srow;
      const int ls = sslot ^ ((r >> 1) & 3);
      const size_t ga = (size_t)(m0 + r) * K + k0 + (ls << 3);
      const size_t gb = (size_t)(n0 + r) * K + k0 + (ls << 3);
      const int lr = (i << 6) + (w << 4);
      gload16(&AsH[buf][lr][0], Ah + ga);
      gload16(&AsL[buf][lr][0], Al + ga);
      gload16(&BsH[buf][lr][0], Bh + gb);
      gload16(&BsL[buf][lr][0], Bl + gb);
    }
  };
  stage(0, 0);
  __syncthreads();
  for (int kt = 0; kt < KT; ++kt) {
    const int cur = kt & 1;
    if (kt + 1 < KT) stage(cur ^ 1, kt + 1);
    half8 ah[4], al[4], bh[4], bl[4];
#pragma unroll
    for (int f = 0; f < 4; ++f) {
      const int row = wr + (f << 4) + rr;
      const int pa = (kgl ^ ((row >> 1) & 3)) << 3;
      ah[f] = *(const half8*)&AsH[cur][row][pa];
      al[f] = *(const half8*)&AsL[cur][row][pa];
      const int col = wc + (f << 4) + rr;
      const int pb = (kgl ^ ((col >> 1) & 3)) << 3;
      bh[f] = *(const half8*)&BsH[cur][col][pb];
      bl[f] = *(const half8*)&BsL[cur][col][pb];
    }
#pragma unroll
    for (int fi = 0; fi < 4; ++fi)
#pragma unroll
      for (int fj = 0; fj < 4; ++fj) {
        acc[fi][fj] = __builtin_amdgcn_mfma_f32_16x16x32_f16(ah[fi], bh[fj], acc[fi][fj], 0, 0, 0);
        acc[fi][fj] = __builtin_amdgcn_mfma_f32_16x16x32_f16(ah[fi], bl[fj], acc[fi][fj], 0, 0, 0);
        acc[fi][fj] = __builtin_amdgcn_mfma_f32_16x16x32_f16(al[fi], bh[fj], acc[fi][fj], 0, 0, 0);
      }
    __syncthreads();
  }
#pragma unroll
  for (int fi = 0; fi < 4; ++fi)
#pragma unroll
    for (int fj = 0; fj < 4; ++fj) {
      const int col = n0 + wc + (fj << 4) + rr;
      const int rowb = m0 + wr + (fi << 4) + (kgl << 2);
      if (EP == 3) {
        if (col < 2048) {
          _Float16* ph = (col < 1024) ? Oh : K2h;
          _Float16* pl = (col < 1024) ? Ol : K2l;
          const int c = col & 1023;
#pragma unroll
          for (int r = 0; r < 4; ++r) {
            const float v = acc[fi][fj][r] * oscale;
            const _Float16 hh2 = (_Float16)v;
            const size_t off = (size_t)(rowb + r) * DIM + c;
            ph[off] = hh2; pl[off] = (_Float16)(v - (float)hh2);
          }
        } else {
          const int c2 = col - 2048;
          half4 h4, l4;
#pragma unroll
          for (int r = 0; r < 4; ++r) {
            const float v = acc[fi][fj][r] * oscale;
            const _Float16 hh2 = (_Float16)v;
            h4[r] = hh2; l4[r] = (_Float16)(v - (float)hh2);
          }
          const size_t vt = ((size_t)((rowb >> 10) << 4) + (size_t)(c2 >> 6)) * 65536 +
                            (size_t)(c2 & 63) * 1024 + (size_t)(rowb & 1023);
          *(half4*)&V2h[vt] = h4;
          *(half4*)&V2l[vt] = l4;
        }
      } else {
#pragma unroll
        for (int r = 0; r < 4; ++r) {
          const size_t off = (size_t)(rowb + r) * F + col;
          const float v = acc[fi][fj][r] * oscale;
          outf[off] = resid[off] + (col >= MPROT ? v : 0.0f);
        }
      }
    }
}

// ---------------- flash attention, causal, fp16x2 split, swapped-QK ----------------
__global__ __launch_bounds__(256, 2) void attn_k(
    const _Float16* __restrict__ Qh, const _Float16* __restrict__ Ql,
    const _Float16* __restrict__ Kh, const _Float16* __restrict__ Kl,
    const _Float16* __restrict__ Vth, const _Float16* __restrict__ Vtl,
    _Float16* __restrict__ Oh, _Float16* __restrict__ Ol) {
  __shared__ _Float16 Ksh[2][32][64], Ksl[2][32][64];
  __shared__ _Float16 Vsh[2][64][40], Vsl[2][64][40];
  __shared__ _Float16 Plh[4][16][40], Pll[4][16][40];
  const int n = blockIdx.x;
  const int qt = n >> 6;
  const int bh = ((n & 7) << 3) | ((n >> 3) & 7);
  const int b = bh >> 4, h = bh & 15;
  const int tid = threadIdx.x, w = tid >> 6, lane = tid & 63;
  const int rr = lane & 15, rg = lane >> 4;
  const size_t tokbase = (size_t)b * TSEQ;
  const int hcol = h << 6;
  const size_t vtbase = (size_t)bh << 16;
  const int q0w = (qt << 7) + (w << 5);
  const float sscale = 0.125f / (SA * SA);

  half8 qfh[2][2], qfl[2][2];
#pragma unroll
  for (int qf = 0; qf < 2; ++qf)
#pragma unroll
    for (int ks = 0; ks < 2; ++ks) {
      const size_t off = (tokbase + q0w + (qf << 4) + rr) * DIM + hcol + (ks << 5) + (rg << 3);
      qfh[qf][ks] = *(const half8*)&Qh[off];
      qfl[qf][ks] = *(const half8*)&Ql[off];
    }

  f32x4 oacc[2][4];
#pragma unroll
  for (int qf = 0; qf < 2; ++qf)
#pragma unroll
    for (int dg = 0; dg < 4; ++dg) oacc[qf][dg] = (f32x4){0.f, 0.f, 0.f, 0.f};
  float mreg[2] = {-INFINITY, -INFINITY}, lreg[2] = {0.f, 0.f};

  const int kr = (w << 3) + (lane >> 3);
  const int kswz = ((lane & 7) ^ (kr & 7)) << 3;
  const int vr = tid >> 2;
  const int vs = (tid & 3) << 3;

  const int ntiles = (qt + 1) << 2;

  {
    gload16(&Ksh[0][w << 3][0], &Kh[(tokbase + kr) * DIM + hcol + kswz]);
    gload16(&Ksl[0][w << 3][0], &Kl[(tokbase + kr) * DIM + hcol + kswz]);
    const half8 vvh = *(const half8*)&Vth[vtbase + (size_t)vr * TSEQ + vs];
    const half8 vvl = *(const half8*)&Vtl[vtbase + (size_t)vr * TSEQ + vs];
    *(half8*)&Vsh[0][vr][vs] = vvh;
    *(half8*)&Vsl[0][vr][vs] = vvl;
    __syncthreads();
  }

  for (int t = 0; t < ntiles; ++t) {
    const int cur = t & 1;
    const int kv0 = t << 5;
    const bool havenext = (t + 1 < ntiles);
    half8 nvh, nvl;
    if (havenext) {
      const int kn = kv0 + 32;
      gload16(&Ksh[cur ^ 1][w << 3][0], &Kh[(tokbase + kn + kr) * DIM + hcol + kswz]);
      gload16(&Ksl[cur ^ 1][w << 3][0], &Kl[(tokbase + kn + kr) * DIM + hcol + kswz]);
      nvh = *(const half8*)&Vth[vtbase + (size_t)vr * TSEQ + kn + vs];
      nvl = *(const half8*)&Vtl[vtbase + (size_t)vr * TSEQ + kn + vs];
    }
    if (kv0 <= q0w + 31) {
      half8 kfh[2][2], kfl[2][2];
#pragma unroll
      for (int kt = 0; kt < 2; ++kt)
#pragma unroll
        for (int ks = 0; ks < 2; ++ks) {
          const int row = (kt << 4) + rr;
          const int sw = ((((ks << 2) + rg)) ^ (row & 7)) << 3;
          kfh[kt][ks] = *(const half8*)&Ksh[cur][row][sw];
          kfl[kt][ks] = *(const half8*)&Ksl[cur][row][sw];
        }
#pragma unroll
      for (int qf = 0; qf < 2; ++qf) {
        if (kv0 > q0w + (qf << 4) + 15) continue;
        f32x4 st[2];
        st[0] = (f32x4){0.f, 0.f, 0.f, 0.f};
        st[1] = (f32x4){0.f, 0.f, 0.f, 0.f};
#pragma unroll
        for (int kt = 0; kt < 2; ++kt)
#pragma unroll
          for (int ks = 0; ks < 2; ++ks) {
            st[kt] = __builtin_amdgcn_mfma_f32_16x16x32_f16(kfh[kt][ks], qfh[qf][ks], st[kt], 0, 0, 0);
            st[kt] = __builtin_amdgcn_mfma_f32_16x16x32_f16(kfh[kt][ks], qfl[qf][ks], st[kt], 0, 0, 0);
            st[kt] = __builtin_amdgcn_mfma_f32_16x16x32_f16(kfl[kt][ks], qfh[qf][ks], st[kt], 0, 0, 0);
          }
        const int qg = q0w + (qf << 4) + rr;
        float s[2][4]; float mx = -INFINITY;
#pragma unroll
        for (int kt = 0; kt < 2; ++kt)
#pragma unroll
          for (int r = 0; r < 4; ++r) {
            float sv = st[kt][r] * sscale;
            if (kv0 + (kt << 4) + (rg << 2) + r > qg) sv = -INFINITY;
            s[kt][r] = sv; mx = fmaxf(mx, sv);
          }
        mx = fmaxf(mx, __shfl_xor(mx, 16));
        mx = fmaxf(mx, __shfl_xor(mx, 32));
        const float mn = fmaxf(mreg[qf], mx);
        const float al = __expf(mreg[qf] - mn);
        mreg[qf] = mn;
        float p[2][4]; float rs = 0.f;
#pragma unroll
        for (int kt = 0; kt < 2; ++kt)
#pragma unroll
          for (int r = 0; r < 4; ++r) { p[kt][r] = __expf(s[kt][r] - mn); rs += p[kt][r]; }
        rs += __shfl_xor(rs, 16);
        rs += __shfl_xor(rs, 32);
        lreg[qf] = lreg[qf] * al + rs;
#pragma unroll
        for (int kt = 0; kt < 2; ++kt) {
          half4 h4, l4;
#pragma unroll
          for (int r = 0; r < 4; ++r) {
            const float pv = p[kt][r] * SPC;
            const _Float16 ph = (_Float16)pv;
            h4[r] = ph; l4[r] = (_Float16)(pv - (float)ph);
          }
          *(half4*)&Plh[w][rr][(kt << 4) + (rg << 2)] = h4;
          *(half4*)&Pll[w][rr][(kt << 4) + (rg << 2)] = l4;
        }
        float alr[4];
#pragma unroll
        for (int r = 0; r < 4; ++r) alr[r] = __shfl(al, (lane & 48) | ((rg << 2) + r));
#pragma unroll
        for (int dg = 0; dg < 4; ++dg)
#pragma unroll
          for (int r = 0; r < 4; ++r) oacc[qf][dg][r] *= alr[r];
        const half8 pah = *(const half8*)&Plh[w][rr][rg << 3];
        const half8 pal = *(const half8*)&Pll[w][rr][rg << 3];
#pragma unroll
        for (int dg = 0; dg < 4; ++dg) {
          const half8 vfh2 = *(const half8*)&Vsh[cur][(dg << 4) + rr][rg << 3];
          const half8 vfl2 = *(const half8*)&Vsl[cur][(dg << 4) + rr][rg << 3];
          oacc[qf][dg] = __builtin_amdgcn_mfma_f32_16x16x32_f16(pah, vfh2, oacc[qf][dg], 0, 0, 0);
          oacc[qf][dg] = __builtin_amdgcn_mfma_f32_16x16x32_f16(pah, vfl2, oacc[qf][dg], 0, 0, 0);
          oacc[qf][dg] = __builtin_amdgcn_mfma_f32_16x16x32_f16(pal, vfh2, oacc[qf][dg], 0, 0, 0);
        }
      }
    }
    if (havenext) {
      *(half8*)&Vsh[cur ^ 1][vr][vs] = nvh;
      *(half8*)&Vsl[cur ^ 1][vr][vs] = nvl;
    }
    __syncthreads();
  }
#pragma unroll
  for (int qf = 0; qf < 2; ++qf) {
    float li[4];
#pragma unroll
    for (int r = 0; r < 4; ++r)
      li[r] = __shfl(lreg[qf], (lane & 48) | ((rg << 2) + r));
#pragma unroll
    for (int dg = 0; dg < 4; ++dg)
#pragma unroll
      for (int r = 0; r < 4; ++r) {
        const int qloc = (rg << 2) + r;
        const float ov = oacc[qf][dg][r] / (li[r] * SPC);
        const _Float16 hh2 = (_Float16)ov;
        const size_t off = (tokbase + q0w + (qf << 4) + qloc) * DIM + hcol + (dg << 4) + rr;
        Oh[off] = hh2;
        Ol[off] = (_Float16)(ov - (float)hh2);
      }
  }
}

// ---------------- final combine: outp += mask(moe) ----------------
__global__ __launch_bounds__(256) void comb_k(float* __restrict__ outp,
                                              const float* __restrict__ moe) {
  const size_t i = (size_t)blockIdx.x * 256 + threadIdx.x;
  const int c4 = (int)(i & 255);
  if (c4 >= 64) {
    float4 o = ((float4*)outp)[i];
    const float4 m = ((const float4*)moe)[i];
    o.x += m.x; o.y += m.y; o.z += m.z; o.w += m.w;
    ((float4*)outp)[i] = o;
  }
}

extern "C" void kernel_launch(void* const* d_in, const int* in_sizes, int n_in,
                              void* d_out, int out_size, void* d_ws, size_t ws_size,
                              hipStream_t stream) {
  (void)in_sizes; (void)n_in; (void)out_size; (void)ws_size;
  const float* x    = (const float*)d_in[0];
  const float* n1w  = (const float*)d_in[1];
  const float* n2w  = (const float*)d_in[2];
  const float* wq   = (const float*)d_in[3];
  const float* wk   = (const float*)d_in[4];
  const float* wv   = (const float*)d_in[5];
  const float* wo   = (const float*)d_in[6];
  const float* qnw  = (const float*)d_in[7];
  const float* knw  = (const float*)d_in[8];
  const float* gw   = (const float*)d_in[9];
  const float* moesrc[12] = {
    (const float*)d_in[10], (const float*)d_in[11],
    (const float*)d_in[12], (const float*)d_in[13], (const float*)d_in[14],
    (const float*)d_in[15], (const float*)d_in[16], (const float*)d_in[17], (const float*)d_in[18],
    (const float*)d_in[19], (const float*)d_in[20], (const float*)d_in[21]
  };
  float* outp = (float*)d_out;

  char* p = (char*)d_ws;
  auto alloc = [&](size_t bytes) { void* r = (void*)p; p += (bytes + 255) & ~(size_t)255; return r; };
  const size_t NC = (size_t)NTOK * DIM;
  const size_t NH2 = (size_t)NTOK * 2048;
  _Float16* hh = (_Float16*)alloc(NC * 2);
  _Float16* hl = (_Float16*)alloc(NC * 2);
  _Float16* qh = (_Float16*)alloc(NC * 2);
  _Float16* ql = (_Float16*)alloc(NC * 2);
  _Float16* kh = (_Float16*)alloc(NC * 2);
  _Float16* kl = (_Float16*)alloc(NC * 2);
  _Float16* vth = (_Float16*)alloc(NC * 2);
  _Float16* vtl = (_Float16*)alloc(NC * 2);
  unsigned short* xfb = (unsigned short*)alloc(NC * 2);
  unsigned short* t0  = (unsigned short*)alloc(NH2 * 2);
  unsigned short* t1  = (unsigned short*)alloc(NH2 * 2);
  float* moe = (float*)alloc(NC * 4);
  float* wts = (float*)alloc((size_t)NTOK * 4 * 4);
  _Float16* awh = (_Float16*)alloc((size_t)4 * 1024 * 1024 * 2);
  _Float16* awl = (_Float16*)alloc((size_t)4 * 1024 * 1024 * 2);
  unsigned short* moeW = (unsigned short*)alloc((size_t)28311552 * 2);
  int* idxE = (int*)alloc((size_t)4 * 4096 * 4);
  int* cnts = (int*)alloc(64);

  const size_t moff[12] = {0, 2097152, 4194304, 6291456, 8388608, 10485760,
                           12582912, 16777216, 20971520, 23068672, 24117248, 26214400};

  // ---- weight conversions ----
  cvt_attn4_k<<<dim3(1024, 4), dim3(256), 0, stream>>>(wq, wk, wv, wo, awh, awl);
  cvt_moe_all_k<<<dim3(4096, 12), dim3(256), 0, stream>>>(
      moesrc[0], moesrc[1], moesrc[2], moesrc[3], moesrc[4], moesrc[5],
      moesrc[6], moesrc[7], moesrc[8], moesrc[9], moesrc[10], moesrc[11], moeW);
  const _Float16* woh = awh + (3 << 20); const _Float16* wol = awl + (3 << 20);

  // ---- attention path (fp16x2) ----
  rms_split_k<<<dim3(NTOK), dim3(256), 0, stream>>>(x, n1w, hh, hl);

  // fused QKV: B = [wq|wk|wv] rows of the converted plane, N=3072
  gemm_split_k<3><<<dim3(24, 32), dim3(256), 0, stream>>>(
      hh, hl, awh, awl, 1024, 3072, qh, ql, 1.0f / SW, nullptr, nullptr,
      kh, kl, vth, vtl);

  qknorm2_k<<<dim3(NTOK * NHEAD / 4, 2), dim3(256), 0, stream>>>(qh, ql, kh, kl, qnw, knw);

  attn_k<<<dim3(512), dim3(256), 0, stream>>>(qh, ql, kh, kl, vth, vtl, hh, hl);

  gemm_split_k<1><<<dim3(8, 32), dim3(256), 0, stream>>>(
      hh, hl, woh, wol, 1024, 1024, nullptr, nullptr, 1.0f / (SA * SW), x, outp,
      nullptr, nullptr, nullptr, nullptr);

  // ---- MoE (sparse top-2) ----
  rmsgate_k<<<dim3(NTOK), dim3(256), 0, stream>>>(outp, n2w, gw, xfb, wts, moe);
  route_k<<<dim3(4), dim3(256), 0, stream>>>(wts, idxE, cnts);

  auto mw = [&](int i) -> const unsigned short* { return moeW + moff[i]; };
  const int* g0 = idxE;           const int* g1 = idxE + 4096;
  const int* g2 = idxE + 8192;    const int* g3 = idxE + 12288;

  // expert 0: gelu(x@up^T)@down^T
  gemm_bf16_k<1, 0, 1><<<dim3(16, 32), dim3(256), 0, stream>>>(
      xfb, mw(0), 1024, 2048, t0, nullptr, nullptr, nullptr, 0, g0, cnts);
  gemm_bf16_k<0, 2, 0><<<dim3(8, 32), dim3(256), 0, stream>>>(
      t0, mw(1), 2048, 1024, nullptr, nullptr, moe, wts, 0, g0, cnts);
  // expert 1: (silu(x@w1^T) * (x@w2^T)) @ down^T
  gemm_bf16_k<0, 0, 1><<<dim3(16, 32), dim3(256), 0, stream>>>(
      xfb, mw(3), 1024, 2048, t0, nullptr, nullptr, nullptr, 1, g1, cnts);
  gemm_bf16_k<0, 1, 1><<<dim3(16, 32), dim3(256), 0, stream>>>(
      xfb, mw(2), 1024, 2048, t1, t0, nullptr, nullptr, 1, g1, cnts);
  gemm_bf16_k<0, 2, 0><<<dim3(8, 32), dim3(256), 0, stream>>>(
      t1, mw(4), 2048, 1024, nullptr, nullptr, moe, wts, 1, g1, cnts);
  // expert 2: gelu(gelu(gelu(x@l1)@l2)@l3)@l4
  gemm_bf16_k<1, 0, 1><<<dim3(16, 32), dim3(256), 0, stream>>>(
      xfb, mw(5), 1024, 2048, t0, nullptr, nullptr, nullptr, 2, g2, cnts);
  gemm_bf16_k<1, 0, 0><<<dim3(16, 32), dim3(256), 0, stream>>>(
      t0, mw(6), 2048, 2048, t1, nullptr, nullptr, nullptr, 2, g2, cnts);
  gemm_bf16_k<1, 0, 0><<<dim3(16, 32), dim3(256), 0, stream>>>(
      t1, mw(7), 2048, 2048, t0, nullptr, nullptr, nullptr, 2, g2, cnts);
  gemm_bf16_k<0, 2, 0><<<dim3(8, 32), dim3(256), 0, stream>>>(
      t0, mw(8), 2048, 1024, nullptr, nullptr, moe, wts, 2, g2, cnts);
  // expert 3: gelu(gelu(x@down)@up)@out
  gemm_bf16_k<1, 0, 1><<<dim3(8, 32), dim3(256), 0, stream>>>(
      xfb, mw(9), 1024, 1024, t1, nullptr, nullptr, nullptr, 3, g3, cnts);
  gemm_bf16_k<1, 0, 0><<<dim3(16, 32), dim3(256), 0, stream>>>(
      t1, mw(10), 1024, 2048, t0, nullptr, nullptr, nullptr, 3, g3, cnts);
  gemm_bf16_k<0, 2, 0><<<dim3(8, 32), dim3(256), 0, stream>>>(
      t0, mw(11), 2048, 1024, nullptr, nullptr, moe, wts, 3, g3, cnts);

  comb_k<<<dim3(4096), dim3(256), 0, stream>>>(outp, moe);
}

// Round 5
// 742.060 us; speedup vs baseline: 1.1210x; 1.1024x over previous
//
#include <hip/hip_runtime.h>
#include <math.h>

#define DIM   1024
#define NTOK  4096
#define TSEQ  1024
#define NHEAD 16
#define MPROT 256
#define EPSR  1.1920929e-07f
#define SA    64.0f
#define SW    256.0f
#define SPC   64.0f

typedef __attribute__((ext_vector_type(8))) short          short8;
typedef __attribute__((ext_vector_type(8))) _Float16       half8;
typedef __attribute__((ext_vector_type(4))) _Float16       half4;
typedef __attribute__((ext_vector_type(4))) float          f32x4;
typedef __attribute__((ext_vector_type(4))) unsigned short us4;

static __device__ __forceinline__ float bf2f(unsigned short s) {
  union { unsigned int u; float f; } c; c.u = ((unsigned int)s) << 16; return c.f;
}
static __device__ __forceinline__ unsigned short f2bf(float f) {
  union { float f; unsigned int u; } c; c.f = f;
  return (unsigned short)((c.u + 0x7fffu + ((c.u >> 16) & 1u)) >> 16);
}
static __device__ __forceinline__ void gload16(void* lds, const void* g) {
  __builtin_amdgcn_global_load_lds(
      (__attribute__((address_space(1))) void*)const_cast<void*>(g),
      (__attribute__((address_space(3))) void*)lds, 16, 0, 0);
}

// XCD swizzle for dense split-GEMMs: stripe m-blocks across XCDs.
static __device__ __forceinline__ void tile_swz(int& m0, int& n0) {
  const int gx = gridDim.x;
  const int L = blockIdx.y * gx + blockIdx.x;
  const int xcd = L & 7;
  const int j = L >> 3;
  const int mbq = j / gx;
  const int nb = j - mbq * gx;
  m0 = ((mbq << 3) | xcd) << 7;
  n0 = nb << 7;
}

// ---------------- conversions ----------------
__global__ __launch_bounds__(256) void cvt_attn4_k(const float* __restrict__ wq,
                                                   const float* __restrict__ wk,
                                                   const float* __restrict__ wv,
                                                   const float* __restrict__ wo,
                                                   _Float16* __restrict__ dh,
                                                   _Float16* __restrict__ dl) {
  const int wi = blockIdx.y;
  const float* s = (wi == 0) ? wq : (wi == 1) ? wk : (wi == 2) ? wv : wo;
  const int i = blockIdx.x * 256 + threadIdx.x;
  const size_t off4 = ((size_t)wi << 20) >> 2;
  const float4 v = ((const float4*)s)[i];
  float a0 = v.x * SW, a1 = v.y * SW, a2 = v.z * SW, a3 = v.w * SW;
  half4 hv, lv;
  _Float16 h0 = (_Float16)a0; hv[0] = h0; lv[0] = (_Float16)(a0 - (float)h0);
  _Float16 h1 = (_Float16)a1; hv[1] = h1; lv[1] = (_Float16)(a1 - (float)h1);
  _Float16 h2 = (_Float16)a2; hv[2] = h2; lv[2] = (_Float16)(a2 - (float)h2);
  _Float16 h3 = (_Float16)a3; hv[3] = h3; lv[3] = (_Float16)(a3 - (float)h3);
  ((half4*)dh)[off4 + i] = hv; ((half4*)dl)[off4 + i] = lv;
}

__global__ __launch_bounds__(256) void cvt_moe_all_k(
    const float* s0, const float* s1, const float* s2, const float* s3,
    const float* s4, const float* s5, const float* s6, const float* s7,
    const float* s8, const float* s9, const float* s10, const float* s11,
    unsigned short* __restrict__ dst) {
  const int n4tab[12] = {524288, 524288, 524288, 524288, 524288, 524288,
                         1048576, 1048576, 524288, 262144, 524288, 524288};
  const size_t offtab[12] = {0, 2097152, 4194304, 6291456, 8388608, 10485760,
                             12582912, 16777216, 20971520, 23068672, 24117248, 26214400};
  const int wi = blockIdx.y;
  const int i = blockIdx.x * 256 + threadIdx.x;
  if (i >= n4tab[wi]) return;
  const float* s;
  switch (wi) {
    case 0: s = s0; break; case 1: s = s1; break; case 2: s = s2; break;
    case 3: s = s3; break; case 4: s = s4; break; case 5: s = s5; break;
    case 6: s = s6; break; case 7: s = s7; break; case 8: s = s8; break;
    case 9: s = s9; break; case 10: s = s10; break; default: s = s11; break;
  }
  const float4 v = ((const float4*)s)[i];
  us4 o; o[0] = f2bf(v.x); o[1] = f2bf(v.y); o[2] = f2bf(v.z); o[3] = f2bf(v.w);
  ((us4*)(dst + offtab[wi]))[i] = o;
}

// ---------------- RMS norms ----------------
__global__ __launch_bounds__(256) void rms_split_k(const float* __restrict__ in,
                                                   const float* __restrict__ wgt,
                                                   _Float16* __restrict__ oh,
                                                   _Float16* __restrict__ ol) {
  const int row = blockIdx.x, tid = threadIdx.x;
  const float4 v = ((const float4*)(in + (size_t)row * DIM))[tid];
  float ss = v.x * v.x + v.y * v.y + v.z * v.z + v.w * v.w;
#pragma unroll
  for (int o = 32; o; o >>= 1) ss += __shfl_xor(ss, o);
  __shared__ float red[4];
  if ((tid & 63) == 0) red[tid >> 6] = ss;
  __syncthreads();
  const float sc = rsqrtf((red[0] + red[1] + red[2] + red[3]) * (1.0f / DIM) + EPSR) * SA;
  const float4 wv = ((const float4*)wgt)[tid];
  float a[4] = {v.x * sc * wv.x, v.y * sc * wv.y, v.z * sc * wv.z, v.w * sc * wv.w};
  half4 hv, lv;
#pragma unroll
  for (int j = 0; j < 4; ++j) {
    _Float16 hh = (_Float16)a[j]; hv[j] = hh; lv[j] = (_Float16)(a[j] - (float)hh);
  }
  ((half4*)(oh + (size_t)row * DIM))[tid] = hv;
  ((half4*)(ol + (size_t)row * DIM))[tid] = lv;
}

// fused RMSNorm(bf16 out) + gate logits/softmax/top-2 + moe buffer zeroing
__global__ __launch_bounds__(256) void rmsgate_k(const float* __restrict__ x2,
                                                 const float* __restrict__ n2w,
                                                 const float* __restrict__ gw,
                                                 unsigned short* __restrict__ xfb,
                                                 float* __restrict__ wts,
                                                 float* __restrict__ moe) {
  const int row = blockIdx.x, tid = threadIdx.x;
  ((float4*)(moe + (size_t)row * DIM))[tid] = (float4){0.f, 0.f, 0.f, 0.f};
  const float4 v = ((const float4*)(x2 + (size_t)row * DIM))[tid];
  float ss = v.x * v.x + v.y * v.y + v.z * v.z + v.w * v.w;
#pragma unroll
  for (int o = 32; o; o >>= 1) ss += __shfl_xor(ss, o);
  __shared__ float red[4];
  __shared__ float redE[4][4];
  const int w = tid >> 6, lane = tid & 63;
  if (lane == 0) red[w] = ss;
  __syncthreads();
  const float sc = rsqrtf((red[0] + red[1] + red[2] + red[3]) * (1.0f / DIM) + EPSR);
  const float4 nw = ((const float4*)n2w)[tid];
  const float xn0 = v.x * sc * nw.x, xn1 = v.y * sc * nw.y;
  const float xn2 = v.z * sc * nw.z, xn3 = v.w * sc * nw.w;
  us4 ob; ob[0] = f2bf(xn0); ob[1] = f2bf(xn1); ob[2] = f2bf(xn2); ob[3] = f2bf(xn3);
  ((us4*)(xfb + (size_t)row * DIM))[tid] = ob;
#pragma unroll
  for (int e = 0; e < 4; ++e) {
    const float4 g = ((const float4*)(gw + (size_t)e * DIM))[tid];
    float d = xn0 * g.x + xn1 * g.y + xn2 * g.z + xn3 * g.w;
#pragma unroll
    for (int o = 32; o; o >>= 1) d += __shfl_xor(d, o);
    if (lane == 0) redE[w][e] = d;
  }
  __syncthreads();
  if (tid == 0) {
    float lg[4];
#pragma unroll
    for (int e = 0; e < 4; ++e) lg[e] = redE[0][e] + redE[1][e] + redE[2][e] + redE[3][e];
    const float mx = fmaxf(fmaxf(lg[0], lg[1]), fmaxf(lg[2], lg[3]));
    float pe[4]; float sum = 0.0f;
#pragma unroll
    for (int e = 0; e < 4; ++e) { pe[e] = __expf(lg[e] - mx); sum += pe[e]; }
#pragma unroll
    for (int e = 0; e < 4; ++e) pe[e] /= sum;
    int i1 = 0;
    for (int e = 1; e < 4; ++e) if (pe[e] > pe[i1]) i1 = e;
    int i2 = -1;
    for (int e = 0; e < 4; ++e) { if (e == i1) continue; if (i2 < 0 || pe[e] > pe[i2]) i2 = e; }
    const float s2 = pe[i1] + pe[i2] + 1e-8f;
    float o[4] = {0.f, 0.f, 0.f, 0.f};
    o[i1] = pe[i1] / s2; o[i2] = pe[i2] / s2;
    float4 r; r.x = o[0]; r.y = o[1]; r.z = o[2]; r.w = o[3];
    *(float4*)(wts + (size_t)row * 4) = r;
  }
}

// per (token,head) RMS over 64 dims; y=0 -> Q planes, y=1 -> K planes
__global__ __launch_bounds__(256) void qknorm2_k(_Float16* __restrict__ qh,
                                                 _Float16* __restrict__ ql,
                                                 _Float16* __restrict__ kh,
                                                 _Float16* __restrict__ kl,
                                                 const float* __restrict__ qnw,
                                                 const float* __restrict__ knw) {
  _Float16* ph; _Float16* pl; const float* wgt;
  if (blockIdx.y == 0) { ph = qh; pl = ql; wgt = qnw; }
  else { ph = kh; pl = kl; wgt = knw; }
  const int idx = (blockIdx.x << 2) + (threadIdx.x >> 6);
  const int lane = threadIdx.x & 63;
  const size_t off = ((size_t)idx << 6) + lane;
  const float v = (float)ph[off] + (float)pl[off];
  float ss = v * v;
#pragma unroll
  for (int o = 32; o; o >>= 1) ss += __shfl_xor(ss, o);
  const float sc = rsqrtf(ss * (1.0f / (64.0f * SA * SA)) + EPSR);
  const float nv = v * sc * wgt[lane];
  _Float16 hh = (_Float16)nv;
  ph[off] = hh; pl[off] = (_Float16)(nv - (float)hh);
}

// ---------------- deterministic order-preserving per-expert compaction ----------------
__global__ __launch_bounds__(256) void route_k(const float* __restrict__ wts,
                                               int* __restrict__ idxE,
                                               int* __restrict__ cnts) {
  const int e = blockIdx.x;
  const int tid = threadIdx.x, w = tid >> 6, lane = tid & 63;
  __shared__ int wsum[4];
  __shared__ int baseS;
  if (tid == 0) baseS = 0;
  __syncthreads();
  for (int c = 0; c < 16; ++c) {
    const int tok = (c << 8) + tid;
    const bool pred = wts[(size_t)tok * 4 + e] > 0.0f;
    const unsigned long long m = __ballot(pred);
    const int lanepre = __popcll(m & ((1ull << lane) - 1ull));
    if (lane == 0) wsum[w] = __popcll(m);
    __syncthreads();
    int wpre = 0;
#pragma unroll
    for (int i = 0; i < 4; ++i) wpre += (i < w) ? wsum[i] : 0;
    const int tot = wsum[0] + wsum[1] + wsum[2] + wsum[3];
    if (pred) idxE[(e << 12) + baseS + wpre + lanepre] = tok;
    __syncthreads();
    if (tid == 0) baseS += tot;
    __syncthreads();
  }
  const int cnt = baseS;
  if (tid == 0) cnts[e] = cnt;
  for (int j = cnt + tid; j < 4096; j += 256) idxE[(e << 12) + j] = 0;
}

// ---------------- grouped sparse bf16 GEMM: up to 4 sub-ops per launch ----------------
struct SubOp {
  const unsigned short* A;
  const unsigned short* Bw;
  unsigned short* outb;
  const unsigned short* other;
  const int* gidx;
  int K, nbn, act, ep, gath, expert;   // ep: 0 store, 1 silu*other, 2 scatter atomicAdd
};
struct Phase4 { SubOp op[4]; };

__global__ __launch_bounds__(256, 2) void gemm_group_k(Phase4 ph,
                                                       const int* __restrict__ cnts,
                                                       const float* __restrict__ wts,
                                                       float* __restrict__ moe) {
  __shared__ unsigned short As[2][128][64];
  __shared__ unsigned short Bs[2][128][64];
  SubOp op;
  switch (blockIdx.z) {
    case 0: op = ph.op[0]; break;
    case 1: op = ph.op[1]; break;
    case 2: op = ph.op[2]; break;
    default: op = ph.op[3]; break;
  }
  if ((int)blockIdx.x >= op.nbn) return;
  const int cnt = cnts[op.expert];
  const int m0 = (int)blockIdx.y << 7;
  if (m0 >= cnt) return;
  const int n0 = (int)blockIdx.x << 7;
  const int F = op.nbn << 7;
  const int K = op.K;
  const int tid = threadIdx.x;
  const int w = tid >> 6, lane = tid & 63;
  const int wr = ((w >> 1) << 6), wc = ((w & 1) << 6);
  const int rr = lane & 15, kgl = lane >> 4;
  const int srow = tid >> 3, sslot = tid & 7;

  int grow[4];
#pragma unroll
  for (int i = 0; i < 4; ++i) {
    const int r = (i << 5) + srow;
    grow[i] = op.gath ? op.gidx[m0 + r] : (m0 + r);
  }

  f32x4 acc[4][4];
#pragma unroll
  for (int a_ = 0; a_ < 4; ++a_)
#pragma unroll
    for (int b_ = 0; b_ < 4; ++b_) acc[a_][b_] = (f32x4){0.f, 0.f, 0.f, 0.f};

  const int KT = K >> 6;
  auto stage = [&](int buf, int kt) {
    const int k0 = kt << 6;
#pragma unroll
    for (int i = 0; i < 4; ++i) {
      const int r = (i << 5) + srow;
      const int ls = sslot ^ (r & 7);
      gload16(&As[buf][(i << 5) + (w << 3)][0], op.A + (size_t)grow[i] * K + k0 + (ls << 3));
      gload16(&Bs[buf][(i << 5) + (w << 3)][0], op.Bw + (size_t)(n0 + r) * K + k0 + (ls << 3));
    }
  };
  stage(0, 0);
  __syncthreads();
  for (int kt = 0; kt < KT; ++kt) {
    const int cur = kt & 1;
    if (kt + 1 < KT) stage(cur ^ 1, kt + 1);
    short8 af[4][2], bfr[4][2];
#pragma unroll
    for (int f = 0; f < 4; ++f) {
#pragma unroll
      for (int ks = 0; ks < 2; ++ks) {
        const int row = wr + (f << 4) + rr;
        const int kg = (ks << 2) + kgl;
        af[f][ks] = *(const short8*)&As[cur][row][(kg ^ (row & 7)) << 3];
        const int col = wc + (f << 4) + rr;
        bfr[f][ks] = *(const short8*)&Bs[cur][col][(kg ^ (col & 7)) << 3];
      }
    }
#pragma unroll
    for (int fi = 0; fi < 4; ++fi)
#pragma unroll
      for (int fj = 0; fj < 4; ++fj)
#pragma unroll
        for (int ks = 0; ks < 2; ++ks)
          acc[fi][fj] = __builtin_amdgcn_mfma_f32_16x16x32_bf16(
              af[fi][ks], bfr[fj][ks], acc[fi][fj], 0, 0, 0);
    __syncthreads();
  }
#pragma unroll
  for (int fi = 0; fi < 4; ++fi)
#pragma unroll
    for (int fj = 0; fj < 4; ++fj) {
      const int col = n0 + wc + (fj << 4) + rr;
#pragma unroll
      for (int r = 0; r < 4; ++r) {
        const int row = m0 + wr + (fi << 4) + (kgl << 2) + r;
        if (row >= cnt) continue;
        float v = acc[fi][fj][r];
        if (op.act) v = 0.5f * v * (1.0f + erff(v * 0.70710678118654752f));
        if (op.ep == 0) {
          op.outb[(size_t)row * F + col] = f2bf(v);
        } else if (op.ep == 1) {
          const size_t off = (size_t)row * F + col;
          const float sv = v / (1.0f + __expf(-v));
          op.outb[off] = f2bf(sv * bf2f(op.other[off]));
        } else {
          const int tok = op.gidx[row];
          atomicAdd(&moe[(size_t)tok * DIM + col], wts[(size_t)tok * 4 + op.expert] * v);
        }
      }
    }
}

// ---------------- fp16x2 split GEMM (3-term) ----------------
// EP: 1 = fp32: resid + masked(v); 3 = fused QKV epilogue (q/k planes + V^T planes)
template <int EP>
__global__ __launch_bounds__(256, 2) void gemm_split_k(
    const _Float16* __restrict__ Ah, const _Float16* __restrict__ Al,
    const _Float16* __restrict__ Bh, const _Float16* __restrict__ Bl,
    int K, int F,
    _Float16* __restrict__ Oh, _Float16* __restrict__ Ol, float oscale,
    const float* __restrict__ resid, float* __restrict__ outf,
    _Float16* __restrict__ K2h, _Float16* __restrict__ K2l,
    _Float16* __restrict__ V2h, _Float16* __restrict__ V2l) {
  __shared__ _Float16 AsH[2][128][32], AsL[2][128][32];
  __shared__ _Float16 BsH[2][128][32], BsL[2][128][32];
  const int tid = threadIdx.x;
  const int w = tid >> 6, lane = tid & 63;
  const int wr = ((w >> 1) << 6), wc = ((w & 1) << 6);
  int m0, n0;
  tile_swz(m0, n0);
  const int rr = lane & 15, kgl = lane >> 4;
  const int srow = tid >> 2, sslot = tid & 3;

  f32x4 acc[4][4];
#pragma unroll
  for (int a_ = 0; a_ < 4; ++a_)
#pragma unroll
    for (int b_ = 0; b_ < 4; ++b_) acc[a_][b_] = (f32x4){0.f, 0.f, 0.f, 0.f};

  const int KT = K >> 5;
  auto stage = [&](int buf, int kt) {
    const int k0 = kt << 5;
#pragma unroll
    for (int i = 0; i < 2; ++i) {
      const int r = (i << 6) + srow;
      const int ls = sslot ^ ((r >> 1) & 3);
      const size_t ga = (size_t)(m0 + r) * K + k0 + (ls << 3);
      const size_t gb = (size_t)(n0 + r) * K + k0 + (ls << 3);
      const int lr = (i << 6) + (w << 4);
      gload16(&AsH[buf][lr][0], Ah + ga);
      gload16(&AsL[buf][lr][0], Al + ga);
      gload16(&BsH[buf][lr][0], Bh + gb);
      gload16(&BsL[buf][lr][0], Bl + gb);
    }
  };
  stage(0, 0);
  __syncthreads();
  for (int kt = 0; kt < KT; ++kt) {
    const int cur = kt & 1;
    if (kt + 1 < KT) stage(cur ^ 1, kt + 1);
    half8 ah[4], al[4], bh[4], bl[4];
#pragma unroll
    for (int f = 0; f < 4; ++f) {
      const int row = wr + (f << 4) + rr;
      const int pa = (kgl ^ ((row >> 1) & 3)) << 3;
      ah[f] = *(const half8*)&AsH[cur][row][pa];
      al[f] = *(const half8*)&AsL[cur][row][pa];
      const int col = wc + (f << 4) + rr;
      const int pb = (kgl ^ ((col >> 1) & 3)) << 3;
      bh[f] = *(const half8*)&BsH[cur][col][pb];
      bl[f] = *(const half8*)&BsL[cur][col][pb];
    }
#pragma unroll
    for (int fi = 0; fi < 4; ++fi)
#pragma unroll
      for (int fj = 0; fj < 4; ++fj) {
        acc[fi][fj] = __builtin_amdgcn_mfma_f32_16x16x32_f16(ah[fi], bh[fj], acc[fi][fj], 0, 0, 0);
        acc[fi][fj] = __builtin_amdgcn_mfma_f32_16x16x32_f16(ah[fi], bl[fj], acc[fi][fj], 0, 0, 0);
        acc[fi][fj] = __builtin_amdgcn_mfma_f32_16x16x32_f16(al[fi], bh[fj], acc[fi][fj], 0, 0, 0);
      }
    __syncthreads();
  }
#pragma unroll
  for (int fi = 0; fi < 4; ++fi)
#pragma unroll
    for (int fj = 0; fj < 4; ++fj) {
      const int col = n0 + wc + (fj << 4) + rr;
      const int rowb = m0 + wr + (fi << 4) + (kgl << 2);
      if (EP == 3) {
        if (col < 2048) {
          _Float16* ph = (col < 1024) ? Oh : K2h;
          _Float16* pl = (col < 1024) ? Ol : K2l;
          const int c = col & 1023;
#pragma unroll
          for (int r = 0; r < 4; ++r) {
            const float v = acc[fi][fj][r] * oscale;
            const _Float16 hh2 = (_Float16)v;
            const size_t off = (size_t)(rowb + r) * DIM + c;
            ph[off] = hh2; pl[off] = (_Float16)(v - (float)hh2);
          }
        } else {
          const int c2 = col - 2048;
          half4 h4, l4;
#pragma unroll
          for (int r = 0; r < 4; ++r) {
            const float v = acc[fi][fj][r] * oscale;
            const _Float16 hh2 = (_Float16)v;
            h4[r] = hh2; l4[r] = (_Float16)(v - (float)hh2);
          }
          const size_t vt = ((size_t)((rowb >> 10) << 4) + (size_t)(c2 >> 6)) * 65536 +
                            (size_t)(c2 & 63) * 1024 + (size_t)(rowb & 1023);
          *(half4*)&V2h[vt] = h4;
          *(half4*)&V2l[vt] = l4;
        }
      } else {
#pragma unroll
        for (int r = 0; r < 4; ++r) {
          const size_t off = (size_t)(rowb + r) * F + col;
          const float v = acc[fi][fj][r] * oscale;
          outf[off] = resid[off] + (col >= MPROT ? v : 0.0f);
        }
      }
    }
}

// ---------------- flash attention, causal, fp16x2 split, swapped-QK ----------------
__global__ __launch_bounds__(256, 2) void attn_k(
    const _Float16* __restrict__ Qh, const _Float16* __restrict__ Ql,
    const _Float16* __restrict__ Kh, const _Float16* __restrict__ Kl,
    const _Float16* __restrict__ Vth, const _Float16* __restrict__ Vtl,
    _Float16* __restrict__ Oh, _Float16* __restrict__ Ol) {
  __shared__ _Float16 Ksh[2][32][64], Ksl[2][32][64];
  __shared__ _Float16 Vsh[2][64][40], Vsl[2][64][40];
  __shared__ _Float16 Plh[4][16][40], Pll[4][16][40];
  const int n = blockIdx.x;
  const int qt = n >> 6;
  const int bh = ((n & 7) << 3) | ((n >> 3) & 7);
  const int b = bh >> 4, h = bh & 15;
  const int tid = threadIdx.x, w = tid >> 6, lane = tid & 63;
  const int rr = lane & 15, rg = lane >> 4;
  const size_t tokbase = (size_t)b * TSEQ;
  const int hcol = h << 6;
  const size_t vtbase = (size_t)bh << 16;
  const int q0w = (qt << 7) + (w << 5);
  const float sscale = 0.125f / (SA * SA);

  half8 qfh[2][2], qfl[2][2];
#pragma unroll
  for (int qf = 0; qf < 2; ++qf)
#pragma unroll
    for (int ks = 0; ks < 2; ++ks) {
      const size_t off = (tokbase + q0w + (qf << 4) + rr) * DIM + hcol + (ks << 5) + (rg << 3);
      qfh[qf][ks] = *(const half8*)&Qh[off];
      qfl[qf][ks] = *(const half8*)&Ql[off];
    }

  f32x4 oacc[2][4];
#pragma unroll
  for (int qf = 0; qf < 2; ++qf)
#pragma unroll
    for (int dg = 0; dg < 4; ++dg) oacc[qf][dg] = (f32x4){0.f, 0.f, 0.f, 0.f};
  float mreg[2] = {-INFINITY, -INFINITY}, lreg[2] = {0.f, 0.f};

  const int kr = (w << 3) + (lane >> 3);
  const int kswz = ((lane & 7) ^ (kr & 7)) << 3;
  const int vr = tid >> 2;
  const int vs = (tid & 3) << 3;

  const int ntiles = (qt + 1) << 2;

  {
    gload16(&Ksh[0][w << 3][0], &Kh[(tokbase + kr) * DIM + hcol + kswz]);
    gload16(&Ksl[0][w << 3][0], &Kl[(tokbase + kr) * DIM + hcol + kswz]);
    const half8 vvh = *(const half8*)&Vth[vtbase + (size_t)vr * TSEQ + vs];
    const half8 vvl = *(const half8*)&Vtl[vtbase + (size_t)vr * TSEQ + vs];
    *(half8*)&Vsh[0][vr][vs] = vvh;
    *(half8*)&Vsl[0][vr][vs] = vvl;
    __syncthreads();
  }

  for (int t = 0; t < ntiles; ++t) {
    const int cur = t & 1;
    const int kv0 = t << 5;
    const bool havenext = (t + 1 < ntiles);
    half8 nvh, nvl;
    if (havenext) {
      const int kn = kv0 + 32;
      gload16(&Ksh[cur ^ 1][w << 3][0], &Kh[(tokbase + kn + kr) * DIM + hcol + kswz]);
      gload16(&Ksl[cur ^ 1][w << 3][0], &Kl[(tokbase + kn + kr) * DIM + hcol + kswz]);
      nvh = *(const half8*)&Vth[vtbase + (size_t)vr * TSEQ + kn + vs];
      nvl = *(const half8*)&Vtl[vtbase + (size_t)vr * TSEQ + kn + vs];
    }
    if (kv0 <= q0w + 31) {
      half8 kfh[2][2], kfl[2][2];
#pragma unroll
      for (int kt = 0; kt < 2; ++kt)
#pragma unroll
        for (int ks = 0; ks < 2; ++ks) {
          const int row = (kt << 4) + rr;
          const int sw = ((((ks << 2) + rg)) ^ (row & 7)) << 3;
          kfh[kt][ks] = *(const half8*)&Ksh[cur][row][sw];
          kfl[kt][ks] = *(const half8*)&Ksl[cur][row][sw];
        }
#pragma unroll
      for (int qf = 0; qf < 2; ++qf) {
        if (kv0 > q0w + (qf << 4) + 15) continue;
        f32x4 st[2];
        st[0] = (f32x4){0.f, 0.f, 0.f, 0.f};
        st[1] = (f32x4){0.f, 0.f, 0.f, 0.f};
#pragma unroll
        for (int kt = 0; kt < 2; ++kt)
#pragma unroll
          for (int ks = 0; ks < 2; ++ks) {
            st[kt] = __builtin_amdgcn_mfma_f32_16x16x32_f16(kfh[kt][ks], qfh[qf][ks], st[kt], 0, 0, 0);
            st[kt] = __builtin_amdgcn_mfma_f32_16x16x32_f16(kfh[kt][ks], qfl[qf][ks], st[kt], 0, 0, 0);
            st[kt] = __builtin_amdgcn_mfma_f32_16x16x32_f16(kfl[kt][ks], qfh[qf][ks], st[kt], 0, 0, 0);
          }
        const int qg = q0w + (qf << 4) + rr;
        float s[2][4]; float mx = -INFINITY;
#pragma unroll
        for (int kt = 0; kt < 2; ++kt)
#pragma unroll
          for (int r = 0; r < 4; ++r) {
            float sv = st[kt][r] * sscale;
            if (kv0 + (kt << 4) + (rg << 2) + r > qg) sv = -INFINITY;
            s[kt][r] = sv; mx = fmaxf(mx, sv);
          }
        mx = fmaxf(mx, __shfl_xor(mx, 16));
        mx = fmaxf(mx, __shfl_xor(mx, 32));
        const float mn = fmaxf(mreg[qf], mx);
        const float al = __expf(mreg[qf] - mn);
        mreg[qf] = mn;
        float p[2][4]; float rs = 0.f;
#pragma unroll
        for (int kt = 0; kt < 2; ++kt)
#pragma unroll
          for (int r = 0; r < 4; ++r) { p[kt][r] = __expf(s[kt][r] - mn); rs += p[kt][r]; }
        rs += __shfl_xor(rs, 16);
        rs += __shfl_xor(rs, 32);
        lreg[qf] = lreg[qf] * al + rs;
#pragma unroll
        for (int kt = 0; kt < 2; ++kt) {
          half4 h4, l4;
#pragma unroll
          for (int r = 0; r < 4; ++r) {
            const float pv = p[kt][r] * SPC;
            const _Float16 ph = (_Float16)pv;
            h4[r] = ph; l4[r] = (_Float16)(pv - (float)ph);
          }
          *(half4*)&Plh[w][rr][(kt << 4) + (rg << 2)] = h4;
          *(half4*)&Pll[w][rr][(kt << 4) + (rg << 2)] = l4;
        }
        float alr[4];
#pragma unroll
        for (int r = 0; r < 4; ++r) alr[r] = __shfl(al, (lane & 48) | ((rg << 2) + r));
#pragma unroll
        for (int dg = 0; dg < 4; ++dg)
#pragma unroll
          for (int r = 0; r < 4; ++r) oacc[qf][dg][r] *= alr[r];
        const half8 pah = *(const half8*)&Plh[w][rr][rg << 3];
        const half8 pal = *(const half8*)&Pll[w][rr][rg << 3];
#pragma unroll
        for (int dg = 0; dg < 4; ++dg) {
          const half8 vfh2 = *(const half8*)&Vsh[cur][(dg << 4) + rr][rg << 3];
          const half8 vfl2 = *(const half8*)&Vsl[cur][(dg << 4) + rr][rg << 3];
          oacc[qf][dg] = __builtin_amdgcn_mfma_f32_16x16x32_f16(pah, vfh2, oacc[qf][dg], 0, 0, 0);
          oacc[qf][dg] = __builtin_amdgcn_mfma_f32_16x16x32_f16(pah, vfl2, oacc[qf][dg], 0, 0, 0);
          oacc[qf][dg] = __builtin_amdgcn_mfma_f32_16x16x32_f16(pal, vfh2, oacc[qf][dg], 0, 0, 0);
        }
      }
    }
    if (havenext) {
      *(half8*)&Vsh[cur ^ 1][vr][vs] = nvh;
      *(half8*)&Vsl[cur ^ 1][vr][vs] = nvl;
    }
    __syncthreads();
  }
#pragma unroll
  for (int qf = 0; qf < 2; ++qf) {
    float li[4];
#pragma unroll
    for (int r = 0; r < 4; ++r)
      li[r] = __shfl(lreg[qf], (lane & 48) | ((rg << 2) + r));
#pragma unroll
    for (int dg = 0; dg < 4; ++dg)
#pragma unroll
      for (int r = 0; r < 4; ++r) {
        const int qloc = (rg << 2) + r;
        const float ov = oacc[qf][dg][r] / (li[r] * SPC);
        const _Float16 hh2 = (_Float16)ov;
        const size_t off = (tokbase + q0w + (qf << 4) + qloc) * DIM + hcol + (dg << 4) + rr;
        Oh[off] = hh2;
        Ol[off] = (_Float16)(ov - (float)hh2);
      }
  }
}

// ---------------- final combine: outp += mask(moe) ----------------
__global__ __launch_bounds__(256) void comb_k(float* __restrict__ outp,
                                              const float* __restrict__ moe) {
  const size_t i = (size_t)blockIdx.x * 256 + threadIdx.x;
  const int c4 = (int)(i & 255);
  if (c4 >= 64) {
    float4 o = ((float4*)outp)[i];
    const float4 m = ((const float4*)moe)[i];
    o.x += m.x; o.y += m.y; o.z += m.z; o.w += m.w;
    ((float4*)outp)[i] = o;
  }
}

extern "C" void kernel_launch(void* const* d_in, const int* in_sizes, int n_in,
                              void* d_out, int out_size, void* d_ws, size_t ws_size,
                              hipStream_t stream) {
  (void)in_sizes; (void)n_in; (void)out_size; (void)ws_size;
  const float* x    = (const float*)d_in[0];
  const float* n1w  = (const float*)d_in[1];
  const float* n2w  = (const float*)d_in[2];
  const float* wq   = (const float*)d_in[3];
  const float* wk   = (const float*)d_in[4];
  const float* wv   = (const float*)d_in[5];
  const float* wo   = (const float*)d_in[6];
  const float* qnw  = (const float*)d_in[7];
  const float* knw  = (const float*)d_in[8];
  const float* gw   = (const float*)d_in[9];
  const float* moesrc[12] = {
    (const float*)d_in[10], (const float*)d_in[11],
    (const float*)d_in[12], (const float*)d_in[13], (const float*)d_in[14],
    (const float*)d_in[15], (const float*)d_in[16], (const float*)d_in[17], (const float*)d_in[18],
    (const float*)d_in[19], (const float*)d_in[20], (const float*)d_in[21]
  };
  float* outp = (float*)d_out;

  char* p = (char*)d_ws;
  auto alloc = [&](size_t bytes) { void* r = (void*)p; p += (bytes + 255) & ~(size_t)255; return r; };
  const size_t NC = (size_t)NTOK * DIM;
  _Float16* hh = (_Float16*)alloc(NC * 2);
  _Float16* hl = (_Float16*)alloc(NC * 2);
  _Float16* qh = (_Float16*)alloc(NC * 2);   // qh..vtl: 48 MB contiguous, reused as MoE arena
  _Float16* ql = (_Float16*)alloc(NC * 2);
  _Float16* kh = (_Float16*)alloc(NC * 2);
  _Float16* kl = (_Float16*)alloc(NC * 2);
  _Float16* vth = (_Float16*)alloc(NC * 2);
  _Float16* vtl = (_Float16*)alloc(NC * 2);
  unsigned short* xfb = (unsigned short*)alloc(NC * 2);
  float* moe = (float*)alloc(NC * 4);
  float* wts = (float*)alloc((size_t)NTOK * 4 * 4);
  _Float16* awh = (_Float16*)alloc((size_t)4 * 1024 * 1024 * 2);
  _Float16* awl = (_Float16*)alloc((size_t)4 * 1024 * 1024 * 2);
  unsigned short* moeW = (unsigned short*)alloc((size_t)28311552 * 2);
  int* idxE = (int*)alloc((size_t)4 * 4096 * 4);
  int* cnts = (int*)alloc(256);
  // MoE intermediate arena: alias dead q/k/v planes + fresh tail
  unsigned short* e0t = (unsigned short*)qh;    // 16 MB (qh+ql)
  unsigned short* e1a = (unsigned short*)kh;    // 16 MB (kh+kl)
  unsigned short* e2a = (unsigned short*)vth;   // 16 MB (vth+vtl), reused as e2c
  unsigned short* e1b = (unsigned short*)alloc((size_t)NTOK * 2048 * 2);
  unsigned short* e2b = (unsigned short*)alloc((size_t)NTOK * 2048 * 2);
  unsigned short* e3a = (unsigned short*)alloc((size_t)NTOK * 1024 * 2);
  unsigned short* e3b = (unsigned short*)alloc((size_t)NTOK * 2048 * 2);
  unsigned short* e2c = e2a;

  const size_t moff[12] = {0, 2097152, 4194304, 6291456, 8388608, 10485760,
                           12582912, 16777216, 20971520, 23068672, 24117248, 26214400};
  auto mw = [&](int i) -> const unsigned short* { return moeW + moff[i]; };

  // ---- weight conversions ----
  cvt_attn4_k<<<dim3(1024, 4), dim3(256), 0, stream>>>(wq, wk, wv, wo, awh, awl);
  cvt_moe_all_k<<<dim3(4096, 12), dim3(256), 0, stream>>>(
      moesrc[0], moesrc[1], moesrc[2], moesrc[3], moesrc[4], moesrc[5],
      moesrc[6], moesrc[7], moesrc[8], moesrc[9], moesrc[10], moesrc[11], moeW);
  const _Float16* woh = awh + (3 << 20); const _Float16* wol = awl + (3 << 20);

  // ---- attention path (fp16x2) ----
  rms_split_k<<<dim3(NTOK), dim3(256), 0, stream>>>(x, n1w, hh, hl);
  gemm_split_k<3><<<dim3(24, 32), dim3(256), 0, stream>>>(
      hh, hl, awh, awl, 1024, 3072, qh, ql, 1.0f / SW, nullptr, nullptr,
      kh, kl, vth, vtl);
  qknorm2_k<<<dim3(NTOK * NHEAD / 4, 2), dim3(256), 0, stream>>>(qh, ql, kh, kl, qnw, knw);
  attn_k<<<dim3(512), dim3(256), 0, stream>>>(qh, ql, kh, kl, vth, vtl, hh, hl);
  gemm_split_k<1><<<dim3(8, 32), dim3(256), 0, stream>>>(
      hh, hl, woh, wol, 1024, 1024, nullptr, nullptr, 1.0f / (SA * SW), x, outp,
      nullptr, nullptr, nullptr, nullptr);

  // ---- MoE (sparse top-2, grouped phases) ----
  rmsgate_k<<<dim3(NTOK), dim3(256), 0, stream>>>(outp, n2w, gw, xfb, wts, moe);
  route_k<<<dim3(4), dim3(256), 0, stream>>>(wts, idxE, cnts);

  const int* g0 = idxE;           const int* g1 = idxE + 4096;
  const int* g2 = idxE + 8192;    const int* g3 = idxE + 12288;

  auto mk = [&](const unsigned short* A, const unsigned short* B, unsigned short* outb,
                const unsigned short* other, const int* gidx, int K, int nbn,
                int act, int ep, int gath, int expert) {
    SubOp s; s.A = A; s.Bw = B; s.outb = outb; s.other = other; s.gidx = gidx;
    s.K = K; s.nbn = nbn; s.act = act; s.ep = ep; s.gath = gath; s.expert = expert;
    return s;
  };

  Phase4 pa;
  pa.op[0] = mk(xfb, mw(0), e0t, nullptr, g0, 1024, 16, 1, 0, 1, 0);  // e0: gelu(x@up)
  pa.op[1] = mk(xfb, mw(3), e1a, nullptr, g1, 1024, 16, 0, 0, 1, 1);  // e1: x@w2 (raw)
  pa.op[2] = mk(xfb, mw(5), e2a, nullptr, g2, 1024, 16, 1, 0, 1, 2);  // e2: gelu(x@l1)
  pa.op[3] = mk(xfb, mw(9), e3a, nullptr, g3, 1024,  8, 1, 0, 1, 3);  // e3: gelu(x@dn)
  gemm_group_k<<<dim3(16, 32, 4), dim3(256), 0, stream>>>(pa, cnts, wts, moe);

  Phase4 pb;
  pb.op[0] = mk(e0t, mw(1), nullptr, nullptr, g0, 2048,  8, 0, 2, 0, 0);  // e0 down -> moe
  pb.op[1] = mk(xfb, mw(2), e1b, e1a, g1, 1024, 16, 0, 1, 1, 1);          // e1: silu(x@w1)*e1a
  pb.op[2] = mk(e2a, mw(6), e2b, nullptr, g2, 2048, 16, 1, 0, 0, 2);      // e2: gelu(@l2)
  pb.op[3] = mk(e3a, mw(10), e3b, nullptr, g3, 1024, 16, 1, 0, 0, 3);     // e3: gelu(@up)
  gemm_group_k<<<dim3(16, 32, 4), dim3(256), 0, stream>>>(pb, cnts, wts, moe);

  Phase4 pc;
  pc.op[0] = mk(e1b, mw(4), nullptr, nullptr, g1, 2048,  8, 0, 2, 0, 1);  // e1 down -> moe
  pc.op[1] = mk(e2b, mw(7), e2c, nullptr, g2, 2048, 16, 1, 0, 0, 2);      // e2: gelu(@l3)
  pc.op[2] = mk(e3b, mw(11), nullptr, nullptr, g3, 2048,  8, 0, 2, 0, 3); // e3 out -> moe
  pc.op[3] = pc.op[0];  // unused (grid z = 3)
  gemm_group_k<<<dim3(16, 32, 3), dim3(256), 0, stream>>>(pc, cnts, wts, moe);

  Phase4 pd;
  pd.op[0] = mk(e2c, mw(8), nullptr, nullptr, g2, 2048, 8, 0, 2, 0, 2);   // e2 l4 -> moe
  pd.op[1] = pd.op[0]; pd.op[2] = pd.op[0]; pd.op[3] = pd.op[0];
  gemm_group_k<<<dim3(8, 32, 1), dim3(256), 0, stream>>>(pd, cnts, wts, moe);

  comb_k<<<dim3(4096), dim3(256), 0, stream>>>(outp, moe);
}

// Round 6
// 645.555 us; speedup vs baseline: 1.2885x; 1.1495x over previous
//
#include <hip/hip_runtime.h>
#include <math.h>

#define DIM   1024
#define NTOK  4096
#define TSEQ  1024
#define NHEAD 16
#define MPROT 256
#define EPSR  1.1920929e-07f
#define SA    64.0f
#define SW    256.0f
#define SPC   64.0f

typedef __attribute__((ext_vector_type(8))) short          short8;
typedef __attribute__((ext_vector_type(8))) _Float16       half8;
typedef __attribute__((ext_vector_type(4))) _Float16       half4;
typedef __attribute__((ext_vector_type(4))) float          f32x4;
typedef __attribute__((ext_vector_type(4))) unsigned short us4;

static __device__ __forceinline__ float bf2f(unsigned short s) {
  union { unsigned int u; float f; } c; c.u = ((unsigned int)s) << 16; return c.f;
}
static __device__ __forceinline__ unsigned short f2bf(float f) {
  union { float f; unsigned int u; } c; c.f = f;
  return (unsigned short)((c.u + 0x7fffu + ((c.u >> 16) & 1u)) >> 16);
}
static __device__ __forceinline__ void gload16(void* lds, const void* g) {
  __builtin_amdgcn_global_load_lds(
      (__attribute__((address_space(1))) void*)const_cast<void*>(g),
      (__attribute__((address_space(3))) void*)lds, 16, 0, 0);
}

// XCD swizzle for dense split-GEMMs: stripe m-blocks across XCDs.
static __device__ __forceinline__ void tile_swz(int& m0, int& n0) {
  const int gx = gridDim.x;
  const int L = blockIdx.y * gx + blockIdx.x;
  const int xcd = L & 7;
  const int j = L >> 3;
  const int mbq = j / gx;
  const int nb = j - mbq * gx;
  m0 = ((mbq << 3) | xcd) << 7;
  n0 = nb << 7;
}

// ---------------- conversions ----------------
__global__ __launch_bounds__(256) void cvt_attn4_k(const float* __restrict__ wq,
                                                   const float* __restrict__ wk,
                                                   const float* __restrict__ wv,
                                                   const float* __restrict__ wo,
                                                   _Float16* __restrict__ dh,
                                                   _Float16* __restrict__ dl) {
  const int wi = blockIdx.y;
  const float* s = (wi == 0) ? wq : (wi == 1) ? wk : (wi == 2) ? wv : wo;
  const int i = blockIdx.x * 256 + threadIdx.x;
  const size_t off4 = ((size_t)wi << 20) >> 2;
  const float4 v = ((const float4*)s)[i];
  float a0 = v.x * SW, a1 = v.y * SW, a2 = v.z * SW, a3 = v.w * SW;
  half4 hv, lv;
  _Float16 h0 = (_Float16)a0; hv[0] = h0; lv[0] = (_Float16)(a0 - (float)h0);
  _Float16 h1 = (_Float16)a1; hv[1] = h1; lv[1] = (_Float16)(a1 - (float)h1);
  _Float16 h2 = (_Float16)a2; hv[2] = h2; lv[2] = (_Float16)(a2 - (float)h2);
  _Float16 h3 = (_Float16)a3; hv[3] = h3; lv[3] = (_Float16)(a3 - (float)h3);
  ((half4*)dh)[off4 + i] = hv; ((half4*)dl)[off4 + i] = lv;
}

__global__ __launch_bounds__(256) void cvt_moe_all_k(
    const float* s0, const float* s1, const float* s2, const float* s3,
    const float* s4, const float* s5, const float* s6, const float* s7,
    const float* s8, const float* s9, const float* s10, const float* s11,
    unsigned short* __restrict__ dst) {
  const int n4tab[12] = {524288, 524288, 524288, 524288, 524288, 524288,
                         1048576, 1048576, 524288, 262144, 524288, 524288};
  const size_t offtab[12] = {0, 2097152, 4194304, 6291456, 8388608, 10485760,
                             12582912, 16777216, 20971520, 23068672, 24117248, 26214400};
  const int wi = blockIdx.y;
  const int i = blockIdx.x * 256 + threadIdx.x;
  if (i >= n4tab[wi]) return;
  const float* s;
  switch (wi) {
    case 0: s = s0; break; case 1: s = s1; break; case 2: s = s2; break;
    case 3: s = s3; break; case 4: s = s4; break; case 5: s = s5; break;
    case 6: s = s6; break; case 7: s = s7; break; case 8: s = s8; break;
    case 9: s = s9; break; case 10: s = s10; break; default: s = s11; break;
  }
  const float4 v = ((const float4*)s)[i];
  us4 o; o[0] = f2bf(v.x); o[1] = f2bf(v.y); o[2] = f2bf(v.z); o[3] = f2bf(v.w);
  ((us4*)(dst + offtab[wi]))[i] = o;
}

// ---------------- RMS norms ----------------
__global__ __launch_bounds__(256) void rms_split_k(const float* __restrict__ in,
                                                   const float* __restrict__ wgt,
                                                   _Float16* __restrict__ oh,
                                                   _Float16* __restrict__ ol) {
  const int row = blockIdx.x, tid = threadIdx.x;
  const float4 v = ((const float4*)(in + (size_t)row * DIM))[tid];
  float ss = v.x * v.x + v.y * v.y + v.z * v.z + v.w * v.w;
#pragma unroll
  for (int o = 32; o; o >>= 1) ss += __shfl_xor(ss, o);
  __shared__ float red[4];
  if ((tid & 63) == 0) red[tid >> 6] = ss;
  __syncthreads();
  const float sc = rsqrtf((red[0] + red[1] + red[2] + red[3]) * (1.0f / DIM) + EPSR) * SA;
  const float4 wv = ((const float4*)wgt)[tid];
  float a[4] = {v.x * sc * wv.x, v.y * sc * wv.y, v.z * sc * wv.z, v.w * sc * wv.w};
  half4 hv, lv;
#pragma unroll
  for (int j = 0; j < 4; ++j) {
    _Float16 hh = (_Float16)a[j]; hv[j] = hh; lv[j] = (_Float16)(a[j] - (float)hh);
  }
  ((half4*)(oh + (size_t)row * DIM))[tid] = hv;
  ((half4*)(ol + (size_t)row * DIM))[tid] = lv;
}

// fused RMSNorm(bf16 out) + gate logits/softmax/top-2 + moe buffer zeroing
__global__ __launch_bounds__(256) void rmsgate_k(const float* __restrict__ x2,
                                                 const float* __restrict__ n2w,
                                                 const float* __restrict__ gw,
                                                 unsigned short* __restrict__ xfb,
                                                 float* __restrict__ wts,
                                                 float* __restrict__ moe) {
  const int row = blockIdx.x, tid = threadIdx.x;
  ((float4*)(moe + (size_t)row * DIM))[tid] = (float4){0.f, 0.f, 0.f, 0.f};
  const float4 v = ((const float4*)(x2 + (size_t)row * DIM))[tid];
  float ss = v.x * v.x + v.y * v.y + v.z * v.z + v.w * v.w;
#pragma unroll
  for (int o = 32; o; o >>= 1) ss += __shfl_xor(ss, o);
  __shared__ float red[4];
  __shared__ float redE[4][4];
  const int w = tid >> 6, lane = tid & 63;
  if (lane == 0) red[w] = ss;
  __syncthreads();
  const float sc = rsqrtf((red[0] + red[1] + red[2] + red[3]) * (1.0f / DIM) + EPSR);
  const float4 nw = ((const float4*)n2w)[tid];
  const float xn0 = v.x * sc * nw.x, xn1 = v.y * sc * nw.y;
  const float xn2 = v.z * sc * nw.z, xn3 = v.w * sc * nw.w;
  us4 ob; ob[0] = f2bf(xn0); ob[1] = f2bf(xn1); ob[2] = f2bf(xn2); ob[3] = f2bf(xn3);
  ((us4*)(xfb + (size_t)row * DIM))[tid] = ob;
#pragma unroll
  for (int e = 0; e < 4; ++e) {
    const float4 g = ((const float4*)(gw + (size_t)e * DIM))[tid];
    float d = xn0 * g.x + xn1 * g.y + xn2 * g.z + xn3 * g.w;
#pragma unroll
    for (int o = 32; o; o >>= 1) d += __shfl_xor(d, o);
    if (lane == 0) redE[w][e] = d;
  }
  __syncthreads();
  if (tid == 0) {
    float lg[4];
#pragma unroll
    for (int e = 0; e < 4; ++e) lg[e] = redE[0][e] + redE[1][e] + redE[2][e] + redE[3][e];
    const float mx = fmaxf(fmaxf(lg[0], lg[1]), fmaxf(lg[2], lg[3]));
    float pe[4]; float sum = 0.0f;
#pragma unroll
    for (int e = 0; e < 4; ++e) { pe[e] = __expf(lg[e] - mx); sum += pe[e]; }
#pragma unroll
    for (int e = 0; e < 4; ++e) pe[e] /= sum;
    int i1 = 0;
    for (int e = 1; e < 4; ++e) if (pe[e] > pe[i1]) i1 = e;
    int i2 = -1;
    for (int e = 0; e < 4; ++e) { if (e == i1) continue; if (i2 < 0 || pe[e] > pe[i2]) i2 = e; }
    const float s2 = pe[i1] + pe[i2] + 1e-8f;
    float o[4] = {0.f, 0.f, 0.f, 0.f};
    o[i1] = pe[i1] / s2; o[i2] = pe[i2] / s2;
    float4 r; r.x = o[0]; r.y = o[1]; r.z = o[2]; r.w = o[3];
    *(float4*)(wts + (size_t)row * 4) = r;
  }
}

// per (token,head) RMS over 64 dims; y=0 -> Q planes, y=1 -> K planes
__global__ __launch_bounds__(256) void qknorm2_k(_Float16* __restrict__ qh,
                                                 _Float16* __restrict__ ql,
                                                 _Float16* __restrict__ kh,
                                                 _Float16* __restrict__ kl,
                                                 const float* __restrict__ qnw,
                                                 const float* __restrict__ knw) {
  _Float16* ph; _Float16* pl; const float* wgt;
  if (blockIdx.y == 0) { ph = qh; pl = ql; wgt = qnw; }
  else { ph = kh; pl = kl; wgt = knw; }
  const int idx = (blockIdx.x << 2) + (threadIdx.x >> 6);
  const int lane = threadIdx.x & 63;
  const size_t off = ((size_t)idx << 6) + lane;
  const float v = (float)ph[off] + (float)pl[off];
  float ss = v * v;
#pragma unroll
  for (int o = 32; o; o >>= 1) ss += __shfl_xor(ss, o);
  const float sc = rsqrtf(ss * (1.0f / (64.0f * SA * SA)) + EPSR);
  const float nv = v * sc * wgt[lane];
  _Float16 hh = (_Float16)nv;
  ph[off] = hh; pl[off] = (_Float16)(nv - (float)hh);
}

// ---------------- packed-slab routing: one ordered list, 128-padded slabs ----------------
// idxP[prow] = token or -1 (pad); meta[0..71] = mb->expert (-1 none); meta[80+e] = slab base row
__global__ __launch_bounds__(256) void route2_k(const float* __restrict__ wts,
                                                int* __restrict__ idxP,
                                                int* __restrict__ meta) {
  const int tid = threadIdx.x, w = tid >> 6, lane = tid & 63;
  __shared__ int wsum[4];
  __shared__ int baseS;
  int off = 0;
  for (int e = 0; e < 4; ++e) {
    if (tid == 0) baseS = 0;
    __syncthreads();
    for (int c = 0; c < 16; ++c) {
      const int tok = (c << 8) + tid;
      const bool pred = wts[(size_t)tok * 4 + e] > 0.0f;
      const unsigned long long m = __ballot(pred);
      const int lanepre = __popcll(m & ((1ull << lane) - 1ull));
      if (lane == 0) wsum[w] = __popcll(m);
      __syncthreads();
      int wpre = 0;
#pragma unroll
      for (int i = 0; i < 4; ++i) wpre += (i < w) ? wsum[i] : 0;
      const int tot = wsum[0] + wsum[1] + wsum[2] + wsum[3];
      if (pred) idxP[off + baseS + wpre + lanepre] = tok;
      __syncthreads();
      if (tid == 0) baseS += tot;
      __syncthreads();
    }
    const int cnt = baseS;
    const int padded = (cnt + 127) & ~127;
    for (int j = cnt + tid; j < padded; j += 256) idxP[off + j] = -1;
    if (tid == 0) meta[80 + e] = off;
    const int mb0 = off >> 7, nmb = padded >> 7;
    for (int j = tid; j < nmb; j += 256) meta[mb0 + j] = e;
    off += padded;
    __syncthreads();
  }
  for (int j = (off >> 7) + tid; j < 72; j += 256) meta[j] = -1;
}

// ---------------- packed grouped sparse bf16 GEMM (m97-style single-buffer LDS) ----------------
struct SubOpP {
  const unsigned short* A;
  const unsigned short* Bw;
  unsigned short* outb;
  const unsigned short* other;
  int K, nbn, act, ep, gath;   // ep: 0 store, 1 silu*other, 2 scatter atomicAdd; nbn=0 -> absent
};
struct PhaseP { SubOpP op[4]; };  // indexed by expert

__global__ __launch_bounds__(256, 4) void gemm_moe_k(PhaseP ph,
                                                     const int* __restrict__ meta,
                                                     const int* __restrict__ idxP,
                                                     const float* __restrict__ wts,
                                                     float* __restrict__ moe) {
  __shared__ unsigned short As[128][64];
  __shared__ unsigned short Bs[128][64];
  // XCD stripe over packed (mb, nb) space; grid fixed (16, 72)
  const int L = blockIdx.y * 16 + blockIdx.x;
  const int xcd = L & 7;
  const int j = L >> 3;
  const int nb = j & 15;
  const int mb = ((j >> 4) << 3) | xcd;
  const int e = meta[mb];
  if (e < 0) return;
  SubOpP op;
  switch (e) {
    case 0: op = ph.op[0]; break;
    case 1: op = ph.op[1]; break;
    case 2: op = ph.op[2]; break;
    default: op = ph.op[3]; break;
  }
  if (op.nbn == 0 || nb >= op.nbn) return;
  const int m0p = mb << 7;                 // packed row base
  const int lr0 = m0p - meta[80 + e];      // local (compact) row base
  const int n0 = nb << 7;
  const int F = op.nbn << 7;
  const int K = op.K;
  const int tid = threadIdx.x;
  const int w = tid >> 6, lane = tid & 63;
  const int wr = ((w >> 1) << 6), wc = ((w & 1) << 6);
  const int rr = lane & 15, kgl = lane >> 4;
  const int srow = tid >> 3, sslot = tid & 7;

  int grow[4];
#pragma unroll
  for (int i = 0; i < 4; ++i) {
    const int r = (i << 5) + srow;
    if (op.gath) {
      const int t = idxP[m0p + r];
      grow[i] = (t < 0) ? 0 : t;
    } else {
      grow[i] = lr0 + r;
    }
  }

  f32x4 acc[4][4];
#pragma unroll
  for (int a_ = 0; a_ < 4; ++a_)
#pragma unroll
    for (int b_ = 0; b_ < 4; ++b_) acc[a_][b_] = (f32x4){0.f, 0.f, 0.f, 0.f};

  const int KT = K >> 6;
  for (int kt = 0; kt < KT; ++kt) {
    const int k0 = kt << 6;
#pragma unroll
    for (int i = 0; i < 4; ++i) {
      const int r = (i << 5) + srow;
      const int ls = sslot ^ (r & 7);
      gload16(&As[(i << 5) + (w << 3)][0], op.A + (size_t)grow[i] * K + k0 + (ls << 3));
      gload16(&Bs[(i << 5) + (w << 3)][0], op.Bw + (size_t)(n0 + r) * K + k0 + (ls << 3));
    }
    __syncthreads();
    short8 af[4][2], bfr[4][2];
#pragma unroll
    for (int f = 0; f < 4; ++f) {
#pragma unroll
      for (int ks = 0; ks < 2; ++ks) {
        const int row = wr + (f << 4) + rr;
        const int kg = (ks << 2) + kgl;
        af[f][ks] = *(const short8*)&As[row][(kg ^ (row & 7)) << 3];
        const int col = wc + (f << 4) + rr;
        bfr[f][ks] = *(const short8*)&Bs[col][(kg ^ (col & 7)) << 3];
      }
    }
#pragma unroll
    for (int fi = 0; fi < 4; ++fi)
#pragma unroll
      for (int fj = 0; fj < 4; ++fj)
#pragma unroll
        for (int ks = 0; ks < 2; ++ks)
          acc[fi][fj] = __builtin_amdgcn_mfma_f32_16x16x32_bf16(
              af[fi][ks], bfr[fj][ks], acc[fi][fj], 0, 0, 0);
    __syncthreads();
  }
#pragma unroll
  for (int fi = 0; fi < 4; ++fi)
#pragma unroll
    for (int fj = 0; fj < 4; ++fj) {
      const int col = n0 + wc + (fj << 4) + rr;
#pragma unroll
      for (int r = 0; r < 4; ++r) {
        const int rl = wr + (fi << 4) + (kgl << 2) + r;
        float v = acc[fi][fj][r];
        if (op.act) v = 0.5f * v * (1.0f + erff(v * 0.70710678118654752f));
        if (op.ep == 0) {
          op.outb[(size_t)(lr0 + rl) * F + col] = f2bf(v);
        } else if (op.ep == 1) {
          const size_t off = (size_t)(lr0 + rl) * F + col;
          const float sv = v / (1.0f + __expf(-v));
          op.outb[off] = f2bf(sv * bf2f(op.other[off]));
        } else {
          const int tok = idxP[m0p + rl];
          if (tok >= 0)
            atomicAdd(&moe[(size_t)tok * DIM + col], wts[(size_t)tok * 4 + e] * v);
        }
      }
    }
}

// ---------------- fp16x2 split GEMM (3-term) ----------------
// EP: 1 = fp32: resid + masked(v); 3 = fused QKV epilogue (q/k planes + V^T planes)
template <int EP>
__global__ __launch_bounds__(256, 2) void gemm_split_k(
    const _Float16* __restrict__ Ah, const _Float16* __restrict__ Al,
    const _Float16* __restrict__ Bh, const _Float16* __restrict__ Bl,
    int K, int F,
    _Float16* __restrict__ Oh, _Float16* __restrict__ Ol, float oscale,
    const float* __restrict__ resid, float* __restrict__ outf,
    _Float16* __restrict__ K2h, _Float16* __restrict__ K2l,
    _Float16* __restrict__ V2h, _Float16* __restrict__ V2l) {
  __shared__ _Float16 AsH[2][128][32], AsL[2][128][32];
  __shared__ _Float16 BsH[2][128][32], BsL[2][128][32];
  const int tid = threadIdx.x;
  const int w = tid >> 6, lane = tid & 63;
  const int wr = ((w >> 1) << 6), wc = ((w & 1) << 6);
  int m0, n0;
  tile_swz(m0, n0);
  const int rr = lane & 15, kgl = lane >> 4;
  const int srow = tid >> 2, sslot = tid & 3;

  f32x4 acc[4][4];
#pragma unroll
  for (int a_ = 0; a_ < 4; ++a_)
#pragma unroll
    for (int b_ = 0; b_ < 4; ++b_) acc[a_][b_] = (f32x4){0.f, 0.f, 0.f, 0.f};

  const int KT = K >> 5;
  auto stage = [&](int buf, int kt) {
    const int k0 = kt << 5;
#pragma unroll
    for (int i = 0; i < 2; ++i) {
      const int r = (i << 6) + srow;
      const int ls = sslot ^ ((r >> 1) & 3);
      const size_t ga = (size_t)(m0 + r) * K + k0 + (ls << 3);
      const size_t gb = (size_t)(n0 + r) * K + k0 + (ls << 3);
      const int lr = (i << 6) + (w << 4);
      gload16(&AsH[buf][lr][0], Ah + ga);
      gload16(&AsL[buf][lr][0], Al + ga);
      gload16(&BsH[buf][lr][0], Bh + gb);
      gload16(&BsL[buf][lr][0], Bl + gb);
    }
  };
  stage(0, 0);
  __syncthreads();
  for (int kt = 0; kt < KT; ++kt) {
    const int cur = kt & 1;
    if (kt + 1 < KT) stage(cur ^ 1, kt + 1);
    half8 ah[4], al[4], bh[4], bl[4];
#pragma unroll
    for (int f = 0; f < 4; ++f) {
      const int row = wr + (f << 4) + rr;
      const int pa = (kgl ^ ((row >> 1) & 3)) << 3;
      ah[f] = *(const half8*)&AsH[cur][row][pa];
      al[f] = *(const half8*)&AsL[cur][row][pa];
      const int col = wc + (f << 4) + rr;
      const int pb = (kgl ^ ((col >> 1) & 3)) << 3;
      bh[f] = *(const half8*)&BsH[cur][col][pb];
      bl[f] = *(const half8*)&BsL[cur][col][pb];
    }
#pragma unroll
    for (int fi = 0; fi < 4; ++fi)
#pragma unroll
      for (int fj = 0; fj < 4; ++fj) {
        acc[fi][fj] = __builtin_amdgcn_mfma_f32_16x16x32_f16(ah[fi], bh[fj], acc[fi][fj], 0, 0, 0);
        acc[fi][fj] = __builtin_amdgcn_mfma_f32_16x16x32_f16(ah[fi], bl[fj], acc[fi][fj], 0, 0, 0);
        acc[fi][fj] = __builtin_amdgcn_mfma_f32_16x16x32_f16(al[fi], bh[fj], acc[fi][fj], 0, 0, 0);
      }
    __syncthreads();
  }
#pragma unroll
  for (int fi = 0; fi < 4; ++fi)
#pragma unroll
    for (int fj = 0; fj < 4; ++fj) {
      const int col = n0 + wc + (fj << 4) + rr;
      const int rowb = m0 + wr + (fi << 4) + (kgl << 2);
      if (EP == 3) {
        if (col < 2048) {
          _Float16* ph = (col < 1024) ? Oh : K2h;
          _Float16* pl = (col < 1024) ? Ol : K2l;
          const int c = col & 1023;
#pragma unroll
          for (int r = 0; r < 4; ++r) {
            const float v = acc[fi][fj][r] * oscale;
            const _Float16 hh2 = (_Float16)v;
            const size_t off = (size_t)(rowb + r) * DIM + c;
            ph[off] = hh2; pl[off] = (_Float16)(v - (float)hh2);
          }
        } else {
          const int c2 = col - 2048;
          half4 h4, l4;
#pragma unroll
          for (int r = 0; r < 4; ++r) {
            const float v = acc[fi][fj][r] * oscale;
            const _Float16 hh2 = (_Float16)v;
            h4[r] = hh2; l4[r] = (_Float16)(v - (float)hh2);
          }
          const size_t vt = ((size_t)((rowb >> 10) << 4) + (size_t)(c2 >> 6)) * 65536 +
                            (size_t)(c2 & 63) * 1024 + (size_t)(rowb & 1023);
          *(half4*)&V2h[vt] = h4;
          *(half4*)&V2l[vt] = l4;
        }
      } else {
#pragma unroll
        for (int r = 0; r < 4; ++r) {
          const size_t off = (size_t)(rowb + r) * F + col;
          const float v = acc[fi][fj][r] * oscale;
          outf[off] = resid[off] + (col >= MPROT ? v : 0.0f);
        }
      }
    }
}

// ---------------- flash attention, causal, fp16x2 split, swapped-QK ----------------
__global__ __launch_bounds__(256, 2) void attn_k(
    const _Float16* __restrict__ Qh, const _Float16* __restrict__ Ql,
    const _Float16* __restrict__ Kh, const _Float16* __restrict__ Kl,
    const _Float16* __restrict__ Vth, const _Float16* __restrict__ Vtl,
    _Float16* __restrict__ Oh, _Float16* __restrict__ Ol) {
  __shared__ _Float16 Ksh[2][32][64], Ksl[2][32][64];
  __shared__ _Float16 Vsh[2][64][40], Vsl[2][64][40];
  __shared__ _Float16 Plh[4][16][40], Pll[4][16][40];
  const int n = blockIdx.x;
  const int qt = n >> 6;
  const int bh = ((n & 7) << 3) | ((n >> 3) & 7);
  const int b = bh >> 4, h = bh & 15;
  const int tid = threadIdx.x, w = tid >> 6, lane = tid & 63;
  const int rr = lane & 15, rg = lane >> 4;
  const size_t tokbase = (size_t)b * TSEQ;
  const int hcol = h << 6;
  const size_t vtbase = (size_t)bh << 16;
  const int q0w = (qt << 7) + (w << 5);
  const float sscale = 0.125f / (SA * SA);

  half8 qfh[2][2], qfl[2][2];
#pragma unroll
  for (int qf = 0; qf < 2; ++qf)
#pragma unroll
    for (int ks = 0; ks < 2; ++ks) {
      const size_t off = (tokbase + q0w + (qf << 4) + rr) * DIM + hcol + (ks << 5) + (rg << 3);
      qfh[qf][ks] = *(const half8*)&Qh[off];
      qfl[qf][ks] = *(const half8*)&Ql[off];
    }

  f32x4 oacc[2][4];
#pragma unroll
  for (int qf = 0; qf < 2; ++qf)
#pragma unroll
    for (int dg = 0; dg < 4; ++dg) oacc[qf][dg] = (f32x4){0.f, 0.f, 0.f, 0.f};
  float mreg[2] = {-INFINITY, -INFINITY}, lreg[2] = {0.f, 0.f};

  const int kr = (w << 3) + (lane >> 3);
  const int kswz = ((lane & 7) ^ (kr & 7)) << 3;
  const int vr = tid >> 2;
  const int vs = (tid & 3) << 3;

  const int ntiles = (qt + 1) << 2;

  {
    gload16(&Ksh[0][w << 3][0], &Kh[(tokbase + kr) * DIM + hcol + kswz]);
    gload16(&Ksl[0][w << 3][0], &Kl[(tokbase + kr) * DIM + hcol + kswz]);
    const half8 vvh = *(const half8*)&Vth[vtbase + (size_t)vr * TSEQ + vs];
    const half8 vvl = *(const half8*)&Vtl[vtbase + (size_t)vr * TSEQ + vs];
    *(half8*)&Vsh[0][vr][vs] = vvh;
    *(half8*)&Vsl[0][vr][vs] = vvl;
    __syncthreads();
  }

  for (int t = 0; t < ntiles; ++t) {
    const int cur = t & 1;
    const int kv0 = t << 5;
    const bool havenext = (t + 1 < ntiles);
    half8 nvh, nvl;
    if (havenext) {
      const int kn = kv0 + 32;
      gload16(&Ksh[cur ^ 1][w << 3][0], &Kh[(tokbase + kn + kr) * DIM + hcol + kswz]);
      gload16(&Ksl[cur ^ 1][w << 3][0], &Kl[(tokbase + kn + kr) * DIM + hcol + kswz]);
      nvh = *(const half8*)&Vth[vtbase + (size_t)vr * TSEQ + kn + vs];
      nvl = *(const half8*)&Vtl[vtbase + (size_t)vr * TSEQ + kn + vs];
    }
    if (kv0 <= q0w + 31) {
      half8 kfh[2][2], kfl[2][2];
#pragma unroll
      for (int kt = 0; kt < 2; ++kt)
#pragma unroll
        for (int ks = 0; ks < 2; ++ks) {
          const int row = (kt << 4) + rr;
          const int sw = ((((ks << 2) + rg)) ^ (row & 7)) << 3;
          kfh[kt][ks] = *(const half8*)&Ksh[cur][row][sw];
          kfl[kt][ks] = *(const half8*)&Ksl[cur][row][sw];
        }
#pragma unroll
      for (int qf = 0; qf < 2; ++qf) {
        if (kv0 > q0w + (qf << 4) + 15) continue;
        f32x4 st[2];
        st[0] = (f32x4){0.f, 0.f, 0.f, 0.f};
        st[1] = (f32x4){0.f, 0.f, 0.f, 0.f};
#pragma unroll
        for (int kt = 0; kt < 2; ++kt)
#pragma unroll
          for (int ks = 0; ks < 2; ++ks) {
            st[kt] = __builtin_amdgcn_mfma_f32_16x16x32_f16(kfh[kt][ks], qfh[qf][ks], st[kt], 0, 0, 0);
            st[kt] = __builtin_amdgcn_mfma_f32_16x16x32_f16(kfh[kt][ks], qfl[qf][ks], st[kt], 0, 0, 0);
            st[kt] = __builtin_amdgcn_mfma_f32_16x16x32_f16(kfl[kt][ks], qfh[qf][ks], st[kt], 0, 0, 0);
          }
        const int qg = q0w + (qf << 4) + rr;
        float s[2][4]; float mx = -INFINITY;
#pragma unroll
        for (int kt = 0; kt < 2; ++kt)
#pragma unroll
          for (int r = 0; r < 4; ++r) {
            float sv = st[kt][r] * sscale;
            if (kv0 + (kt << 4) + (rg << 2) + r > qg) sv = -INFINITY;
            s[kt][r] = sv; mx = fmaxf(mx, sv);
          }
        mx = fmaxf(mx, __shfl_xor(mx, 16));
        mx = fmaxf(mx, __shfl_xor(mx, 32));
        const float mn = fmaxf(mreg[qf], mx);
        const float al = __expf(mreg[qf] - mn);
        mreg[qf] = mn;
        float p[2][4]; float rs = 0.f;
#pragma unroll
        for (int kt = 0; kt < 2; ++kt)
#pragma unroll
          for (int r = 0; r < 4; ++r) { p[kt][r] = __expf(s[kt][r] - mn); rs += p[kt][r]; }
        rs += __shfl_xor(rs, 16);
        rs += __shfl_xor(rs, 32);
        lreg[qf] = lreg[qf] * al + rs;
#pragma unroll
        for (int kt = 0; kt < 2; ++kt) {
          half4 h4, l4;
#pragma unroll
          for (int r = 0; r < 4; ++r) {
            const float pv = p[kt][r] * SPC;
            const _Float16 ph = (_Float16)pv;
            h4[r] = ph; l4[r] = (_Float16)(pv - (float)ph);
          }
          *(half4*)&Plh[w][rr][(kt << 4) + (rg << 2)] = h4;
          *(half4*)&Pll[w][rr][(kt << 4) + (rg << 2)] = l4;
        }
        float alr[4];
#pragma unroll
        for (int r = 0; r < 4; ++r) alr[r] = __shfl(al, (lane & 48) | ((rg << 2) + r));
#pragma unroll
        for (int dg = 0; dg < 4; ++dg)
#pragma unroll
          for (int r = 0; r < 4; ++r) oacc[qf][dg][r] *= alr[r];
        const half8 pah = *(const half8*)&Plh[w][rr][rg << 3];
        const half8 pal = *(const half8*)&Pll[w][rr][rg << 3];
#pragma unroll
        for (int dg = 0; dg < 4; ++dg) {
          const half8 vfh2 = *(const half8*)&Vsh[cur][(dg << 4) + rr][rg << 3];
          const half8 vfl2 = *(const half8*)&Vsl[cur][(dg << 4) + rr][rg << 3];
          oacc[qf][dg] = __builtin_amdgcn_mfma_f32_16x16x32_f16(pah, vfh2, oacc[qf][dg], 0, 0, 0);
          oacc[qf][dg] = __builtin_amdgcn_mfma_f32_16x16x32_f16(pah, vfl2, oacc[qf][dg], 0, 0, 0);
          oacc[qf][dg] = __builtin_amdgcn_mfma_f32_16x16x32_f16(pal, vfh2, oacc[qf][dg], 0, 0, 0);
        }
      }
    }
    if (havenext) {
      *(half8*)&Vsh[cur ^ 1][vr][vs] = nvh;
      *(half8*)&Vsl[cur ^ 1][vr][vs] = nvl;
    }
    __syncthreads();
  }
#pragma unroll
  for (int qf = 0; qf < 2; ++qf) {
    float li[4];
#pragma unroll
    for (int r = 0; r < 4; ++r)
      li[r] = __shfl(lreg[qf], (lane & 48) | ((rg << 2) + r));
#pragma unroll
    for (int dg = 0; dg < 4; ++dg)
#pragma unroll
      for (int r = 0; r < 4; ++r) {
        const int qloc = (rg << 2) + r;
        const float ov = oacc[qf][dg][r] / (li[r] * SPC);
        const _Float16 hh2 = (_Float16)ov;
        const size_t off = (tokbase + q0w + (qf << 4) + qloc) * DIM + hcol + (dg << 4) + rr;
        Oh[off] = hh2;
        Ol[off] = (_Float16)(ov - (float)hh2);
      }
  }
}

// ---------------- final combine: outp += mask(moe) ----------------
__global__ __launch_bounds__(256) void comb_k(float* __restrict__ outp,
                                              const float* __restrict__ moe) {
  const size_t i = (size_t)blockIdx.x * 256 + threadIdx.x;
  const int c4 = (int)(i & 255);
  if (c4 >= 64) {
    float4 o = ((float4*)outp)[i];
    const float4 m = ((const float4*)moe)[i];
    o.x += m.x; o.y += m.y; o.z += m.z; o.w += m.w;
    ((float4*)outp)[i] = o;
  }
}

extern "C" void kernel_launch(void* const* d_in, const int* in_sizes, int n_in,
                              void* d_out, int out_size, void* d_ws, size_t ws_size,
                              hipStream_t stream) {
  (void)in_sizes; (void)n_in; (void)out_size; (void)ws_size;
  const float* x    = (const float*)d_in[0];
  const float* n1w  = (const float*)d_in[1];
  const float* n2w  = (const float*)d_in[2];
  const float* wq   = (const float*)d_in[3];
  const float* wk   = (const float*)d_in[4];
  const float* wv   = (const float*)d_in[5];
  const float* wo   = (const float*)d_in[6];
  const float* qnw  = (const float*)d_in[7];
  const float* knw  = (const float*)d_in[8];
  const float* gw   = (const float*)d_in[9];
  const float* moesrc[12] = {
    (const float*)d_in[10], (const float*)d_in[11],
    (const float*)d_in[12], (const float*)d_in[13], (const float*)d_in[14],
    (const float*)d_in[15], (const float*)d_in[16], (const float*)d_in[17], (const float*)d_in[18],
    (const float*)d_in[19], (const float*)d_in[20], (const float*)d_in[21]
  };
  float* outp = (float*)d_out;

  char* p = (char*)d_ws;
  auto alloc = [&](size_t bytes) { void* r = (void*)p; p += (bytes + 255) & ~(size_t)255; return r; };
  const size_t NC = (size_t)NTOK * DIM;
  _Float16* hh = (_Float16*)alloc(NC * 2);
  _Float16* hl = (_Float16*)alloc(NC * 2);
  _Float16* qh = (_Float16*)alloc(NC * 2);   // qh..vtl: 48 MB contiguous, reused as MoE arena
  _Float16* ql = (_Float16*)alloc(NC * 2);
  _Float16* kh = (_Float16*)alloc(NC * 2);
  _Float16* kl = (_Float16*)alloc(NC * 2);
  _Float16* vth = (_Float16*)alloc(NC * 2);
  _Float16* vtl = (_Float16*)alloc(NC * 2);
  unsigned short* xfb = (unsigned short*)alloc(NC * 2);
  float* moe = (float*)alloc(NC * 4);
  float* wts = (float*)alloc((size_t)NTOK * 4 * 4);
  _Float16* awh = (_Float16*)alloc((size_t)4 * 1024 * 1024 * 2);
  _Float16* awl = (_Float16*)alloc((size_t)4 * 1024 * 1024 * 2);
  unsigned short* moeW = (unsigned short*)alloc((size_t)28311552 * 2);
  int* idxP = (int*)alloc((size_t)9216 * 4);
  int* meta = (int*)alloc(512);
  // MoE intermediate arena: alias dead q/k/v planes + fresh tail
  unsigned short* e0t = (unsigned short*)qh;    // 16 MB (qh+ql)
  unsigned short* e1a = (unsigned short*)kh;    // 16 MB (kh+kl)
  unsigned short* e2a = (unsigned short*)vth;   // 16 MB (vth+vtl), reused as e2c
  unsigned short* e1b = (unsigned short*)alloc((size_t)NTOK * 2048 * 2);
  unsigned short* e2b = (unsigned short*)alloc((size_t)NTOK * 2048 * 2);
  unsigned short* e3a = (unsigned short*)alloc((size_t)NTOK * 1024 * 2);
  unsigned short* e3b = (unsigned short*)alloc((size_t)NTOK * 2048 * 2);
  unsigned short* e2c = e2a;

  const size_t moff[12] = {0, 2097152, 4194304, 6291456, 8388608, 10485760,
                           12582912, 16777216, 20971520, 23068672, 24117248, 26214400};
  auto mw = [&](int i) -> const unsigned short* { return moeW + moff[i]; };

  // ---- weight conversions ----
  cvt_attn4_k<<<dim3(1024, 4), dim3(256), 0, stream>>>(wq, wk, wv, wo, awh, awl);
  cvt_moe_all_k<<<dim3(4096, 12), dim3(256), 0, stream>>>(
      moesrc[0], moesrc[1], moesrc[2], moesrc[3], moesrc[4], moesrc[5],
      moesrc[6], moesrc[7], moesrc[8], moesrc[9], moesrc[10], moesrc[11], moeW);
  const _Float16* woh = awh + (3 << 20); const _Float16* wol = awl + (3 << 20);

  // ---- attention path (fp16x2) ----
  rms_split_k<<<dim3(NTOK), dim3(256), 0, stream>>>(x, n1w, hh, hl);
  gemm_split_k<3><<<dim3(24, 32), dim3(256), 0, stream>>>(
      hh, hl, awh, awl, 1024, 3072, qh, ql, 1.0f / SW, nullptr, nullptr,
      kh, kl, vth, vtl);
  qknorm2_k<<<dim3(NTOK * NHEAD / 4, 2), dim3(256), 0, stream>>>(qh, ql, kh, kl, qnw, knw);
  attn_k<<<dim3(512), dim3(256), 0, stream>>>(qh, ql, kh, kl, vth, vtl, hh, hl);
  gemm_split_k<1><<<dim3(8, 32), dim3(256), 0, stream>>>(
      hh, hl, woh, wol, 1024, 1024, nullptr, nullptr, 1.0f / (SA * SW), x, outp,
      nullptr, nullptr, nullptr, nullptr);

  // ---- MoE (sparse top-2, packed-slab grouped phases) ----
  rmsgate_k<<<dim3(NTOK), dim3(256), 0, stream>>>(outp, n2w, gw, xfb, wts, moe);
  route2_k<<<dim3(1), dim3(256), 0, stream>>>(wts, idxP, meta);

  auto mk = [&](const unsigned short* A, const unsigned short* B, unsigned short* outb,
                const unsigned short* other, int K, int nbn, int act, int ep, int gath) {
    SubOpP s; s.A = A; s.Bw = B; s.outb = outb; s.other = other;
    s.K = K; s.nbn = nbn; s.act = act; s.ep = ep; s.gath = gath;
    return s;
  };
  const SubOpP none = mk(nullptr, nullptr, nullptr, nullptr, 1024, 0, 0, 0, 0);

  PhaseP p1;
  p1.op[0] = mk(xfb, mw(0), e0t, nullptr, 1024, 16, 1, 0, 1);   // e0: gelu(x@up)
  p1.op[1] = mk(xfb, mw(3), e1a, nullptr, 1024, 16, 0, 0, 1);   // e1: x@w2 raw
  p1.op[2] = mk(xfb, mw(5), e2a, nullptr, 1024, 16, 1, 0, 1);   // e2: gelu(x@l1)
  p1.op[3] = none;
  gemm_moe_k<<<dim3(16, 72), dim3(256), 0, stream>>>(p1, meta, idxP, wts, moe);

  PhaseP p2;
  p2.op[0] = mk(e0t, mw(1), nullptr, nullptr, 2048, 8, 0, 2, 0);  // e0 down -> moe
  p2.op[1] = mk(xfb, mw(2), e1b, e1a, 1024, 16, 0, 1, 1);         // e1: silu(x@w1)*e1a
  p2.op[2] = mk(e2a, mw(6), e2b, nullptr, 2048, 16, 1, 0, 0);     // e2: gelu(@l2)
  p2.op[3] = mk(xfb, mw(9), e3a, nullptr, 1024, 8, 1, 0, 1);      // e3: gelu(x@dn)
  gemm_moe_k<<<dim3(16, 72), dim3(256), 0, stream>>>(p2, meta, idxP, wts, moe);

  PhaseP p3;
  p3.op[0] = none;
  p3.op[1] = mk(e1b, mw(4), nullptr, nullptr, 2048, 8, 0, 2, 0);  // e1 down -> moe
  p3.op[2] = mk(e2b, mw(7), e2c, nullptr, 2048, 16, 1, 0, 0);     // e2: gelu(@l3)
  p3.op[3] = mk(e3a, mw(10), e3b, nullptr, 1024, 16, 1, 0, 0);    // e3: gelu(@up)
  gemm_moe_k<<<dim3(16, 72), dim3(256), 0, stream>>>(p3, meta, idxP, wts, moe);

  PhaseP p4;
  p4.op[0] = none;
  p4.op[1] = none;
  p4.op[2] = mk(e2c, mw(8), nullptr, nullptr, 2048, 8, 0, 2, 0);  // e2 l4 -> moe
  p4.op[3] = mk(e3b, mw(11), nullptr, nullptr, 2048, 8, 0, 2, 0); // e3 out -> moe
  gemm_moe_k<<<dim3(16, 72), dim3(256), 0, stream>>>(p4, meta, idxP, wts, moe);

  comb_k<<<dim3(4096), dim3(256), 0, stream>>>(outp, moe);
}

// Round 7
// 638.396 us; speedup vs baseline: 1.3030x; 1.0112x over previous
//
#include <hip/hip_runtime.h>
#include <math.h>

#define DIM   1024
#define NTOK  4096
#define TSEQ  1024
#define NHEAD 16
#define MPROT 256
#define EPSR  1.1920929e-07f
#define SA    64.0f
#define SW    256.0f
#define SPC   64.0f

typedef __attribute__((ext_vector_type(8))) short          short8;
typedef __attribute__((ext_vector_type(8))) _Float16       half8;
typedef __attribute__((ext_vector_type(4))) _Float16       half4;
typedef __attribute__((ext_vector_type(4))) float          f32x4;
typedef __attribute__((ext_vector_type(4))) unsigned short us4;

static __device__ __forceinline__ float bf2f(unsigned short s) {
  union { unsigned int u; float f; } c; c.u = ((unsigned int)s) << 16; return c.f;
}
static __device__ __forceinline__ unsigned short f2bf(float f) {
  union { float f; unsigned int u; } c; c.f = f;
  return (unsigned short)((c.u + 0x7fffu + ((c.u >> 16) & 1u)) >> 16);
}
static __device__ __forceinline__ void gload16(void* lds, const void* g) {
  __builtin_amdgcn_global_load_lds(
      (__attribute__((address_space(1))) void*)const_cast<void*>(g),
      (__attribute__((address_space(3))) void*)lds, 16, 0, 0);
}

// XCD swizzle for dense split-GEMMs: stripe m-blocks across XCDs.
static __device__ __forceinline__ void tile_swz(int& m0, int& n0) {
  const int gx = gridDim.x;
  const int L = blockIdx.y * gx + blockIdx.x;
  const int xcd = L & 7;
  const int j = L >> 3;
  const int mbq = j / gx;
  const int nb = j - mbq * gx;
  m0 = ((mbq << 3) | xcd) << 7;
  n0 = nb << 7;
}

// ---------------- conversions ----------------
__global__ __launch_bounds__(256) void cvt_attn4_k(const float* __restrict__ wq,
                                                   const float* __restrict__ wk,
                                                   const float* __restrict__ wv,
                                                   const float* __restrict__ wo,
                                                   _Float16* __restrict__ dh,
                                                   _Float16* __restrict__ dl) {
  const int wi = blockIdx.y;
  const float* s = (wi == 0) ? wq : (wi == 1) ? wk : (wi == 2) ? wv : wo;
  const int i = blockIdx.x * 256 + threadIdx.x;
  const size_t off4 = ((size_t)wi << 20) >> 2;
  const float4 v = ((const float4*)s)[i];
  float a0 = v.x * SW, a1 = v.y * SW, a2 = v.z * SW, a3 = v.w * SW;
  half4 hv, lv;
  _Float16 h0 = (_Float16)a0; hv[0] = h0; lv[0] = (_Float16)(a0 - (float)h0);
  _Float16 h1 = (_Float16)a1; hv[1] = h1; lv[1] = (_Float16)(a1 - (float)h1);
  _Float16 h2 = (_Float16)a2; hv[2] = h2; lv[2] = (_Float16)(a2 - (float)h2);
  _Float16 h3 = (_Float16)a3; hv[3] = h3; lv[3] = (_Float16)(a3 - (float)h3);
  ((half4*)dh)[off4 + i] = hv; ((half4*)dl)[off4 + i] = lv;
}

__global__ __launch_bounds__(256) void cvt_moe_all_k(
    const float* s0, const float* s1, const float* s2, const float* s3,
    const float* s4, const float* s5, const float* s6, const float* s7,
    const float* s8, const float* s9, const float* s10, const float* s11,
    unsigned short* __restrict__ dst) {
  const int n4tab[12] = {524288, 524288, 524288, 524288, 524288, 524288,
                         1048576, 1048576, 524288, 262144, 524288, 524288};
  const size_t offtab[12] = {0, 2097152, 4194304, 6291456, 8388608, 10485760,
                             12582912, 16777216, 20971520, 23068672, 24117248, 26214400};
  const int wi = blockIdx.y;
  const int i = blockIdx.x * 256 + threadIdx.x;
  if (i >= n4tab[wi]) return;
  const float* s;
  switch (wi) {
    case 0: s = s0; break; case 1: s = s1; break; case 2: s = s2; break;
    case 3: s = s3; break; case 4: s = s4; break; case 5: s = s5; break;
    case 6: s = s6; break; case 7: s = s7; break; case 8: s = s8; break;
    case 9: s = s9; break; case 10: s = s10; break; default: s = s11; break;
  }
  const float4 v = ((const float4*)s)[i];
  us4 o; o[0] = f2bf(v.x); o[1] = f2bf(v.y); o[2] = f2bf(v.z); o[3] = f2bf(v.w);
  ((us4*)(dst + offtab[wi]))[i] = o;
}

// ---------------- RMS norms ----------------
__global__ __launch_bounds__(256) void rms_split_k(const float* __restrict__ in,
                                                   const float* __restrict__ wgt,
                                                   _Float16* __restrict__ oh,
                                                   _Float16* __restrict__ ol) {
  const int row = blockIdx.x, tid = threadIdx.x;
  const float4 v = ((const float4*)(in + (size_t)row * DIM))[tid];
  float ss = v.x * v.x + v.y * v.y + v.z * v.z + v.w * v.w;
#pragma unroll
  for (int o = 32; o; o >>= 1) ss += __shfl_xor(ss, o);
  __shared__ float red[4];
  if ((tid & 63) == 0) red[tid >> 6] = ss;
  __syncthreads();
  const float sc = rsqrtf((red[0] + red[1] + red[2] + red[3]) * (1.0f / DIM) + EPSR) * SA;
  const float4 wv = ((const float4*)wgt)[tid];
  float a[4] = {v.x * sc * wv.x, v.y * sc * wv.y, v.z * sc * wv.z, v.w * sc * wv.w};
  half4 hv, lv;
#pragma unroll
  for (int j = 0; j < 4; ++j) {
    _Float16 hh = (_Float16)a[j]; hv[j] = hh; lv[j] = (_Float16)(a[j] - (float)hh);
  }
  ((half4*)(oh + (size_t)row * DIM))[tid] = hv;
  ((half4*)(ol + (size_t)row * DIM))[tid] = lv;
}

// fused RMSNorm(bf16 out) + gate logits/softmax/top-2 + moe buffer zeroing
__global__ __launch_bounds__(256) void rmsgate_k(const float* __restrict__ x2,
                                                 const float* __restrict__ n2w,
                                                 const float* __restrict__ gw,
                                                 unsigned short* __restrict__ xfb,
                                                 float* __restrict__ wts,
                                                 float* __restrict__ moe) {
  const int row = blockIdx.x, tid = threadIdx.x;
  ((float4*)(moe + (size_t)row * DIM))[tid] = (float4){0.f, 0.f, 0.f, 0.f};
  const float4 v = ((const float4*)(x2 + (size_t)row * DIM))[tid];
  float ss = v.x * v.x + v.y * v.y + v.z * v.z + v.w * v.w;
#pragma unroll
  for (int o = 32; o; o >>= 1) ss += __shfl_xor(ss, o);
  __shared__ float red[4];
  __shared__ float redE[4][4];
  const int w = tid >> 6, lane = tid & 63;
  if (lane == 0) red[w] = ss;
  __syncthreads();
  const float sc = rsqrtf((red[0] + red[1] + red[2] + red[3]) * (1.0f / DIM) + EPSR);
  const float4 nw = ((const float4*)n2w)[tid];
  const float xn0 = v.x * sc * nw.x, xn1 = v.y * sc * nw.y;
  const float xn2 = v.z * sc * nw.z, xn3 = v.w * sc * nw.w;
  us4 ob; ob[0] = f2bf(xn0); ob[1] = f2bf(xn1); ob[2] = f2bf(xn2); ob[3] = f2bf(xn3);
  ((us4*)(xfb + (size_t)row * DIM))[tid] = ob;
#pragma unroll
  for (int e = 0; e < 4; ++e) {
    const float4 g = ((const float4*)(gw + (size_t)e * DIM))[tid];
    float d = xn0 * g.x + xn1 * g.y + xn2 * g.z + xn3 * g.w;
#pragma unroll
    for (int o = 32; o; o >>= 1) d += __shfl_xor(d, o);
    if (lane == 0) redE[w][e] = d;
  }
  __syncthreads();
  if (tid == 0) {
    float lg[4];
#pragma unroll
    for (int e = 0; e < 4; ++e) lg[e] = redE[0][e] + redE[1][e] + redE[2][e] + redE[3][e];
    const float mx = fmaxf(fmaxf(lg[0], lg[1]), fmaxf(lg[2], lg[3]));
    float pe[4]; float sum = 0.0f;
#pragma unroll
    for (int e = 0; e < 4; ++e) { pe[e] = __expf(lg[e] - mx); sum += pe[e]; }
#pragma unroll
    for (int e = 0; e < 4; ++e) pe[e] /= sum;
    int i1 = 0;
    for (int e = 1; e < 4; ++e) if (pe[e] > pe[i1]) i1 = e;
    int i2 = -1;
    for (int e = 0; e < 4; ++e) { if (e == i1) continue; if (i2 < 0 || pe[e] > pe[i2]) i2 = e; }
    const float s2 = pe[i1] + pe[i2] + 1e-8f;
    float o[4] = {0.f, 0.f, 0.f, 0.f};
    o[i1] = pe[i1] / s2; o[i2] = pe[i2] / s2;
    float4 r; r.x = o[0]; r.y = o[1]; r.z = o[2]; r.w = o[3];
    *(float4*)(wts + (size_t)row * 4) = r;
  }
}

// per (token,head) RMS over 64 dims; y=0 -> Q planes, y=1 -> K planes
__global__ __launch_bounds__(256) void qknorm2_k(_Float16* __restrict__ qh,
                                                 _Float16* __restrict__ ql,
                                                 _Float16* __restrict__ kh,
                                                 _Float16* __restrict__ kl,
                                                 const float* __restrict__ qnw,
                                                 const float* __restrict__ knw) {
  _Float16* ph; _Float16* pl; const float* wgt;
  if (blockIdx.y == 0) { ph = qh; pl = ql; wgt = qnw; }
  else { ph = kh; pl = kl; wgt = knw; }
  const int idx = (blockIdx.x << 2) + (threadIdx.x >> 6);
  const int lane = threadIdx.x & 63;
  const size_t off = ((size_t)idx << 6) + lane;
  const float v = (float)ph[off] + (float)pl[off];
  float ss = v * v;
#pragma unroll
  for (int o = 32; o; o >>= 1) ss += __shfl_xor(ss, o);
  const float sc = rsqrtf(ss * (1.0f / (64.0f * SA * SA)) + EPSR);
  const float nv = v * sc * wgt[lane];
  _Float16 hh = (_Float16)nv;
  ph[off] = hh; pl[off] = (_Float16)(nv - (float)hh);
}

// ---------------- packed-slab routing: one ordered list, 128-padded slabs ----------------
// idxP[prow] = token or -1 (pad); meta[0..71] = mb->expert (-1 none); meta[80+e] = slab base row
__global__ __launch_bounds__(256) void route2_k(const float* __restrict__ wts,
                                                int* __restrict__ idxP,
                                                int* __restrict__ meta) {
  const int tid = threadIdx.x, w = tid >> 6, lane = tid & 63;
  __shared__ int wsum[4];
  __shared__ int baseS;
  int off = 0;
  for (int e = 0; e < 4; ++e) {
    if (tid == 0) baseS = 0;
    __syncthreads();
    for (int c = 0; c < 16; ++c) {
      const int tok = (c << 8) + tid;
      const bool pred = wts[(size_t)tok * 4 + e] > 0.0f;
      const unsigned long long m = __ballot(pred);
      const int lanepre = __popcll(m & ((1ull << lane) - 1ull));
      if (lane == 0) wsum[w] = __popcll(m);
      __syncthreads();
      int wpre = 0;
#pragma unroll
      for (int i = 0; i < 4; ++i) wpre += (i < w) ? wsum[i] : 0;
      const int tot = wsum[0] + wsum[1] + wsum[2] + wsum[3];
      if (pred) idxP[off + baseS + wpre + lanepre] = tok;
      __syncthreads();
      if (tid == 0) baseS += tot;
      __syncthreads();
    }
    const int cnt = baseS;
    const int padded = (cnt + 127) & ~127;
    for (int j = cnt + tid; j < padded; j += 256) idxP[off + j] = -1;
    if (tid == 0) meta[80 + e] = off;
    const int mb0 = off >> 7, nmb = padded >> 7;
    for (int j = tid; j < nmb; j += 256) meta[mb0 + j] = e;
    off += padded;
    __syncthreads();
  }
  for (int j = (off >> 7) + tid; j < 72; j += 256) meta[j] = -1;
}

// ---------------- packed grouped sparse bf16 GEMM (single-buffer LDS) ----------------
struct SubOpP {
  const unsigned short* A;
  const unsigned short* Bw;
  unsigned short* outb;
  const unsigned short* other;
  int K, nbn, act, ep, gath;   // ep: 0 store, 1 silu*other, 2 scatter atomicAdd; nbn=0 -> absent
};
struct PhaseP { SubOpP op[4]; };  // indexed by expert

__global__ __launch_bounds__(256, 4) void gemm_moe_k(PhaseP ph,
                                                     const int* __restrict__ meta,
                                                     const int* __restrict__ idxP,
                                                     const float* __restrict__ wts,
                                                     float* __restrict__ moe) {
  __shared__ unsigned short As[128][64];
  __shared__ unsigned short Bs[128][64];
  // XCD stripe over packed (mb, nb) space; grid fixed (16, 72)
  const int L = blockIdx.y * 16 + blockIdx.x;
  const int xcd = L & 7;
  const int j = L >> 3;
  const int nb = j & 15;
  const int mb = ((j >> 4) << 3) | xcd;
  const int e = meta[mb];
  if (e < 0) return;
  SubOpP op;
  switch (e) {
    case 0: op = ph.op[0]; break;
    case 1: op = ph.op[1]; break;
    case 2: op = ph.op[2]; break;
    default: op = ph.op[3]; break;
  }
  if (op.nbn == 0 || nb >= op.nbn) return;
  const int m0p = mb << 7;                 // packed row base
  const int lr0 = m0p - meta[80 + e];      // local (compact) row base
  const int n0 = nb << 7;
  const int F = op.nbn << 7;
  const int K = op.K;
  const int tid = threadIdx.x;
  const int w = tid >> 6, lane = tid & 63;
  const int wr = ((w >> 1) << 6), wc = ((w & 1) << 6);
  const int rr = lane & 15, kgl = lane >> 4;
  const int srow = tid >> 3, sslot = tid & 7;

  int grow[4];
#pragma unroll
  for (int i = 0; i < 4; ++i) {
    const int r = (i << 5) + srow;
    if (op.gath) {
      const int t = idxP[m0p + r];
      grow[i] = (t < 0) ? 0 : t;
    } else {
      grow[i] = lr0 + r;
    }
  }

  f32x4 acc[4][4];
#pragma unroll
  for (int a_ = 0; a_ < 4; ++a_)
#pragma unroll
    for (int b_ = 0; b_ < 4; ++b_) acc[a_][b_] = (f32x4){0.f, 0.f, 0.f, 0.f};

  const int KT = K >> 6;
  for (int kt = 0; kt < KT; ++kt) {
    const int k0 = kt << 6;
#pragma unroll
    for (int i = 0; i < 4; ++i) {
      const int r = (i << 5) + srow;
      const int ls = sslot ^ (r & 7);
      gload16(&As[(i << 5) + (w << 3)][0], op.A + (size_t)grow[i] * K + k0 + (ls << 3));
      gload16(&Bs[(i << 5) + (w << 3)][0], op.Bw + (size_t)(n0 + r) * K + k0 + (ls << 3));
    }
    __syncthreads();
    short8 af[4][2], bfr[4][2];
#pragma unroll
    for (int f = 0; f < 4; ++f) {
#pragma unroll
      for (int ks = 0; ks < 2; ++ks) {
        const int row = wr + (f << 4) + rr;
        const int kg = (ks << 2) + kgl;
        af[f][ks] = *(const short8*)&As[row][(kg ^ (row & 7)) << 3];
        const int col = wc + (f << 4) + rr;
        bfr[f][ks] = *(const short8*)&Bs[col][(kg ^ (col & 7)) << 3];
      }
    }
#pragma unroll
    for (int fi = 0; fi < 4; ++fi)
#pragma unroll
      for (int fj = 0; fj < 4; ++fj)
#pragma unroll
        for (int ks = 0; ks < 2; ++ks)
          acc[fi][fj] = __builtin_amdgcn_mfma_f32_16x16x32_bf16(
              af[fi][ks], bfr[fj][ks], acc[fi][fj], 0, 0, 0);
    __syncthreads();
  }
#pragma unroll
  for (int fi = 0; fi < 4; ++fi)
#pragma unroll
    for (int fj = 0; fj < 4; ++fj) {
      const int col = n0 + wc + (fj << 4) + rr;
#pragma unroll
      for (int r = 0; r < 4; ++r) {
        const int rl = wr + (fi << 4) + (kgl << 2) + r;
        float v = acc[fi][fj][r];
        if (op.act) v = 0.5f * v * (1.0f + erff(v * 0.70710678118654752f));
        if (op.ep == 0) {
          op.outb[(size_t)(lr0 + rl) * F + col] = f2bf(v);
        } else if (op.ep == 1) {
          const size_t off = (size_t)(lr0 + rl) * F + col;
          const float sv = v / (1.0f + __expf(-v));
          op.outb[off] = f2bf(sv * bf2f(op.other[off]));
        } else {
          const int tok = idxP[m0p + rl];
          if (tok >= 0)
            atomicAdd(&moe[(size_t)tok * DIM + col], wts[(size_t)tok * 4 + e] * v);
        }
      }
    }
}

// ---------------- fp16x2 split GEMM (3-term), single-buffer LDS ----------------
// EP: 1 = fp32: resid + masked(v); 3 = fused QKV epilogue (q/k planes + V^T planes)
template <int EP>
__global__ __launch_bounds__(256, 4) void gemm_split_k(
    const _Float16* __restrict__ Ah, const _Float16* __restrict__ Al,
    const _Float16* __restrict__ Bh, const _Float16* __restrict__ Bl,
    int K, int F,
    _Float16* __restrict__ Oh, _Float16* __restrict__ Ol, float oscale,
    const float* __restrict__ resid, float* __restrict__ outf,
    _Float16* __restrict__ K2h, _Float16* __restrict__ K2l,
    _Float16* __restrict__ V2h, _Float16* __restrict__ V2l) {
  __shared__ _Float16 AsH[128][32], AsL[128][32];
  __shared__ _Float16 BsH[128][32], BsL[128][32];
  const int tid = threadIdx.x;
  const int w = tid >> 6, lane = tid & 63;
  const int wr = ((w >> 1) << 6), wc = ((w & 1) << 6);
  int m0, n0;
  tile_swz(m0, n0);
  const int rr = lane & 15, kgl = lane >> 4;
  const int srow = tid >> 2, sslot = tid & 3;

  f32x4 acc[4][4];
#pragma unroll
  for (int a_ = 0; a_ < 4; ++a_)
#pragma unroll
    for (int b_ = 0; b_ < 4; ++b_) acc[a_][b_] = (f32x4){0.f, 0.f, 0.f, 0.f};

  const int KT = K >> 5;
  for (int kt = 0; kt < KT; ++kt) {
    const int k0 = kt << 5;
#pragma unroll
    for (int i = 0; i < 2; ++i) {
      const int r = (i << 6) + srow;
      const int ls = sslot ^ ((r >> 1) & 3);
      const size_t ga = (size_t)(m0 + r) * K + k0 + (ls << 3);
      const size_t gb = (size_t)(n0 + r) * K + k0 + (ls << 3);
      const int lr = (i << 6) + (w << 4);
      gload16(&AsH[lr][0], Ah + ga);
      gload16(&AsL[lr][0], Al + ga);
      gload16(&BsH[lr][0], Bh + gb);
      gload16(&BsL[lr][0], Bl + gb);
    }
    __syncthreads();
    half8 ah[4], al[4], bh[4], bl[4];
#pragma unroll
    for (int f = 0; f < 4; ++f) {
      const int row = wr + (f << 4) + rr;
      const int pa = (kgl ^ ((row >> 1) & 3)) << 3;
      ah[f] = *(const half8*)&AsH[row][pa];
      al[f] = *(const half8*)&AsL[row][pa];
      const int col = wc + (f << 4) + rr;
      const int pb = (kgl ^ ((col >> 1) & 3)) << 3;
      bh[f] = *(const half8*)&BsH[col][pb];
      bl[f] = *(const half8*)&BsL[col][pb];
    }
#pragma unroll
    for (int fi = 0; fi < 4; ++fi)
#pragma unroll
      for (int fj = 0; fj < 4; ++fj) {
        acc[fi][fj] = __builtin_amdgcn_mfma_f32_16x16x32_f16(ah[fi], bh[fj], acc[fi][fj], 0, 0, 0);
        acc[fi][fj] = __builtin_amdgcn_mfma_f32_16x16x32_f16(ah[fi], bl[fj], acc[fi][fj], 0, 0, 0);
        acc[fi][fj] = __builtin_amdgcn_mfma_f32_16x16x32_f16(al[fi], bh[fj], acc[fi][fj], 0, 0, 0);
      }
    __syncthreads();
  }
#pragma unroll
  for (int fi = 0; fi < 4; ++fi)
#pragma unroll
    for (int fj = 0; fj < 4; ++fj) {
      const int col = n0 + wc + (fj << 4) + rr;
      const int rowb = m0 + wr + (fi << 4) + (kgl << 2);
      if (EP == 3) {
        if (col < 2048) {
          _Float16* ph = (col < 1024) ? Oh : K2h;
          _Float16* pl = (col < 1024) ? Ol : K2l;
          const int c = col & 1023;
#pragma unroll
          for (int r = 0; r < 4; ++r) {
            const float v = acc[fi][fj][r] * oscale;
            const _Float16 hh2 = (_Float16)v;
            const size_t off = (size_t)(rowb + r) * DIM + c;
            ph[off] = hh2; pl[off] = (_Float16)(v - (float)hh2);
          }
        } else {
          const int c2 = col - 2048;
          half4 h4, l4;
#pragma unroll
          for (int r = 0; r < 4; ++r) {
            const float v = acc[fi][fj][r] * oscale;
            const _Float16 hh2 = (_Float16)v;
            h4[r] = hh2; l4[r] = (_Float16)(v - (float)hh2);
          }
          const size_t vt = ((size_t)((rowb >> 10) << 4) + (size_t)(c2 >> 6)) * 65536 +
                            (size_t)(c2 & 63) * 1024 + (size_t)(rowb & 1023);
          *(half4*)&V2h[vt] = h4;
          *(half4*)&V2l[vt] = l4;
        }
      } else {
#pragma unroll
        for (int r = 0; r < 4; ++r) {
          const size_t off = (size_t)(rowb + r) * F + col;
          const float v = acc[fi][fj][r] * oscale;
          outf[off] = resid[off] + (col >= MPROT ? v : 0.0f);
        }
      }
    }
}

// ---------------- flash attention, causal, fp16x2 split, swapped-QK ----------------
__global__ __launch_bounds__(256, 2) void attn_k(
    const _Float16* __restrict__ Qh, const _Float16* __restrict__ Ql,
    const _Float16* __restrict__ Kh, const _Float16* __restrict__ Kl,
    const _Float16* __restrict__ Vth, const _Float16* __restrict__ Vtl,
    _Float16* __restrict__ Oh, _Float16* __restrict__ Ol) {
  __shared__ _Float16 Ksh[2][32][64], Ksl[2][32][64];
  __shared__ _Float16 Vsh[2][64][40], Vsl[2][64][40];
  __shared__ _Float16 Plh[4][16][40], Pll[4][16][40];
  const int n = blockIdx.x;
  const int qt = n >> 6;
  const int bh = ((n & 7) << 3) | ((n >> 3) & 7);
  const int b = bh >> 4, h = bh & 15;
  const int tid = threadIdx.x, w = tid >> 6, lane = tid & 63;
  const int rr = lane & 15, rg = lane >> 4;
  const size_t tokbase = (size_t)b * TSEQ;
  const int hcol = h << 6;
  const size_t vtbase = (size_t)bh << 16;
  const int q0w = (qt << 7) + (w << 5);
  const float sscale = 0.125f / (SA * SA);

  half8 qfh[2][2], qfl[2][2];
#pragma unroll
  for (int qf = 0; qf < 2; ++qf)
#pragma unroll
    for (int ks = 0; ks < 2; ++ks) {
      const size_t off = (tokbase + q0w + (qf << 4) + rr) * DIM + hcol + (ks << 5) + (rg << 3);
      qfh[qf][ks] = *(const half8*)&Qh[off];
      qfl[qf][ks] = *(const half8*)&Ql[off];
    }

  f32x4 oacc[2][4];
#pragma unroll
  for (int qf = 0; qf < 2; ++qf)
#pragma unroll
    for (int dg = 0; dg < 4; ++dg) oacc[qf][dg] = (f32x4){0.f, 0.f, 0.f, 0.f};
  float mreg[2] = {-INFINITY, -INFINITY}, lreg[2] = {0.f, 0.f};

  const int kr = (w << 3) + (lane >> 3);
  const int kswz = ((lane & 7) ^ (kr & 7)) << 3;
  const int vr = tid >> 2;
  const int vs = (tid & 3) << 3;

  const int ntiles = (qt + 1) << 2;

  {
    gload16(&Ksh[0][w << 3][0], &Kh[(tokbase + kr) * DIM + hcol + kswz]);
    gload16(&Ksl[0][w << 3][0], &Kl[(tokbase + kr) * DIM + hcol + kswz]);
    const half8 vvh = *(const half8*)&Vth[vtbase + (size_t)vr * TSEQ + vs];
    const half8 vvl = *(const half8*)&Vtl[vtbase + (size_t)vr * TSEQ + vs];
    *(half8*)&Vsh[0][vr][vs] = vvh;
    *(half8*)&Vsl[0][vr][vs] = vvl;
    __syncthreads();
  }

  for (int t = 0; t < ntiles; ++t) {
    const int cur = t & 1;
    const int kv0 = t << 5;
    const bool havenext = (t + 1 < ntiles);
    half8 nvh, nvl;
    if (havenext) {
      const int kn = kv0 + 32;
      gload16(&Ksh[cur ^ 1][w << 3][0], &Kh[(tokbase + kn + kr) * DIM + hcol + kswz]);
      gload16(&Ksl[cur ^ 1][w << 3][0], &Kl[(tokbase + kn + kr) * DIM + hcol + kswz]);
      nvh = *(const half8*)&Vth[vtbase + (size_t)vr * TSEQ + kn + vs];
      nvl = *(const half8*)&Vtl[vtbase + (size_t)vr * TSEQ + kn + vs];
    }
    if (kv0 <= q0w + 31) {
      half8 kfh[2][2], kfl[2][2];
#pragma unroll
      for (int kt = 0; kt < 2; ++kt)
#pragma unroll
        for (int ks = 0; ks < 2; ++ks) {
          const int row = (kt << 4) + rr;
          const int sw = ((((ks << 2) + rg)) ^ (row & 7)) << 3;
          kfh[kt][ks] = *(const half8*)&Ksh[cur][row][sw];
          kfl[kt][ks] = *(const half8*)&Ksl[cur][row][sw];
        }
#pragma unroll
      for (int qf = 0; qf < 2; ++qf) {
        if (kv0 > q0w + (qf << 4) + 15) continue;
        f32x4 st[2];
        st[0] = (f32x4){0.f, 0.f, 0.f, 0.f};
        st[1] = (f32x4){0.f, 0.f, 0.f, 0.f};
#pragma unroll
        for (int kt = 0; kt < 2; ++kt)
#pragma unroll
          for (int ks = 0; ks < 2; ++ks) {
            st[kt] = __builtin_amdgcn_mfma_f32_16x16x32_f16(kfh[kt][ks], qfh[qf][ks], st[kt], 0, 0, 0);
            st[kt] = __builtin_amdgcn_mfma_f32_16x16x32_f16(kfh[kt][ks], qfl[qf][ks], st[kt], 0, 0, 0);
            st[kt] = __builtin_amdgcn_mfma_f32_16x16x32_f16(kfl[kt][ks], qfh[qf][ks], st[kt], 0, 0, 0);
          }
        const int qg = q0w + (qf << 4) + rr;
        float s[2][4]; float mx = -INFINITY;
#pragma unroll
        for (int kt = 0; kt < 2; ++kt)
#pragma unroll
          for (int r = 0; r < 4; ++r) {
            float sv = st[kt][r] * sscale;
            if (kv0 + (kt << 4) + (rg << 2) + r > qg) sv = -INFINITY;
            s[kt][r] = sv; mx = fmaxf(mx, sv);
          }
        mx = fmaxf(mx, __shfl_xor(mx, 16));
        mx = fmaxf(mx, __shfl_xor(mx, 32));
        const float mn = fmaxf(mreg[qf], mx);
        const float al = __expf(mreg[qf] - mn);
        mreg[qf] = mn;
        float p[2][4]; float rs = 0.f;
#pragma unroll
        for (int kt = 0; kt < 2; ++kt)
#pragma unroll
          for (int r = 0; r < 4; ++r) { p[kt][r] = __expf(s[kt][r] - mn); rs += p[kt][r]; }
        rs += __shfl_xor(rs, 16);
        rs += __shfl_xor(rs, 32);
        lreg[qf] = lreg[qf] * al + rs;
#pragma unroll
        for (int kt = 0; kt < 2; ++kt) {
          half4 h4, l4;
#pragma unroll
          for (int r = 0; r < 4; ++r) {
            const float pv = p[kt][r] * SPC;
            const _Float16 ph = (_Float16)pv;
            h4[r] = ph; l4[r] = (_Float16)(pv - (float)ph);
          }
          *(half4*)&Plh[w][rr][(kt << 4) + (rg << 2)] = h4;
          *(half4*)&Pll[w][rr][(kt << 4) + (rg << 2)] = l4;
        }
        float alr[4];
#pragma unroll
        for (int r = 0; r < 4; ++r) alr[r] = __shfl(al, (lane & 48) | ((rg << 2) + r));
#pragma unroll
        for (int dg = 0; dg < 4; ++dg)
#pragma unroll
          for (int r = 0; r < 4; ++r) oacc[qf][dg][r] *= alr[r];
        const half8 pah = *(const half8*)&Plh[w][rr][rg << 3];
        const half8 pal = *(const half8*)&Pll[w][rr][rg << 3];
#pragma unroll
        for (int dg = 0; dg < 4; ++dg) {
          const half8 vfh2 = *(const half8*)&Vsh[cur][(dg << 4) + rr][rg << 3];
          const half8 vfl2 = *(const half8*)&Vsl[cur][(dg << 4) + rr][rg << 3];
          oacc[qf][dg] = __builtin_amdgcn_mfma_f32_16x16x32_f16(pah, vfh2, oacc[qf][dg], 0, 0, 0);
          oacc[qf][dg] = __builtin_amdgcn_mfma_f32_16x16x32_f16(pah, vfl2, oacc[qf][dg], 0, 0, 0);
          oacc[qf][dg] = __builtin_amdgcn_mfma_f32_16x16x32_f16(pal, vfh2, oacc[qf][dg], 0, 0, 0);
        }
      }
    }
    if (havenext) {
      *(half8*)&Vsh[cur ^ 1][vr][vs] = nvh;
      *(half8*)&Vsl[cur ^ 1][vr][vs] = nvl;
    }
    __syncthreads();
  }
#pragma unroll
  for (int qf = 0; qf < 2; ++qf) {
    float li[4];
#pragma unroll
    for (int r = 0; r < 4; ++r)
      li[r] = __shfl(lreg[qf], (lane & 48) | ((rg << 2) + r));
#pragma unroll
    for (int dg = 0; dg < 4; ++dg)
#pragma unroll
      for (int r = 0; r < 4; ++r) {
        const int qloc = (rg << 2) + r;
        const float ov = oacc[qf][dg][r] / (li[r] * SPC);
        const _Float16 hh2 = (_Float16)ov;
        const size_t off = (tokbase + q0w + (qf << 4) + qloc) * DIM + hcol + (dg << 4) + rr;
        Oh[off] = hh2;
        Ol[off] = (_Float16)(ov - (float)hh2);
      }
  }
}

// ---------------- final combine: outp += mask(moe) ----------------
__global__ __launch_bounds__(256) void comb_k(float* __restrict__ outp,
                                              const float* __restrict__ moe) {
  const size_t i = (size_t)blockIdx.x * 256 + threadIdx.x;
  const int c4 = (int)(i & 255);
  if (c4 >= 64) {
    float4 o = ((float4*)outp)[i];
    const float4 m = ((const float4*)moe)[i];
    o.x += m.x; o.y += m.y; o.z += m.z; o.w += m.w;
    ((float4*)outp)[i] = o;
  }
}

extern "C" void kernel_launch(void* const* d_in, const int* in_sizes, int n_in,
                              void* d_out, int out_size, void* d_ws, size_t ws_size,
                              hipStream_t stream) {
  (void)in_sizes; (void)n_in; (void)out_size; (void)ws_size;
  const float* x    = (const float*)d_in[0];
  const float* n1w  = (const float*)d_in[1];
  const float* n2w  = (const float*)d_in[2];
  const float* wq   = (const float*)d_in[3];
  const float* wk   = (const float*)d_in[4];
  const float* wv   = (const float*)d_in[5];
  const float* wo   = (const float*)d_in[6];
  const float* qnw  = (const float*)d_in[7];
  const float* knw  = (const float*)d_in[8];
  const float* gw   = (const float*)d_in[9];
  const float* moesrc[12] = {
    (const float*)d_in[10], (const float*)d_in[11],
    (const float*)d_in[12], (const float*)d_in[13], (const float*)d_in[14],
    (const float*)d_in[15], (const float*)d_in[16], (const float*)d_in[17], (const float*)d_in[18],
    (const float*)d_in[19], (const float*)d_in[20], (const float*)d_in[21]
  };
  float* outp = (float*)d_out;

  char* p = (char*)d_ws;
  auto alloc = [&](size_t bytes) { void* r = (void*)p; p += (bytes + 255) & ~(size_t)255; return r; };
  const size_t NC = (size_t)NTOK * DIM;
  _Float16* hh = (_Float16*)alloc(NC * 2);
  _Float16* hl = (_Float16*)alloc(NC * 2);
  _Float16* qh = (_Float16*)alloc(NC * 2);   // qh..vtl: 48 MB contiguous, reused as MoE arena
  _Float16* ql = (_Float16*)alloc(NC * 2);
  _Float16* kh = (_Float16*)alloc(NC * 2);
  _Float16* kl = (_Float16*)alloc(NC * 2);
  _Float16* vth = (_Float16*)alloc(NC * 2);
  _Float16* vtl = (_Float16*)alloc(NC * 2);
  unsigned short* xfb = (unsigned short*)alloc(NC * 2);
  float* moe = (float*)alloc(NC * 4);
  float* wts = (float*)alloc((size_t)NTOK * 4 * 4);
  _Float16* awh = (_Float16*)alloc((size_t)4 * 1024 * 1024 * 2);
  _Float16* awl = (_Float16*)alloc((size_t)4 * 1024 * 1024 * 2);
  unsigned short* moeW = (unsigned short*)alloc((size_t)28311552 * 2);
  int* idxP = (int*)alloc((size_t)9216 * 4);
  int* meta = (int*)alloc(512);
  // MoE intermediate arena: alias dead q/k/v planes + fresh tail
  unsigned short* e0t = (unsigned short*)qh;    // 16 MB (qh+ql)
  unsigned short* e1a = (unsigned short*)kh;    // 16 MB (kh+kl)
  unsigned short* e2a = (unsigned short*)vth;   // 16 MB (vth+vtl), reused as e2c
  unsigned short* e1b = (unsigned short*)alloc((size_t)NTOK * 2048 * 2);
  unsigned short* e2b = (unsigned short*)alloc((size_t)NTOK * 2048 * 2);
  unsigned short* e3a = (unsigned short*)alloc((size_t)NTOK * 1024 * 2);
  unsigned short* e3b = (unsigned short*)alloc((size_t)NTOK * 2048 * 2);
  unsigned short* e2c = e2a;

  const size_t moff[12] = {0, 2097152, 4194304, 6291456, 8388608, 10485760,
                           12582912, 16777216, 20971520, 23068672, 24117248, 26214400};
  auto mw = [&](int i) -> const unsigned short* { return moeW + moff[i]; };

  // ---- weight conversions ----
  cvt_attn4_k<<<dim3(1024, 4), dim3(256), 0, stream>>>(wq, wk, wv, wo, awh, awl);
  cvt_moe_all_k<<<dim3(4096, 12), dim3(256), 0, stream>>>(
      moesrc[0], moesrc[1], moesrc[2], moesrc[3], moesrc[4], moesrc[5],
      moesrc[6], moesrc[7], moesrc[8], moesrc[9], moesrc[10], moesrc[11], moeW);
  const _Float16* woh = awh + (3 << 20); const _Float16* wol = awl + (3 << 20);

  // ---- attention path (fp16x2) ----
  rms_split_k<<<dim3(NTOK), dim3(256), 0, stream>>>(x, n1w, hh, hl);
  gemm_split_k<3><<<dim3(24, 32), dim3(256), 0, stream>>>(
      hh, hl, awh, awl, 1024, 3072, qh, ql, 1.0f / SW, nullptr, nullptr,
      kh, kl, vth, vtl);
  qknorm2_k<<<dim3(NTOK * NHEAD / 4, 2), dim3(256), 0, stream>>>(qh, ql, kh, kl, qnw, knw);
  attn_k<<<dim3(512), dim3(256), 0, stream>>>(qh, ql, kh, kl, vth, vtl, hh, hl);
  gemm_split_k<1><<<dim3(8, 32), dim3(256), 0, stream>>>(
      hh, hl, woh, wol, 1024, 1024, nullptr, nullptr, 1.0f / (SA * SW), x, outp,
      nullptr, nullptr, nullptr, nullptr);

  // ---- MoE (sparse top-2, packed-slab grouped phases) ----
  rmsgate_k<<<dim3(NTOK), dim3(256), 0, stream>>>(outp, n2w, gw, xfb, wts, moe);
  route2_k<<<dim3(1), dim3(256), 0, stream>>>(wts, idxP, meta);

  auto mk = [&](const unsigned short* A, const unsigned short* B, unsigned short* outb,
                const unsigned short* other, int K, int nbn, int act, int ep, int gath) {
    SubOpP s; s.A = A; s.Bw = B; s.outb = outb; s.other = other;
    s.K = K; s.nbn = nbn; s.act = act; s.ep = ep; s.gath = gath;
    return s;
  };
  const SubOpP none = mk(nullptr, nullptr, nullptr, nullptr, 1024, 0, 0, 0, 0);

  PhaseP p1;
  p1.op[0] = mk(xfb, mw(0), e0t, nullptr, 1024, 16, 1, 0, 1);   // e0: gelu(x@up)
  p1.op[1] = mk(xfb, mw(3), e1a, nullptr, 1024, 16, 0, 0, 1);   // e1: x@w2 raw
  p1.op[2] = mk(xfb, mw(5), e2a, nullptr, 1024, 16, 1, 0, 1);   // e2: gelu(x@l1)
  p1.op[3] = none;
  gemm_moe_k<<<dim3(16, 72), dim3(256), 0, stream>>>(p1, meta, idxP, wts, moe);

  PhaseP p2;
  p2.op[0] = mk(e0t, mw(1), nullptr, nullptr, 2048, 8, 0, 2, 0);  // e0 down -> moe
  p2.op[1] = mk(xfb, mw(2), e1b, e1a, 1024, 16, 0, 1, 1);         // e1: silu(x@w1)*e1a
  p2.op[2] = mk(e2a, mw(6), e2b, nullptr, 2048, 16, 1, 0, 0);     // e2: gelu(@l2)
  p2.op[3] = mk(xfb, mw(9), e3a, nullptr, 1024, 8, 1, 0, 1);      // e3: gelu(x@dn)
  gemm_moe_k<<<dim3(16, 72), dim3(256), 0, stream>>>(p2, meta, idxP, wts, moe);

  PhaseP p3;
  p3.op[0] = none;
  p3.op[1] = mk(e1b, mw(4), nullptr, nullptr, 2048, 8, 0, 2, 0);  // e1 down -> moe
  p3.op[2] = mk(e2b, mw(7), e2c, nullptr, 2048, 16, 1, 0, 0);     // e2: gelu(@l3)
  p3.op[3] = mk(e3a, mw(10), e3b, nullptr, 1024, 16, 1, 0, 0);    // e3: gelu(@up)
  gemm_moe_k<<<dim3(16, 72), dim3(256), 0, stream>>>(p3, meta, idxP, wts, moe);

  PhaseP p4;
  p4.op[0] = none;
  p4.op[1] = none;
  p4.op[2] = mk(e2c, mw(8), nullptr, nullptr, 2048, 8, 0, 2, 0);  // e2 l4 -> moe
  p4.op[3] = mk(e3b, mw(11), nullptr, nullptr, 2048, 8, 0, 2, 0); // e3 out -> moe
  gemm_moe_k<<<dim3(16, 72), dim3(256), 0, stream>>>(p4, meta, idxP, wts, moe);

  comb_k<<<dim3(4096), dim3(256), 0, stream>>>(outp, moe);
}

// Round 8
// 633.659 us; speedup vs baseline: 1.3127x; 1.0075x over previous
//
#include <hip/hip_runtime.h>
#include <math.h>

#define DIM   1024
#define NTOK  4096
#define TSEQ  1024
#define NHEAD 16
#define MPROT 256
#define EPSR  1.1920929e-07f
#define SA    64.0f
#define SW    256.0f
#define SPC   64.0f
#define MAXI  160

typedef __attribute__((ext_vector_type(8))) short          short8;
typedef __attribute__((ext_vector_type(8))) _Float16       half8;
typedef __attribute__((ext_vector_type(4))) _Float16       half4;
typedef __attribute__((ext_vector_type(4))) float          f32x4;
typedef __attribute__((ext_vector_type(4))) unsigned short us4;

static __device__ __forceinline__ float bf2f(unsigned short s) {
  union { unsigned int u; float f; } c; c.u = ((unsigned int)s) << 16; return c.f;
}
static __device__ __forceinline__ unsigned short f2bf(float f) {
  union { float f; unsigned int u; } c; c.f = f;
  return (unsigned short)((c.u + 0x7fffu + ((c.u >> 16) & 1u)) >> 16);
}
static __device__ __forceinline__ void gload16(void* lds, const void* g) {
  __builtin_amdgcn_global_load_lds(
      (__attribute__((address_space(1))) void*)const_cast<void*>(g),
      (__attribute__((address_space(3))) void*)lds, 16, 0, 0);
}

// XCD swizzle for dense split-GEMMs: stripe m-blocks across XCDs.
static __device__ __forceinline__ void tile_swz(int& m0, int& n0) {
  const int gx = gridDim.x;
  const int L = blockIdx.y * gx + blockIdx.x;
  const int xcd = L & 7;
  const int j = L >> 3;
  const int mbq = j / gx;
  const int nb = j - mbq * gx;
  m0 = ((mbq << 3) | xcd) << 7;
  n0 = nb << 7;
}

// ---------------- conversions ----------------
__global__ __launch_bounds__(256) void cvt_attn4_k(const float* __restrict__ wq,
                                                   const float* __restrict__ wk,
                                                   const float* __restrict__ wv,
                                                   const float* __restrict__ wo,
                                                   _Float16* __restrict__ dh,
                                                   _Float16* __restrict__ dl) {
  const int wi = blockIdx.y;
  const float* s = (wi == 0) ? wq : (wi == 1) ? wk : (wi == 2) ? wv : wo;
  const int i = blockIdx.x * 256 + threadIdx.x;
  const size_t off4 = ((size_t)wi << 20) >> 2;
  const float4 v = ((const float4*)s)[i];
  float a0 = v.x * SW, a1 = v.y * SW, a2 = v.z * SW, a3 = v.w * SW;
  half4 hv, lv;
  _Float16 h0 = (_Float16)a0; hv[0] = h0; lv[0] = (_Float16)(a0 - (float)h0);
  _Float16 h1 = (_Float16)a1; hv[1] = h1; lv[1] = (_Float16)(a1 - (float)h1);
  _Float16 h2 = (_Float16)a2; hv[2] = h2; lv[2] = (_Float16)(a2 - (float)h2);
  _Float16 h3 = (_Float16)a3; hv[3] = h3; lv[3] = (_Float16)(a3 - (float)h3);
  ((half4*)dh)[off4 + i] = hv; ((half4*)dl)[off4 + i] = lv;
}

__global__ __launch_bounds__(256) void cvt_moe_all_k(
    const float* s0, const float* s1, const float* s2, const float* s3,
    const float* s4, const float* s5, const float* s6, const float* s7,
    const float* s8, const float* s9, const float* s10, const float* s11,
    unsigned short* __restrict__ dst) {
  const int n4tab[12] = {524288, 524288, 524288, 524288, 524288, 524288,
                         1048576, 1048576, 524288, 262144, 524288, 524288};
  const size_t offtab[12] = {0, 2097152, 4194304, 6291456, 8388608, 10485760,
                             12582912, 16777216, 20971520, 23068672, 24117248, 26214400};
  const int wi = blockIdx.y;
  const int i = blockIdx.x * 256 + threadIdx.x;
  if (i >= n4tab[wi]) return;
  const float* s;
  switch (wi) {
    case 0: s = s0; break; case 1: s = s1; break; case 2: s = s2; break;
    case 3: s = s3; break; case 4: s = s4; break; case 5: s = s5; break;
    case 6: s = s6; break; case 7: s = s7; break; case 8: s = s8; break;
    case 9: s = s9; break; case 10: s = s10; break; default: s = s11; break;
  }
  const float4 v = ((const float4*)s)[i];
  us4 o; o[0] = f2bf(v.x); o[1] = f2bf(v.y); o[2] = f2bf(v.z); o[3] = f2bf(v.w);
  ((us4*)(dst + offtab[wi]))[i] = o;
}

// ---------------- RMS norms ----------------
__global__ __launch_bounds__(256) void rms_split_k(const float* __restrict__ in,
                                                   const float* __restrict__ wgt,
                                                   _Float16* __restrict__ oh,
                                                   _Float16* __restrict__ ol) {
  const int row = blockIdx.x, tid = threadIdx.x;
  const float4 v = ((const float4*)(in + (size_t)row * DIM))[tid];
  float ss = v.x * v.x + v.y * v.y + v.z * v.z + v.w * v.w;
#pragma unroll
  for (int o = 32; o; o >>= 1) ss += __shfl_xor(ss, o);
  __shared__ float red[4];
  if ((tid & 63) == 0) red[tid >> 6] = ss;
  __syncthreads();
  const float sc = rsqrtf((red[0] + red[1] + red[2] + red[3]) * (1.0f / DIM) + EPSR) * SA;
  const float4 wv = ((const float4*)wgt)[tid];
  float a[4] = {v.x * sc * wv.x, v.y * sc * wv.y, v.z * sc * wv.z, v.w * sc * wv.w};
  half4 hv, lv;
#pragma unroll
  for (int j = 0; j < 4; ++j) {
    _Float16 hh = (_Float16)a[j]; hv[j] = hh; lv[j] = (_Float16)(a[j] - (float)hh);
  }
  ((half4*)(oh + (size_t)row * DIM))[tid] = hv;
  ((half4*)(ol + (size_t)row * DIM))[tid] = lv;
}

// fused RMSNorm(bf16 out) + gate logits/softmax/top-2 + moe buffer zeroing
__global__ __launch_bounds__(256) void rmsgate_k(const float* __restrict__ x2,
                                                 const float* __restrict__ n2w,
                                                 const float* __restrict__ gw,
                                                 unsigned short* __restrict__ xfb,
                                                 float* __restrict__ wts,
                                                 float* __restrict__ moe) {
  const int row = blockIdx.x, tid = threadIdx.x;
  ((float4*)(moe + (size_t)row * DIM))[tid] = (float4){0.f, 0.f, 0.f, 0.f};
  const float4 v = ((const float4*)(x2 + (size_t)row * DIM))[tid];
  float ss = v.x * v.x + v.y * v.y + v.z * v.z + v.w * v.w;
#pragma unroll
  for (int o = 32; o; o >>= 1) ss += __shfl_xor(ss, o);
  __shared__ float red[4];
  __shared__ float redE[4][4];
  const int w = tid >> 6, lane = tid & 63;
  if (lane == 0) red[w] = ss;
  __syncthreads();
  const float sc = rsqrtf((red[0] + red[1] + red[2] + red[3]) * (1.0f / DIM) + EPSR);
  const float4 nw = ((const float4*)n2w)[tid];
  const float xn0 = v.x * sc * nw.x, xn1 = v.y * sc * nw.y;
  const float xn2 = v.z * sc * nw.z, xn3 = v.w * sc * nw.w;
  us4 ob; ob[0] = f2bf(xn0); ob[1] = f2bf(xn1); ob[2] = f2bf(xn2); ob[3] = f2bf(xn3);
  ((us4*)(xfb + (size_t)row * DIM))[tid] = ob;
#pragma unroll
  for (int e = 0; e < 4; ++e) {
    const float4 g = ((const float4*)(gw + (size_t)e * DIM))[tid];
    float d = xn0 * g.x + xn1 * g.y + xn2 * g.z + xn3 * g.w;
#pragma unroll
    for (int o = 32; o; o >>= 1) d += __shfl_xor(d, o);
    if (lane == 0) redE[w][e] = d;
  }
  __syncthreads();
  if (tid == 0) {
    float lg[4];
#pragma unroll
    for (int e = 0; e < 4; ++e) lg[e] = redE[0][e] + redE[1][e] + redE[2][e] + redE[3][e];
    const float mx = fmaxf(fmaxf(lg[0], lg[1]), fmaxf(lg[2], lg[3]));
    float pe[4]; float sum = 0.0f;
#pragma unroll
    for (int e = 0; e < 4; ++e) { pe[e] = __expf(lg[e] - mx); sum += pe[e]; }
#pragma unroll
    for (int e = 0; e < 4; ++e) pe[e] /= sum;
    int i1 = 0;
    for (int e = 1; e < 4; ++e) if (pe[e] > pe[i1]) i1 = e;
    int i2 = -1;
    for (int e = 0; e < 4; ++e) { if (e == i1) continue; if (i2 < 0 || pe[e] > pe[i2]) i2 = e; }
    const float s2 = pe[i1] + pe[i2] + 1e-8f;
    float o[4] = {0.f, 0.f, 0.f, 0.f};
    o[i1] = pe[i1] / s2; o[i2] = pe[i2] / s2;
    float4 r; r.x = o[0]; r.y = o[1]; r.z = o[2]; r.w = o[3];
    *(float4*)(wts + (size_t)row * 4) = r;
  }
}

// per (token,head) RMS over 64 dims; y=0 -> Q planes, y=1 -> K planes
__global__ __launch_bounds__(256) void qknorm2_k(_Float16* __restrict__ qh,
                                                 _Float16* __restrict__ ql,
                                                 _Float16* __restrict__ kh,
                                                 _Float16* __restrict__ kl,
                                                 const float* __restrict__ qnw,
                                                 const float* __restrict__ knw) {
  _Float16* ph; _Float16* pl; const float* wgt;
  if (blockIdx.y == 0) { ph = qh; pl = ql; wgt = qnw; }
  else { ph = kh; pl = kl; wgt = knw; }
  const int idx = (blockIdx.x << 2) + (threadIdx.x >> 6);
  const int lane = threadIdx.x & 63;
  const size_t off = ((size_t)idx << 6) + lane;
  const float v = (float)ph[off] + (float)pl[off];
  float ss = v * v;
#pragma unroll
  for (int o = 32; o; o >>= 1) ss += __shfl_xor(ss, o);
  const float sc = rsqrtf(ss * (1.0f / (64.0f * SA * SA)) + EPSR);
  const float nv = v * sc * wgt[lane];
  _Float16 hh = (_Float16)nv;
  ph[off] = hh; pl[off] = (_Float16)(nv - (float)hh);
}

// ---------------- routing + dense per-XCD work lists ----------------
// idxP[prow]=token or -1; meta[0..71]=mb->expert(-1); meta[80+e]=slab base row
// work[phase][i][xcd] (i<MAXI): item = mb | nb<<8 | kpart<<16, or -1
struct MoeCfg { int nbn[4][4]; int ks[4][4]; };

__global__ __launch_bounds__(256) void route2_k(const float* __restrict__ wts,
                                                int* __restrict__ idxP,
                                                int* __restrict__ meta,
                                                int* __restrict__ work,
                                                MoeCfg cfg) {
  const int tid = threadIdx.x, w = tid >> 6, lane = tid & 63;
  __shared__ int wsum[4];
  __shared__ int baseS;
  int off = 0;
  for (int e = 0; e < 4; ++e) {
    if (tid == 0) baseS = 0;
    __syncthreads();
    for (int c = 0; c < 16; ++c) {
      const int tok = (c << 8) + tid;
      const bool pred = wts[(size_t)tok * 4 + e] > 0.0f;
      const unsigned long long m = __ballot(pred);
      const int lanepre = __popcll(m & ((1ull << lane) - 1ull));
      if (lane == 0) wsum[w] = __popcll(m);
      __syncthreads();
      int wpre = 0;
#pragma unroll
      for (int i = 0; i < 4; ++i) wpre += (i < w) ? wsum[i] : 0;
      const int tot = wsum[0] + wsum[1] + wsum[2] + wsum[3];
      if (pred) idxP[off + baseS + wpre + lanepre] = tok;
      __syncthreads();
      if (tid == 0) baseS += tot;
      __syncthreads();
    }
    const int cnt = baseS;
    const int padded = (cnt + 127) & ~127;
    for (int j = cnt + tid; j < padded; j += 256) idxP[off + j] = -1;
    if (tid == 0) meta[80 + e] = off;
    const int mb0 = off >> 7, nmb = padded >> 7;
    for (int j = tid; j < nmb; j += 256) meta[mb0 + j] = e;
    off += padded;
    __syncthreads();
  }
  for (int j = (off >> 7) + tid; j < 72; j += 256) meta[j] = -1;
  // init work lists to -1
  for (int j = tid; j < 4 * 8 * MAXI; j += 256) work[j] = -1;
  __syncthreads();
  // build dense per-(phase,xcd) item queues; thread = (phase<<3)|xcd
  if (tid < 32) {
    const int p = tid >> 3, x = tid & 7;
    int* wb = work + p * (8 * MAXI);
    int n = 0;
    const int totmb = off >> 7;
    for (int mb = x; mb < totmb; mb += 8) {
      const int e = meta[mb];
      const int nbn = cfg.nbn[p][e];
      const int ks = cfg.ks[p][e];
      for (int nb = 0; nb < nbn; ++nb)
        for (int k = 0; k < ks; ++k) {
          wb[n * 8 + x] = mb | (nb << 8) | (k << 16);
          ++n;
        }
    }
  }
}

// ---------------- packed grouped sparse bf16 GEMM (single-buffer LDS, work-list) ----------------
struct SubOpP {
  const unsigned short* A;
  const unsigned short* Bw;
  unsigned short* outb;
  const unsigned short* other;
  int K, nbn, act, ep, gath, ks;  // ep: 0 store, 1 silu*other, 2 scatter atomicAdd
};
struct PhaseP { SubOpP op[4]; };  // indexed by expert

__global__ __launch_bounds__(256, 4) void gemm_moe_k(PhaseP ph,
                                                     const int* __restrict__ meta,
                                                     const int* __restrict__ idxP,
                                                     const float* __restrict__ wts,
                                                     float* __restrict__ moe,
                                                     const int* __restrict__ wk) {
  __shared__ unsigned short As[128][64];
  __shared__ unsigned short Bs[128][64];
  const int item = wk[blockIdx.y * 8 + blockIdx.x];
  if (item < 0) return;
  const int mb = item & 255;
  const int nb = (item >> 8) & 255;
  const int kpart = (item >> 16) & 3;
  const int e = meta[mb];
  SubOpP op;
  switch (e) {
    case 0: op = ph.op[0]; break;
    case 1: op = ph.op[1]; break;
    case 2: op = ph.op[2]; break;
    default: op = ph.op[3]; break;
  }
  const int m0p = mb << 7;                 // packed row base
  const int lr0 = m0p - meta[80 + e];      // local (compact) row base
  const int n0 = nb << 7;
  const int F = op.nbn << 7;
  const int K = op.K;
  const int tid = threadIdx.x;
  const int w = tid >> 6, lane = tid & 63;
  const int wr = ((w >> 1) << 6), wc = ((w & 1) << 6);
  const int rr = lane & 15, kgl = lane >> 4;
  const int srow = tid >> 3, sslot = tid & 7;

  int grow[4];
#pragma unroll
  for (int i = 0; i < 4; ++i) {
    const int r = (i << 5) + srow;
    if (op.gath) {
      const int t = idxP[m0p + r];
      grow[i] = (t < 0) ? 0 : t;
    } else {
      grow[i] = lr0 + r;
    }
  }

  f32x4 acc[4][4];
#pragma unroll
  for (int a_ = 0; a_ < 4; ++a_)
#pragma unroll
    for (int b_ = 0; b_ < 4; ++b_) acc[a_][b_] = (f32x4){0.f, 0.f, 0.f, 0.f};

  int kt0 = 0, ktN = K >> 6;
  if (op.ks == 2) { const int hgt = ktN >> 1; kt0 = kpart * hgt; ktN = kt0 + hgt; }
  for (int kt = kt0; kt < ktN; ++kt) {
    const int k0 = kt << 6;
#pragma unroll
    for (int i = 0; i < 4; ++i) {
      const int r = (i << 5) + srow;
      const int ls = sslot ^ (r & 7);
      gload16(&As[(i << 5) + (w << 3)][0], op.A + (size_t)grow[i] * K + k0 + (ls << 3));
      gload16(&Bs[(i << 5) + (w << 3)][0], op.Bw + (size_t)(n0 + r) * K + k0 + (ls << 3));
    }
    __syncthreads();
    short8 af[4][2], bfr[4][2];
#pragma unroll
    for (int f = 0; f < 4; ++f) {
#pragma unroll
      for (int ks = 0; ks < 2; ++ks) {
        const int row = wr + (f << 4) + rr;
        const int kg = (ks << 2) + kgl;
        af[f][ks] = *(const short8*)&As[row][(kg ^ (row & 7)) << 3];
        const int col = wc + (f << 4) + rr;
        bfr[f][ks] = *(const short8*)&Bs[col][(kg ^ (col & 7)) << 3];
      }
    }
#pragma unroll
    for (int fi = 0; fi < 4; ++fi)
#pragma unroll
      for (int fj = 0; fj < 4; ++fj)
#pragma unroll
        for (int ks = 0; ks < 2; ++ks)
          acc[fi][fj] = __builtin_amdgcn_mfma_f32_16x16x32_bf16(
              af[fi][ks], bfr[fj][ks], acc[fi][fj], 0, 0, 0);
    __syncthreads();
  }
#pragma unroll
  for (int fi = 0; fi < 4; ++fi)
#pragma unroll
    for (int fj = 0; fj < 4; ++fj) {
      const int col = n0 + wc + (fj << 4) + rr;
#pragma unroll
      for (int r = 0; r < 4; ++r) {
        const int rl = wr + (fi << 4) + (kgl << 2) + r;
        float v = acc[fi][fj][r];
        if (op.act) v = 0.5f * v * (1.0f + erff(v * 0.70710678118654752f));
        if (op.ep == 0) {
          op.outb[(size_t)(lr0 + rl) * F + col] = f2bf(v);
        } else if (op.ep == 1) {
          const size_t off = (size_t)(lr0 + rl) * F + col;
          const float sv = v / (1.0f + __expf(-v));
          op.outb[off] = f2bf(sv * bf2f(op.other[off]));
        } else {
          const int tok = idxP[m0p + rl];
          if (tok >= 0)
            atomicAdd(&moe[(size_t)tok * DIM + col], wts[(size_t)tok * 4 + e] * v);
        }
      }
    }
}

// ---------------- fp16x2 split GEMM (3-term), single-buffer LDS ----------------
// EP: 1 = fp32: resid + masked(v); 3 = fused QKV epilogue (q/k planes + V^T planes)
template <int EP>
__global__ __launch_bounds__(256, 4) void gemm_split_k(
    const _Float16* __restrict__ Ah, const _Float16* __restrict__ Al,
    const _Float16* __restrict__ Bh, const _Float16* __restrict__ Bl,
    int K, int F,
    _Float16* __restrict__ Oh, _Float16* __restrict__ Ol, float oscale,
    const float* __restrict__ resid, float* __restrict__ outf,
    _Float16* __restrict__ K2h, _Float16* __restrict__ K2l,
    _Float16* __restrict__ V2h, _Float16* __restrict__ V2l) {
  __shared__ _Float16 AsH[128][32], AsL[128][32];
  __shared__ _Float16 BsH[128][32], BsL[128][32];
  const int tid = threadIdx.x;
  const int w = tid >> 6, lane = tid & 63;
  const int wr = ((w >> 1) << 6), wc = ((w & 1) << 6);
  int m0, n0;
  tile_swz(m0, n0);
  const int rr = lane & 15, kgl = lane >> 4;
  const int srow = tid >> 2, sslot = tid & 3;

  f32x4 acc[4][4];
#pragma unroll
  for (int a_ = 0; a_ < 4; ++a_)
#pragma unroll
    for (int b_ = 0; b_ < 4; ++b_) acc[a_][b_] = (f32x4){0.f, 0.f, 0.f, 0.f};

  const int KT = K >> 5;
  for (int kt = 0; kt < KT; ++kt) {
    const int k0 = kt << 5;
#pragma unroll
    for (int i = 0; i < 2; ++i) {
      const int r = (i << 6) + srow;
      const int ls = sslot ^ ((r >> 1) & 3);
      const size_t ga = (size_t)(m0 + r) * K + k0 + (ls << 3);
      const size_t gb = (size_t)(n0 + r) * K + k0 + (ls << 3);
      const int lr = (i << 6) + (w << 4);
      gload16(&AsH[lr][0], Ah + ga);
      gload16(&AsL[lr][0], Al + ga);
      gload16(&BsH[lr][0], Bh + gb);
      gload16(&BsL[lr][0], Bl + gb);
    }
    __syncthreads();
    half8 ah[4], al[4], bh[4], bl[4];
#pragma unroll
    for (int f = 0; f < 4; ++f) {
      const int row = wr + (f << 4) + rr;
      const int pa = (kgl ^ ((row >> 1) & 3)) << 3;
      ah[f] = *(const half8*)&AsH[row][pa];
      al[f] = *(const half8*)&AsL[row][pa];
      const int col = wc + (f << 4) + rr;
      const int pb = (kgl ^ ((col >> 1) & 3)) << 3;
      bh[f] = *(const half8*)&BsH[col][pb];
      bl[f] = *(const half8*)&BsL[col][pb];
    }
#pragma unroll
    for (int fi = 0; fi < 4; ++fi)
#pragma unroll
      for (int fj = 0; fj < 4; ++fj) {
        acc[fi][fj] = __builtin_amdgcn_mfma_f32_16x16x32_f16(ah[fi], bh[fj], acc[fi][fj], 0, 0, 0);
        acc[fi][fj] = __builtin_amdgcn_mfma_f32_16x16x32_f16(ah[fi], bl[fj], acc[fi][fj], 0, 0, 0);
        acc[fi][fj] = __builtin_amdgcn_mfma_f32_16x16x32_f16(al[fi], bh[fj], acc[fi][fj], 0, 0, 0);
      }
    __syncthreads();
  }
#pragma unroll
  for (int fi = 0; fi < 4; ++fi)
#pragma unroll
    for (int fj = 0; fj < 4; ++fj) {
      const int col = n0 + wc + (fj << 4) + rr;
      const int rowb = m0 + wr + (fi << 4) + (kgl << 2);
      if (EP == 3) {
        if (col < 2048) {
          _Float16* ph = (col < 1024) ? Oh : K2h;
          _Float16* pl = (col < 1024) ? Ol : K2l;
          const int c = col & 1023;
#pragma unroll
          for (int r = 0; r < 4; ++r) {
            const float v = acc[fi][fj][r] * oscale;
            const _Float16 hh2 = (_Float16)v;
            const size_t off = (size_t)(rowb + r) * DIM + c;
            ph[off] = hh2; pl[off] = (_Float16)(v - (float)hh2);
          }
        } else {
          const int c2 = col - 2048;
          half4 h4, l4;
#pragma unroll
          for (int r = 0; r < 4; ++r) {
            const float v = acc[fi][fj][r] * oscale;
            const _Float16 hh2 = (_Float16)v;
            h4[r] = hh2; l4[r] = (_Float16)(v - (float)hh2);
          }
          const size_t vt = ((size_t)((rowb >> 10) << 4) + (size_t)(c2 >> 6)) * 65536 +
                            (size_t)(c2 & 63) * 1024 + (size_t)(rowb & 1023);
          *(half4*)&V2h[vt] = h4;
          *(half4*)&V2l[vt] = l4;
        }
      } else {
#pragma unroll
        for (int r = 0; r < 4; ++r) {
          const size_t off = (size_t)(rowb + r) * F + col;
          const float v = acc[fi][fj][r] * oscale;
          outf[off] = resid[off] + (col >= MPROT ? v : 0.0f);
        }
      }
    }
}

// ---------------- flash attention, causal, fp16x2 split, swapped-QK ----------------
__global__ __launch_bounds__(256, 2) void attn_k(
    const _Float16* __restrict__ Qh, const _Float16* __restrict__ Ql,
    const _Float16* __restrict__ Kh, const _Float16* __restrict__ Kl,
    const _Float16* __restrict__ Vth, const _Float16* __restrict__ Vtl,
    _Float16* __restrict__ Oh, _Float16* __restrict__ Ol) {
  __shared__ _Float16 Ksh[2][32][64], Ksl[2][32][64];
  __shared__ _Float16 Vsh[2][64][40], Vsl[2][64][40];
  __shared__ _Float16 Plh[4][16][40], Pll[4][16][40];
  const int n = blockIdx.x;
  const int qt = n >> 6;
  const int bh = ((n & 7) << 3) | ((n >> 3) & 7);
  const int b = bh >> 4, h = bh & 15;
  const int tid = threadIdx.x, w = tid >> 6, lane = tid & 63;
  const int rr = lane & 15, rg = lane >> 4;
  const size_t tokbase = (size_t)b * TSEQ;
  const int hcol = h << 6;
  const size_t vtbase = (size_t)bh << 16;
  const int q0w = (qt << 7) + (w << 5);
  const float sscale = 0.125f / (SA * SA);

  half8 qfh[2][2], qfl[2][2];
#pragma unroll
  for (int qf = 0; qf < 2; ++qf)
#pragma unroll
    for (int ks = 0; ks < 2; ++ks) {
      const size_t off = (tokbase + q0w + (qf << 4) + rr) * DIM + hcol + (ks << 5) + (rg << 3);
      qfh[qf][ks] = *(const half8*)&Qh[off];
      qfl[qf][ks] = *(const half8*)&Ql[off];
    }

  f32x4 oacc[2][4];
#pragma unroll
  for (int qf = 0; qf < 2; ++qf)
#pragma unroll
    for (int dg = 0; dg < 4; ++dg) oacc[qf][dg] = (f32x4){0.f, 0.f, 0.f, 0.f};
  float mreg[2] = {-INFINITY, -INFINITY}, lreg[2] = {0.f, 0.f};

  const int kr = (w << 3) + (lane >> 3);
  const int kswz = ((lane & 7) ^ (kr & 7)) << 3;
  const int vr = tid >> 2;
  const int vs = (tid & 3) << 3;

  const int ntiles = (qt + 1) << 2;

  {
    gload16(&Ksh[0][w << 3][0], &Kh[(tokbase + kr) * DIM + hcol + kswz]);
    gload16(&Ksl[0][w << 3][0], &Kl[(tokbase + kr) * DIM + hcol + kswz]);
    const half8 vvh = *(const half8*)&Vth[vtbase + (size_t)vr * TSEQ + vs];
    const half8 vvl = *(const half8*)&Vtl[vtbase + (size_t)vr * TSEQ + vs];
    *(half8*)&Vsh[0][vr][vs] = vvh;
    *(half8*)&Vsl[0][vr][vs] = vvl;
    __syncthreads();
  }

  for (int t = 0; t < ntiles; ++t) {
    const int cur = t & 1;
    const int kv0 = t << 5;
    const bool havenext = (t + 1 < ntiles);
    half8 nvh, nvl;
    if (havenext) {
      const int kn = kv0 + 32;
      gload16(&Ksh[cur ^ 1][w << 3][0], &Kh[(tokbase + kn + kr) * DIM + hcol + kswz]);
      gload16(&Ksl[cur ^ 1][w << 3][0], &Kl[(tokbase + kn + kr) * DIM + hcol + kswz]);
      nvh = *(const half8*)&Vth[vtbase + (size_t)vr * TSEQ + kn + vs];
      nvl = *(const half8*)&Vtl[vtbase + (size_t)vr * TSEQ + kn + vs];
    }
    if (kv0 <= q0w + 31) {
      half8 kfh[2][2], kfl[2][2];
#pragma unroll
      for (int kt = 0; kt < 2; ++kt)
#pragma unroll
        for (int ks = 0; ks < 2; ++ks) {
          const int row = (kt << 4) + rr;
          const int sw = ((((ks << 2) + rg)) ^ (row & 7)) << 3;
          kfh[kt][ks] = *(const half8*)&Ksh[cur][row][sw];
          kfl[kt][ks] = *(const half8*)&Ksl[cur][row][sw];
        }
#pragma unroll
      for (int qf = 0; qf < 2; ++qf) {
        if (kv0 > q0w + (qf << 4) + 15) continue;
        f32x4 st[2];
        st[0] = (f32x4){0.f, 0.f, 0.f, 0.f};
        st[1] = (f32x4){0.f, 0.f, 0.f, 0.f};
#pragma unroll
        for (int kt = 0; kt < 2; ++kt)
#pragma unroll
          for (int ks = 0; ks < 2; ++ks) {
            st[kt] = __builtin_amdgcn_mfma_f32_16x16x32_f16(kfh[kt][ks], qfh[qf][ks], st[kt], 0, 0, 0);
            st[kt] = __builtin_amdgcn_mfma_f32_16x16x32_f16(kfh[kt][ks], qfl[qf][ks], st[kt], 0, 0, 0);
            st[kt] = __builtin_amdgcn_mfma_f32_16x16x32_f16(kfl[kt][ks], qfh[qf][ks], st[kt], 0, 0, 0);
          }
        const int qg = q0w + (qf << 4) + rr;
        float s[2][4]; float mx = -INFINITY;
#pragma unroll
        for (int kt = 0; kt < 2; ++kt)
#pragma unroll
          for (int r = 0; r < 4; ++r) {
            float sv = st[kt][r] * sscale;
            if (kv0 + (kt << 4) + (rg << 2) + r > qg) sv = -INFINITY;
            s[kt][r] = sv; mx = fmaxf(mx, sv);
          }
        mx = fmaxf(mx, __shfl_xor(mx, 16));
        mx = fmaxf(mx, __shfl_xor(mx, 32));
        const float mn = fmaxf(mreg[qf], mx);
        const float al = __expf(mreg[qf] - mn);
        mreg[qf] = mn;
        float p[2][4]; float rs = 0.f;
#pragma unroll
        for (int kt = 0; kt < 2; ++kt)
#pragma unroll
          for (int r = 0; r < 4; ++r) { p[kt][r] = __expf(s[kt][r] - mn); rs += p[kt][r]; }
        rs += __shfl_xor(rs, 16);
        rs += __shfl_xor(rs, 32);
        lreg[qf] = lreg[qf] * al + rs;
#pragma unroll
        for (int kt = 0; kt < 2; ++kt) {
          half4 h4, l4;
#pragma unroll
          for (int r = 0; r < 4; ++r) {
            const float pv = p[kt][r] * SPC;
            const _Float16 ph = (_Float16)pv;
            h4[r] = ph; l4[r] = (_Float16)(pv - (float)ph);
          }
          *(half4*)&Plh[w][rr][(kt << 4) + (rg << 2)] = h4;
          *(half4*)&Pll[w][rr][(kt << 4) + (rg << 2)] = l4;
        }
        float alr[4];
#pragma unroll
        for (int r = 0; r < 4; ++r) alr[r] = __shfl(al, (lane & 48) | ((rg << 2) + r));
#pragma unroll
        for (int dg = 0; dg < 4; ++dg)
#pragma unroll
          for (int r = 0; r < 4; ++r) oacc[qf][dg][r] *= alr[r];
        const half8 pah = *(const half8*)&Plh[w][rr][rg << 3];
        const half8 pal = *(const half8*)&Pll[w][rr][rg << 3];
#pragma unroll
        for (int dg = 0; dg < 4; ++dg) {
          const half8 vfh2 = *(const half8*)&Vsh[cur][(dg << 4) + rr][rg << 3];
          const half8 vfl2 = *(const half8*)&Vsl[cur][(dg << 4) + rr][rg << 3];
          oacc[qf][dg] = __builtin_amdgcn_mfma_f32_16x16x32_f16(pah, vfh2, oacc[qf][dg], 0, 0, 0);
          oacc[qf][dg] = __builtin_amdgcn_mfma_f32_16x16x32_f16(pah, vfl2, oacc[qf][dg], 0, 0, 0);
          oacc[qf][dg] = __builtin_amdgcn_mfma_f32_16x16x32_f16(pal, vfh2, oacc[qf][dg], 0, 0, 0);
        }
      }
    }
    if (havenext) {
      *(half8*)&Vsh[cur ^ 1][vr][vs] = nvh;
      *(half8*)&Vsl[cur ^ 1][vr][vs] = nvl;
    }
    __syncthreads();
  }
#pragma unroll
  for (int qf = 0; qf < 2; ++qf) {
    float li[4];
#pragma unroll
    for (int r = 0; r < 4; ++r)
      li[r] = __shfl(lreg[qf], (lane & 48) | ((rg << 2) + r));
#pragma unroll
    for (int dg = 0; dg < 4; ++dg)
#pragma unroll
      for (int r = 0; r < 4; ++r) {
        const int qloc = (rg << 2) + r;
        const float ov = oacc[qf][dg][r] / (li[r] * SPC);
        const _Float16 hh2 = (_Float16)ov;
        const size_t off = (tokbase + q0w + (qf << 4) + qloc) * DIM + hcol + (dg << 4) + rr;
        Oh[off] = hh2;
        Ol[off] = (_Float16)(ov - (float)hh2);
      }
  }
}

// ---------------- final combine: outp += mask(moe) ----------------
__global__ __launch_bounds__(256) void comb_k(float* __restrict__ outp,
                                              const float* __restrict__ moe) {
  const size_t i = (size_t)blockIdx.x * 256 + threadIdx.x;
  const int c4 = (int)(i & 255);
  if (c4 >= 64) {
    float4 o = ((float4*)outp)[i];
    const float4 m = ((const float4*)moe)[i];
    o.x += m.x; o.y += m.y; o.z += m.z; o.w += m.w;
    ((float4*)outp)[i] = o;
  }
}

extern "C" void kernel_launch(void* const* d_in, const int* in_sizes, int n_in,
                              void* d_out, int out_size, void* d_ws, size_t ws_size,
                              hipStream_t stream) {
  (void)in_sizes; (void)n_in; (void)out_size; (void)ws_size;
  const float* x    = (const float*)d_in[0];
  const float* n1w  = (const float*)d_in[1];
  const float* n2w  = (const float*)d_in[2];
  const float* wq   = (const float*)d_in[3];
  const float* wk   = (const float*)d_in[4];
  const float* wv   = (const float*)d_in[5];
  const float* wo   = (const float*)d_in[6];
  const float* qnw  = (const float*)d_in[7];
  const float* knw  = (const float*)d_in[8];
  const float* gw   = (const float*)d_in[9];
  const float* moesrc[12] = {
    (const float*)d_in[10], (const float*)d_in[11],
    (const float*)d_in[12], (const float*)d_in[13], (const float*)d_in[14],
    (const float*)d_in[15], (const float*)d_in[16], (const float*)d_in[17], (const float*)d_in[18],
    (const float*)d_in[19], (const float*)d_in[20], (const float*)d_in[21]
  };
  float* outp = (float*)d_out;

  char* p = (char*)d_ws;
  auto alloc = [&](size_t bytes) { void* r = (void*)p; p += (bytes + 255) & ~(size_t)255; return r; };
  const size_t NC = (size_t)NTOK * DIM;
  _Float16* hh = (_Float16*)alloc(NC * 2);
  _Float16* hl = (_Float16*)alloc(NC * 2);
  _Float16* qh = (_Float16*)alloc(NC * 2);   // qh..vtl: 48 MB contiguous, reused as MoE arena
  _Float16* ql = (_Float16*)alloc(NC * 2);
  _Float16* kh = (_Float16*)alloc(NC * 2);
  _Float16* kl = (_Float16*)alloc(NC * 2);
  _Float16* vth = (_Float16*)alloc(NC * 2);
  _Float16* vtl = (_Float16*)alloc(NC * 2);
  unsigned short* xfb = (unsigned short*)alloc(NC * 2);
  float* moe = (float*)alloc(NC * 4);
  float* wts = (float*)alloc((size_t)NTOK * 4 * 4);
  _Float16* awh = (_Float16*)alloc((size_t)4 * 1024 * 1024 * 2);
  _Float16* awl = (_Float16*)alloc((size_t)4 * 1024 * 1024 * 2);
  unsigned short* moeW = (unsigned short*)alloc((size_t)28311552 * 2);
  int* idxP = (int*)alloc((size_t)9216 * 4);
  int* meta = (int*)alloc(512);
  int* work = (int*)alloc((size_t)4 * 8 * MAXI * 4);
  // MoE intermediate arena: alias dead q/k/v planes + fresh tail
  unsigned short* e0t = (unsigned short*)qh;    // 16 MB (qh+ql)
  unsigned short* e1a = (unsigned short*)kh;    // 16 MB (kh+kl)
  unsigned short* e2a = (unsigned short*)vth;   // 16 MB (vth+vtl), reused as e2c
  unsigned short* e1b = (unsigned short*)alloc((size_t)NTOK * 2048 * 2);
  unsigned short* e2b = (unsigned short*)alloc((size_t)NTOK * 2048 * 2);
  unsigned short* e3a = (unsigned short*)alloc((size_t)NTOK * 1024 * 2);
  unsigned short* e3b = (unsigned short*)alloc((size_t)NTOK * 2048 * 2);
  unsigned short* e2c = e2a;

  const size_t moff[12] = {0, 2097152, 4194304, 6291456, 8388608, 10485760,
                           12582912, 16777216, 20971520, 23068672, 24117248, 26214400};
  auto mw = [&](int i) -> const unsigned short* { return moeW + moff[i]; };

  // ---- weight conversions ----
  cvt_attn4_k<<<dim3(1024, 4), dim3(256), 0, stream>>>(wq, wk, wv, wo, awh, awl);
  cvt_moe_all_k<<<dim3(4096, 12), dim3(256), 0, stream>>>(
      moesrc[0], moesrc[1], moesrc[2], moesrc[3], moesrc[4], moesrc[5],
      moesrc[6], moesrc[7], moesrc[8], moesrc[9], moesrc[10], moesrc[11], moeW);
  const _Float16* woh = awh + (3 << 20); const _Float16* wol = awl + (3 << 20);

  // ---- attention path (fp16x2) ----
  rms_split_k<<<dim3(NTOK), dim3(256), 0, stream>>>(x, n1w, hh, hl);
  gemm_split_k<3><<<dim3(24, 32), dim3(256), 0, stream>>>(
      hh, hl, awh, awl, 1024, 3072, qh, ql, 1.0f / SW, nullptr, nullptr,
      kh, kl, vth, vtl);
  qknorm2_k<<<dim3(NTOK * NHEAD / 4, 2), dim3(256), 0, stream>>>(qh, ql, kh, kl, qnw, knw);
  attn_k<<<dim3(512), dim3(256), 0, stream>>>(qh, ql, kh, kl, vth, vtl, hh, hl);
  gemm_split_k<1><<<dim3(8, 32), dim3(256), 0, stream>>>(
      hh, hl, woh, wol, 1024, 1024, nullptr, nullptr, 1.0f / (SA * SW), x, outp,
      nullptr, nullptr, nullptr, nullptr);

  // ---- MoE (sparse top-2, dense work-list phases) ----
  rmsgate_k<<<dim3(NTOK), dim3(256), 0, stream>>>(outp, n2w, gw, xfb, wts, moe);

  // phase x expert config (nbn, ksplit); must mirror PhaseP tables below
  MoeCfg cfg;
  const int nbn_tab[4][4] = {{16, 16, 16, 8},
                             {8, 16, 16, 16},
                             {0, 8, 16, 8},
                             {0, 0, 8, 0}};
  const int ks_tab[4][4]  = {{1, 1, 1, 1},
                             {2, 1, 1, 1},
                             {1, 2, 1, 2},
                             {1, 1, 2, 1}};
  for (int pp = 0; pp < 4; ++pp)
    for (int ee = 0; ee < 4; ++ee) { cfg.nbn[pp][ee] = nbn_tab[pp][ee]; cfg.ks[pp][ee] = ks_tab[pp][ee]; }

  route2_k<<<dim3(1), dim3(256), 0, stream>>>(wts, idxP, meta, work, cfg);

  auto mk = [&](const unsigned short* A, const unsigned short* B, unsigned short* outb,
                const unsigned short* other, int K, int nbn, int act, int ep, int gath, int ks) {
    SubOpP s; s.A = A; s.Bw = B; s.outb = outb; s.other = other;
    s.K = K; s.nbn = nbn; s.act = act; s.ep = ep; s.gath = gath; s.ks = ks;
    return s;
  };
  const SubOpP none = mk(nullptr, nullptr, nullptr, nullptr, 1024, 0, 0, 0, 0, 1);

  PhaseP p1;
  p1.op[0] = mk(xfb, mw(0), e0t, nullptr, 1024, 16, 1, 0, 1, 1);  // e0: gelu(x@up)
  p1.op[1] = mk(xfb, mw(3), e1a, nullptr, 1024, 16, 0, 0, 1, 1);  // e1: x@w2 raw
  p1.op[2] = mk(xfb, mw(5), e2a, nullptr, 1024, 16, 1, 0, 1, 1);  // e2: gelu(x@l1)
  p1.op[3] = mk(xfb, mw(9), e3a, nullptr, 1024, 8, 1, 0, 1, 1);   // e3: gelu(x@dn)
  gemm_moe_k<<<dim3(8, MAXI), dim3(256), 0, stream>>>(p1, meta, idxP, wts, moe, work);

  PhaseP p2;
  p2.op[0] = mk(e0t, mw(1), nullptr, nullptr, 2048, 8, 0, 2, 0, 2);  // e0 down -> moe (K-split)
  p2.op[1] = mk(xfb, mw(2), e1b, e1a, 1024, 16, 0, 1, 1, 1);         // e1: silu(x@w1)*e1a
  p2.op[2] = mk(e2a, mw(6), e2b, nullptr, 2048, 16, 1, 0, 0, 1);     // e2: gelu(@l2)
  p2.op[3] = mk(e3a, mw(10), e3b, nullptr, 1024, 16, 1, 0, 0, 1);    // e3: gelu(@up)
  gemm_moe_k<<<dim3(8, MAXI), dim3(256), 0, stream>>>(p2, meta, idxP, wts, moe, work + 8 * MAXI);

  PhaseP p3;
  p3.op[0] = none;
  p3.op[1] = mk(e1b, mw(4), nullptr, nullptr, 2048, 8, 0, 2, 0, 2);  // e1 down -> moe (K-split)
  p3.op[2] = mk(e2b, mw(7), e2c, nullptr, 2048, 16, 1, 0, 0, 1);     // e2: gelu(@l3)
  p3.op[3] = mk(e3b, mw(11), nullptr, nullptr, 2048, 8, 0, 2, 0, 2); // e3 out -> moe (K-split)
  gemm_moe_k<<<dim3(8, MAXI), dim3(256), 0, stream>>>(p3, meta, idxP, wts, moe, work + 16 * MAXI);

  PhaseP p4;
  p4.op[0] = none;
  p4.op[1] = none;
  p4.op[2] = mk(e2c, mw(8), nullptr, nullptr, 2048, 8, 0, 2, 0, 2);  // e2 l4 -> moe (K-split)
  p4.op[3] = none;
  gemm_moe_k<<<dim3(8, MAXI), dim3(256), 0, stream>>>(p4, meta, idxP, wts, moe, work + 24 * MAXI);

  comb_k<<<dim3(4096), dim3(256), 0, stream>>>(outp, moe);
}

// Round 9
// 596.277 us; speedup vs baseline: 1.3950x; 1.0627x over previous
//
#include <hip/hip_runtime.h>
#include <math.h>

#define DIM   1024
#define NTOK  4096
#define TSEQ  1024
#define NHEAD 16
#define MPROT 256
#define EPSR  1.1920929e-07f
#define SA    64.0f
#define SW    256.0f
#define SPC   64.0f
#define MAXI  160

typedef __attribute__((ext_vector_type(8))) short          short8;
typedef __attribute__((ext_vector_type(8))) _Float16       half8;
typedef __attribute__((ext_vector_type(4))) _Float16       half4;
typedef __attribute__((ext_vector_type(4))) float          f32x4;
typedef __attribute__((ext_vector_type(4))) unsigned short us4;

static __device__ __forceinline__ float bf2f(unsigned short s) {
  union { unsigned int u; float f; } c; c.u = ((unsigned int)s) << 16; return c.f;
}
static __device__ __forceinline__ unsigned short f2bf(float f) {
  union { float f; unsigned int u; } c; c.f = f;
  return (unsigned short)((c.u + 0x7fffu + ((c.u >> 16) & 1u)) >> 16);
}
static __device__ __forceinline__ void gload16(void* lds, const void* g) {
  __builtin_amdgcn_global_load_lds(
      (__attribute__((address_space(1))) void*)const_cast<void*>(g),
      (__attribute__((address_space(3))) void*)lds, 16, 0, 0);
}

// XCD swizzle for dense split-GEMMs: stripe m-blocks across XCDs.
static __device__ __forceinline__ void tile_swz(int& m0, int& n0) {
  const int gx = gridDim.x;
  const int L = blockIdx.y * gx + blockIdx.x;
  const int xcd = L & 7;
  const int j = L >> 3;
  const int mbq = j / gx;
  const int nb = j - mbq * gx;
  m0 = ((mbq << 3) | xcd) << 7;
  n0 = nb << 7;
}

// ---------------- conversions ----------------
__global__ __launch_bounds__(256) void cvt_attn4_k(const float* __restrict__ wq,
                                                   const float* __restrict__ wk,
                                                   const float* __restrict__ wv,
                                                   const float* __restrict__ wo,
                                                   _Float16* __restrict__ dh,
                                                   _Float16* __restrict__ dl) {
  const int wi = blockIdx.y;
  const float* s = (wi == 0) ? wq : (wi == 1) ? wk : (wi == 2) ? wv : wo;
  const int i = blockIdx.x * 256 + threadIdx.x;
  const size_t off4 = ((size_t)wi << 20) >> 2;
  const float4 v = ((const float4*)s)[i];
  float a0 = v.x * SW, a1 = v.y * SW, a2 = v.z * SW, a3 = v.w * SW;
  half4 hv, lv;
  _Float16 h0 = (_Float16)a0; hv[0] = h0; lv[0] = (_Float16)(a0 - (float)h0);
  _Float16 h1 = (_Float16)a1; hv[1] = h1; lv[1] = (_Float16)(a1 - (float)h1);
  _Float16 h2 = (_Float16)a2; hv[2] = h2; lv[2] = (_Float16)(a2 - (float)h2);
  _Float16 h3 = (_Float16)a3; hv[3] = h3; lv[3] = (_Float16)(a3 - (float)h3);
  ((half4*)dh)[off4 + i] = hv; ((half4*)dl)[off4 + i] = lv;
}

__global__ __launch_bounds__(256) void cvt_moe_all_k(
    const float* s0, const float* s1, const float* s2, const float* s3,
    const float* s4, const float* s5, const float* s6, const float* s7,
    const float* s8, const float* s9, const float* s10, const float* s11,
    unsigned short* __restrict__ dst) {
  const int n4tab[12] = {524288, 524288, 524288, 524288, 524288, 524288,
                         1048576, 1048576, 524288, 262144, 524288, 524288};
  const size_t offtab[12] = {0, 2097152, 4194304, 6291456, 8388608, 10485760,
                             12582912, 16777216, 20971520, 23068672, 24117248, 26214400};
  const int wi = blockIdx.y;
  const int i = blockIdx.x * 256 + threadIdx.x;
  if (i >= n4tab[wi]) return;
  const float* s;
  switch (wi) {
    case 0: s = s0; break; case 1: s = s1; break; case 2: s = s2; break;
    case 3: s = s3; break; case 4: s = s4; break; case 5: s = s5; break;
    case 6: s = s6; break; case 7: s = s7; break; case 8: s = s8; break;
    case 9: s = s9; break; case 10: s = s10; break; default: s = s11; break;
  }
  const float4 v = ((const float4*)s)[i];
  us4 o; o[0] = f2bf(v.x); o[1] = f2bf(v.y); o[2] = f2bf(v.z); o[3] = f2bf(v.w);
  ((us4*)(dst + offtab[wi]))[i] = o;
}

// ---------------- RMS norms ----------------
__global__ __launch_bounds__(256) void rms_split_k(const float* __restrict__ in,
                                                   const float* __restrict__ wgt,
                                                   _Float16* __restrict__ oh,
                                                   _Float16* __restrict__ ol) {
  const int row = blockIdx.x, tid = threadIdx.x;
  const float4 v = ((const float4*)(in + (size_t)row * DIM))[tid];
  float ss = v.x * v.x + v.y * v.y + v.z * v.z + v.w * v.w;
#pragma unroll
  for (int o = 32; o; o >>= 1) ss += __shfl_xor(ss, o);
  __shared__ float red[4];
  if ((tid & 63) == 0) red[tid >> 6] = ss;
  __syncthreads();
  const float sc = rsqrtf((red[0] + red[1] + red[2] + red[3]) * (1.0f / DIM) + EPSR) * SA;
  const float4 wv = ((const float4*)wgt)[tid];
  float a[4] = {v.x * sc * wv.x, v.y * sc * wv.y, v.z * sc * wv.z, v.w * sc * wv.w};
  half4 hv, lv;
#pragma unroll
  for (int j = 0; j < 4; ++j) {
    _Float16 hh = (_Float16)a[j]; hv[j] = hh; lv[j] = (_Float16)(a[j] - (float)hh);
  }
  ((half4*)(oh + (size_t)row * DIM))[tid] = hv;
  ((half4*)(ol + (size_t)row * DIM))[tid] = lv;
}

// fused RMSNorm(bf16 out) + gate logits/softmax/top-2
__global__ __launch_bounds__(256) void rmsgate_k(const float* __restrict__ x2,
                                                 const float* __restrict__ n2w,
                                                 const float* __restrict__ gw,
                                                 unsigned short* __restrict__ xfb,
                                                 float* __restrict__ wts) {
  const int row = blockIdx.x, tid = threadIdx.x;
  const float4 v = ((const float4*)(x2 + (size_t)row * DIM))[tid];
  float ss = v.x * v.x + v.y * v.y + v.z * v.z + v.w * v.w;
#pragma unroll
  for (int o = 32; o; o >>= 1) ss += __shfl_xor(ss, o);
  __shared__ float red[4];
  __shared__ float redE[4][4];
  const int w = tid >> 6, lane = tid & 63;
  if (lane == 0) red[w] = ss;
  __syncthreads();
  const float sc = rsqrtf((red[0] + red[1] + red[2] + red[3]) * (1.0f / DIM) + EPSR);
  const float4 nw = ((const float4*)n2w)[tid];
  const float xn0 = v.x * sc * nw.x, xn1 = v.y * sc * nw.y;
  const float xn2 = v.z * sc * nw.z, xn3 = v.w * sc * nw.w;
  us4 ob; ob[0] = f2bf(xn0); ob[1] = f2bf(xn1); ob[2] = f2bf(xn2); ob[3] = f2bf(xn3);
  ((us4*)(xfb + (size_t)row * DIM))[tid] = ob;
#pragma unroll
  for (int e = 0; e < 4; ++e) {
    const float4 g = ((const float4*)(gw + (size_t)e * DIM))[tid];
    float d = xn0 * g.x + xn1 * g.y + xn2 * g.z + xn3 * g.w;
#pragma unroll
    for (int o = 32; o; o >>= 1) d += __shfl_xor(d, o);
    if (lane == 0) redE[w][e] = d;
  }
  __syncthreads();
  if (tid == 0) {
    float lg[4];
#pragma unroll
    for (int e = 0; e < 4; ++e) lg[e] = redE[0][e] + redE[1][e] + redE[2][e] + redE[3][e];
    const float mx = fmaxf(fmaxf(lg[0], lg[1]), fmaxf(lg[2], lg[3]));
    float pe[4]; float sum = 0.0f;
#pragma unroll
    for (int e = 0; e < 4; ++e) { pe[e] = __expf(lg[e] - mx); sum += pe[e]; }
#pragma unroll
    for (int e = 0; e < 4; ++e) pe[e] /= sum;
    int i1 = 0;
    for (int e = 1; e < 4; ++e) if (pe[e] > pe[i1]) i1 = e;
    int i2 = -1;
    for (int e = 0; e < 4; ++e) { if (e == i1) continue; if (i2 < 0 || pe[e] > pe[i2]) i2 = e; }
    const float s2 = pe[i1] + pe[i2] + 1e-8f;
    float o[4] = {0.f, 0.f, 0.f, 0.f};
    o[i1] = pe[i1] / s2; o[i2] = pe[i2] / s2;
    float4 r; r.x = o[0]; r.y = o[1]; r.z = o[2]; r.w = o[3];
    *(float4*)(wts + (size_t)row * 4) = r;
  }
}

// ---------------- routing + dense per-XCD work lists ----------------
struct MoeCfg { int nbn[4][4]; int ks[4][4]; };

__global__ __launch_bounds__(256) void route2_k(const float* __restrict__ wts,
                                                int* __restrict__ idxP,
                                                int* __restrict__ meta,
                                                int* __restrict__ work,
                                                MoeCfg cfg) {
  const int tid = threadIdx.x, w = tid >> 6, lane = tid & 63;
  __shared__ int wsum[4];
  __shared__ int baseS;
  int off = 0;
  for (int e = 0; e < 4; ++e) {
    if (tid == 0) baseS = 0;
    __syncthreads();
    for (int c = 0; c < 16; ++c) {
      const int tok = (c << 8) + tid;
      const bool pred = wts[(size_t)tok * 4 + e] > 0.0f;
      const unsigned long long m = __ballot(pred);
      const int lanepre = __popcll(m & ((1ull << lane) - 1ull));
      if (lane == 0) wsum[w] = __popcll(m);
      __syncthreads();
      int wpre = 0;
#pragma unroll
      for (int i = 0; i < 4; ++i) wpre += (i < w) ? wsum[i] : 0;
      const int tot = wsum[0] + wsum[1] + wsum[2] + wsum[3];
      if (pred) idxP[off + baseS + wpre + lanepre] = tok;
      __syncthreads();
      if (tid == 0) baseS += tot;
      __syncthreads();
    }
    const int cnt = baseS;
    const int padded = (cnt + 127) & ~127;
    for (int j = cnt + tid; j < padded; j += 256) idxP[off + j] = -1;
    if (tid == 0) meta[80 + e] = off;
    const int mb0 = off >> 7, nmb = padded >> 7;
    for (int j = tid; j < nmb; j += 256) meta[mb0 + j] = e;
    off += padded;
    __syncthreads();
  }
  for (int j = (off >> 7) + tid; j < 72; j += 256) meta[j] = -1;
  for (int j = tid; j < 4 * 8 * MAXI; j += 256) work[j] = -1;
  __syncthreads();
  if (tid < 32) {
    const int p = tid >> 3, x = tid & 7;
    int* wb = work + p * (8 * MAXI);
    int n = 0;
    const int totmb = off >> 7;
    for (int mb = x; mb < totmb; mb += 8) {
      const int e = meta[mb];
      const int nbn = cfg.nbn[p][e];
      const int ks = cfg.ks[p][e];
      for (int nb = 0; nb < nbn; ++nb)
        for (int k = 0; k < ks; ++k) {
          wb[n * 8 + x] = mb | (nb << 8) | (k << 16);
          ++n;
        }
    }
  }
}

// ---------------- packed grouped sparse bf16 GEMM (single-buffer LDS, work-list) ----------------
struct SubOpP {
  const unsigned short* A;
  const unsigned short* Bw;
  unsigned short* outb;
  const unsigned short* other;
  int K, nbn, act, ep, gath, ks;  // ep: 0 store, 1 silu*other, 2 scatter atomicAdd->outp (masked)
};
struct PhaseP { SubOpP op[4]; };  // indexed by expert

__global__ __launch_bounds__(256, 4) void gemm_moe_k(PhaseP ph,
                                                     const int* __restrict__ meta,
                                                     const int* __restrict__ idxP,
                                                     const float* __restrict__ wts,
                                                     float* __restrict__ outp,
                                                     const int* __restrict__ wk) {
  __shared__ unsigned short As[128][64];
  __shared__ unsigned short Bs[128][64];
  const int item = wk[blockIdx.y * 8 + blockIdx.x];
  if (item < 0) return;
  const int mb = item & 255;
  const int nb = (item >> 8) & 255;
  const int kpart = (item >> 16) & 3;
  const int e = meta[mb];
  SubOpP op;
  switch (e) {
    case 0: op = ph.op[0]; break;
    case 1: op = ph.op[1]; break;
    case 2: op = ph.op[2]; break;
    default: op = ph.op[3]; break;
  }
  const int m0p = mb << 7;
  const int lr0 = m0p - meta[80 + e];
  const int n0 = nb << 7;
  const int F = op.nbn << 7;
  const int K = op.K;
  const int tid = threadIdx.x;
  const int w = tid >> 6, lane = tid & 63;
  const int wr = ((w >> 1) << 6), wc = ((w & 1) << 6);
  const int rr = lane & 15, kgl = lane >> 4;
  const int srow = tid >> 3, sslot = tid & 7;

  int grow[4];
#pragma unroll
  for (int i = 0; i < 4; ++i) {
    const int r = (i << 5) + srow;
    if (op.gath) {
      const int t = idxP[m0p + r];
      grow[i] = (t < 0) ? 0 : t;
    } else {
      grow[i] = lr0 + r;
    }
  }

  f32x4 acc[4][4];
#pragma unroll
  for (int a_ = 0; a_ < 4; ++a_)
#pragma unroll
    for (int b_ = 0; b_ < 4; ++b_) acc[a_][b_] = (f32x4){0.f, 0.f, 0.f, 0.f};

  int kt0 = 0, ktN = K >> 6;
  if (op.ks == 2) { const int hgt = ktN >> 1; kt0 = kpart * hgt; ktN = kt0 + hgt; }
  for (int kt = kt0; kt < ktN; ++kt) {
    const int k0 = kt << 6;
#pragma unroll
    for (int i = 0; i < 4; ++i) {
      const int r = (i << 5) + srow;
      const int ls = sslot ^ (r & 7);
      gload16(&As[(i << 5) + (w << 3)][0], op.A + (size_t)grow[i] * K + k0 + (ls << 3));
      gload16(&Bs[(i << 5) + (w << 3)][0], op.Bw + (size_t)(n0 + r) * K + k0 + (ls << 3));
    }
    __syncthreads();
    short8 af[4][2], bfr[4][2];
#pragma unroll
    for (int f = 0; f < 4; ++f) {
#pragma unroll
      for (int ks = 0; ks < 2; ++ks) {
        const int row = wr + (f << 4) + rr;
        const int kg = (ks << 2) + kgl;
        af[f][ks] = *(const short8*)&As[row][(kg ^ (row & 7)) << 3];
        const int col = wc + (f << 4) + rr;
        bfr[f][ks] = *(const short8*)&Bs[col][(kg ^ (col & 7)) << 3];
      }
    }
#pragma unroll
    for (int fi = 0; fi < 4; ++fi)
#pragma unroll
      for (int fj = 0; fj < 4; ++fj)
#pragma unroll
        for (int ks = 0; ks < 2; ++ks)
          acc[fi][fj] = __builtin_amdgcn_mfma_f32_16x16x32_bf16(
              af[fi][ks], bfr[fj][ks], acc[fi][fj], 0, 0, 0);
    __syncthreads();
  }
#pragma unroll
  for (int fi = 0; fi < 4; ++fi)
#pragma unroll
    for (int fj = 0; fj < 4; ++fj) {
      const int col = n0 + wc + (fj << 4) + rr;
#pragma unroll
      for (int r = 0; r < 4; ++r) {
        const int rl = wr + (fi << 4) + (kgl << 2) + r;
        float v = acc[fi][fj][r];
        if (op.act) v = 0.5f * v * (1.0f + erff(v * 0.70710678118654752f));
        if (op.ep == 0) {
          op.outb[(size_t)(lr0 + rl) * F + col] = f2bf(v);
        } else if (op.ep == 1) {
          const size_t off = (size_t)(lr0 + rl) * F + col;
          const float sv = v / (1.0f + __expf(-v));
          op.outb[off] = f2bf(sv * bf2f(op.other[off]));
        } else {
          const int tok = idxP[m0p + rl];
          if (tok >= 0 && col >= MPROT)
            atomicAdd(&outp[(size_t)tok * DIM + col], wts[(size_t)tok * 4 + e] * v);
        }
      }
    }
}

// ---------------- fp16x2 split GEMM (3-term), single-buffer LDS ----------------
// EP: 1 = fp32: resid + masked(v); 3 = fused QKV epilogue with fused qk-norm
template <int EP>
__global__ __launch_bounds__(256, 4) void gemm_split_k(
    const _Float16* __restrict__ Ah, const _Float16* __restrict__ Al,
    const _Float16* __restrict__ Bh, const _Float16* __restrict__ Bl,
    int K, int F,
    _Float16* __restrict__ Oh, _Float16* __restrict__ Ol, float oscale,
    const float* __restrict__ resid, float* __restrict__ outf,
    _Float16* __restrict__ K2h, _Float16* __restrict__ K2l,
    _Float16* __restrict__ V2h, _Float16* __restrict__ V2l,
    const float* __restrict__ qnw, const float* __restrict__ knw) {
  __shared__ _Float16 AsH[128][32], AsL[128][32];
  __shared__ _Float16 BsH[128][32], BsL[128][32];
  const int tid = threadIdx.x;
  const int w = tid >> 6, lane = tid & 63;
  const int wr = ((w >> 1) << 6), wc = ((w & 1) << 6);
  int m0, n0;
  tile_swz(m0, n0);
  const int rr = lane & 15, kgl = lane >> 4;
  const int srow = tid >> 2, sslot = tid & 3;

  f32x4 acc[4][4];
#pragma unroll
  for (int a_ = 0; a_ < 4; ++a_)
#pragma unroll
    for (int b_ = 0; b_ < 4; ++b_) acc[a_][b_] = (f32x4){0.f, 0.f, 0.f, 0.f};

  const int KT = K >> 5;
  for (int kt = 0; kt < KT; ++kt) {
    const int k0 = kt << 5;
#pragma unroll
    for (int i = 0; i < 2; ++i) {
      const int r = (i << 6) + srow;
      const int ls = sslot ^ ((r >> 1) & 3);
      const size_t ga = (size_t)(m0 + r) * K + k0 + (ls << 3);
      const size_t gb = (size_t)(n0 + r) * K + k0 + (ls << 3);
      const int lr = (i << 6) + (w << 4);
      gload16(&AsH[lr][0], Ah + ga);
      gload16(&AsL[lr][0], Al + ga);
      gload16(&BsH[lr][0], Bh + gb);
      gload16(&BsL[lr][0], Bl + gb);
    }
    __syncthreads();
    half8 ah[4], al[4], bh[4], bl[4];
#pragma unroll
    for (int f = 0; f < 4; ++f) {
      const int row = wr + (f << 4) + rr;
      const int pa = (kgl ^ ((row >> 1) & 3)) << 3;
      ah[f] = *(const half8*)&AsH[row][pa];
      al[f] = *(const half8*)&AsL[row][pa];
      const int col = wc + (f << 4) + rr;
      const int pb = (kgl ^ ((col >> 1) & 3)) << 3;
      bh[f] = *(const half8*)&BsH[col][pb];
      bl[f] = *(const half8*)&BsL[col][pb];
    }
#pragma unroll
    for (int fi = 0; fi < 4; ++fi)
#pragma unroll
      for (int fj = 0; fj < 4; ++fj) {
        acc[fi][fj] = __builtin_amdgcn_mfma_f32_16x16x32_f16(ah[fi], bh[fj], acc[fi][fj], 0, 0, 0);
        acc[fi][fj] = __builtin_amdgcn_mfma_f32_16x16x32_f16(ah[fi], bl[fj], acc[fi][fj], 0, 0, 0);
        acc[fi][fj] = __builtin_amdgcn_mfma_f32_16x16x32_f16(al[fi], bh[fj], acc[fi][fj], 0, 0, 0);
      }
    __syncthreads();
  }

  if (EP == 3 && n0 < 2048) {
    // q (n0<1024) or k tile: fuse per-(row,head) RMS norm over the 64 head dims.
    const bool isq = (n0 < 1024);
    _Float16* ph = isq ? Oh : K2h;
    _Float16* pl = isq ? Ol : K2l;
    const float* wvec = isq ? qnw : knw;
    float wreg[4];
#pragma unroll
    for (int fj = 0; fj < 4; ++fj) wreg[fj] = wvec[(fj << 4) + rr];
#pragma unroll
    for (int fi = 0; fi < 4; ++fi) {
#pragma unroll
      for (int r = 0; r < 4; ++r) {
        float vv[4]; float ss = 0.f;
#pragma unroll
        for (int fj = 0; fj < 4; ++fj) {
          vv[fj] = acc[fi][fj][r] * oscale;
          ss += vv[fj] * vv[fj];
        }
        ss += __shfl_xor(ss, 1);
        ss += __shfl_xor(ss, 2);
        ss += __shfl_xor(ss, 4);
        ss += __shfl_xor(ss, 8);
        const float sc = rsqrtf(ss * (1.0f / (64.0f * SA * SA)) + EPSR);
        const int row = m0 + wr + (fi << 4) + (kgl << 2) + r;
#pragma unroll
        for (int fj = 0; fj < 4; ++fj) {
          const int c = (n0 + wc + (fj << 4) + rr) & 1023;
          const float nv = vv[fj] * sc * wreg[fj];
          const _Float16 hh2 = (_Float16)nv;
          const size_t off = (size_t)row * DIM + c;
          ph[off] = hh2; pl[off] = (_Float16)(nv - (float)hh2);
        }
      }
    }
    return;
  }

#pragma unroll
  for (int fi = 0; fi < 4; ++fi)
#pragma unroll
    for (int fj = 0; fj < 4; ++fj) {
      const int col = n0 + wc + (fj << 4) + rr;
      const int rowb = m0 + wr + (fi << 4) + (kgl << 2);
      if (EP == 3) {
        const int c2 = col - 2048;
        half4 h4, l4;
#pragma unroll
        for (int r = 0; r < 4; ++r) {
          const float v = acc[fi][fj][r] * oscale;
          const _Float16 hh2 = (_Float16)v;
          h4[r] = hh2; l4[r] = (_Float16)(v - (float)hh2);
        }
        const size_t vt = ((size_t)((rowb >> 10) << 4) + (size_t)(c2 >> 6)) * 65536 +
                          (size_t)(c2 & 63) * 1024 + (size_t)(rowb & 1023);
        *(half4*)&V2h[vt] = h4;
        *(half4*)&V2l[vt] = l4;
      } else {
#pragma unroll
        for (int r = 0; r < 4; ++r) {
          const size_t off = (size_t)(rowb + r) * F + col;
          const float v = acc[fi][fj][r] * oscale;
          outf[off] = resid[off] + (col >= MPROT ? v : 0.0f);
        }
      }
    }
}

// ---------------- flash attention, causal, fp16x2 split, swapped-QK ----------------
// load-balanced qt pairing: blocks 2j/2j+1 get qt = pt / 7-pt (uniform 36 tiles per pair)
__global__ __launch_bounds__(256, 2) void attn_k(
    const _Float16* __restrict__ Qh, const _Float16* __restrict__ Ql,
    const _Float16* __restrict__ Kh, const _Float16* __restrict__ Kl,
    const _Float16* __restrict__ Vth, const _Float16* __restrict__ Vtl,
    _Float16* __restrict__ Oh, _Float16* __restrict__ Ol) {
  __shared__ _Float16 Ksh[2][32][64], Ksl[2][32][64];
  __shared__ _Float16 Vsh[2][64][40], Vsl[2][64][40];
  __shared__ _Float16 Plh[4][16][40], Pll[4][16][40];
  const int n = blockIdx.x;
  const int j = n >> 1, s = n & 1;
  const int pt = j >> 6;
  const int qt = s ? (7 - pt) : pt;
  const int bh = j & 63;
  const int b = bh >> 4, h = bh & 15;
  const int tid = threadIdx.x, w = tid >> 6, lane = tid & 63;
  const int rr = lane & 15, rg = lane >> 4;
  const size_t tokbase = (size_t)b * TSEQ;
  const int hcol = h << 6;
  const size_t vtbase = (size_t)bh << 16;
  const int q0w = (qt << 7) + (w << 5);
  const float sscale = 0.125f / (SA * SA);

  half8 qfh[2][2], qfl[2][2];
#pragma unroll
  for (int qf = 0; qf < 2; ++qf)
#pragma unroll
    for (int ks = 0; ks < 2; ++ks) {
      const size_t off = (tokbase + q0w + (qf << 4) + rr) * DIM + hcol + (ks << 5) + (rg << 3);
      qfh[qf][ks] = *(const half8*)&Qh[off];
      qfl[qf][ks] = *(const half8*)&Ql[off];
    }

  f32x4 oacc[2][4];
#pragma unroll
  for (int qf = 0; qf < 2; ++qf)
#pragma unroll
    for (int dg = 0; dg < 4; ++dg) oacc[qf][dg] = (f32x4){0.f, 0.f, 0.f, 0.f};
  float mreg[2] = {-INFINITY, -INFINITY}, lreg[2] = {0.f, 0.f};

  const int kr = (w << 3) + (lane >> 3);
  const int kswz = ((lane & 7) ^ (kr & 7)) << 3;
  const int vr = tid >> 2;
  const int vs = (tid & 3) << 3;

  const int ntiles = (qt + 1) << 2;

  {
    gload16(&Ksh[0][w << 3][0], &Kh[(tokbase + kr) * DIM + hcol + kswz]);
    gload16(&Ksl[0][w << 3][0], &Kl[(tokbase + kr) * DIM + hcol + kswz]);
    const half8 vvh = *(const half8*)&Vth[vtbase + (size_t)vr * TSEQ + vs];
    const half8 vvl = *(const half8*)&Vtl[vtbase + (size_t)vr * TSEQ + vs];
    *(half8*)&Vsh[0][vr][vs] = vvh;
    *(half8*)&Vsl[0][vr][vs] = vvl;
    __syncthreads();
  }

  for (int t = 0; t < ntiles; ++t) {
    const int cur = t & 1;
    const int kv0 = t << 5;
    const bool havenext = (t + 1 < ntiles);
    half8 nvh, nvl;
    if (havenext) {
      const int kn = kv0 + 32;
      gload16(&Ksh[cur ^ 1][w << 3][0], &Kh[(tokbase + kn + kr) * DIM + hcol + kswz]);
      gload16(&Ksl[cur ^ 1][w << 3][0], &Kl[(tokbase + kn + kr) * DIM + hcol + kswz]);
      nvh = *(const half8*)&Vth[vtbase + (size_t)vr * TSEQ + kn + vs];
      nvl = *(const half8*)&Vtl[vtbase + (size_t)vr * TSEQ + kn + vs];
    }
    if (kv0 <= q0w + 31) {
      half8 kfh[2][2], kfl[2][2];
#pragma unroll
      for (int kt = 0; kt < 2; ++kt)
#pragma unroll
        for (int ks = 0; ks < 2; ++ks) {
          const int row = (kt << 4) + rr;
          const int sw = ((((ks << 2) + rg)) ^ (row & 7)) << 3;
          kfh[kt][ks] = *(const half8*)&Ksh[cur][row][sw];
          kfl[kt][ks] = *(const half8*)&Ksl[cur][row][sw];
        }
#pragma unroll
      for (int qf = 0; qf < 2; ++qf) {
        if (kv0 > q0w + (qf << 4) + 15) continue;
        f32x4 st[2];
        st[0] = (f32x4){0.f, 0.f, 0.f, 0.f};
        st[1] = (f32x4){0.f, 0.f, 0.f, 0.f};
        __builtin_amdgcn_s_setprio(1);
#pragma unroll
        for (int kt = 0; kt < 2; ++kt)
#pragma unroll
          for (int ks = 0; ks < 2; ++ks) {
            st[kt] = __builtin_amdgcn_mfma_f32_16x16x32_f16(kfh[kt][ks], qfh[qf][ks], st[kt], 0, 0, 0);
            st[kt] = __builtin_amdgcn_mfma_f32_16x16x32_f16(kfh[kt][ks], qfl[qf][ks], st[kt], 0, 0, 0);
            st[kt] = __builtin_amdgcn_mfma_f32_16x16x32_f16(kfl[kt][ks], qfh[qf][ks], st[kt], 0, 0, 0);
          }
        __builtin_amdgcn_s_setprio(0);
        const int qg = q0w + (qf << 4) + rr;
        float s2[2][4]; float mx = -INFINITY;
#pragma unroll
        for (int kt = 0; kt < 2; ++kt)
#pragma unroll
          for (int r = 0; r < 4; ++r) {
            float sv = st[kt][r] * sscale;
            if (kv0 + (kt << 4) + (rg << 2) + r > qg) sv = -INFINITY;
            s2[kt][r] = sv; mx = fmaxf(mx, sv);
          }
        mx = fmaxf(mx, __shfl_xor(mx, 16));
        mx = fmaxf(mx, __shfl_xor(mx, 32));
        const float mn = fmaxf(mreg[qf], mx);
        const float al = __expf(mreg[qf] - mn);
        mreg[qf] = mn;
        float p[2][4]; float rs = 0.f;
#pragma unroll
        for (int kt = 0; kt < 2; ++kt)
#pragma unroll
          for (int r = 0; r < 4; ++r) { p[kt][r] = __expf(s2[kt][r] - mn); rs += p[kt][r]; }
        rs += __shfl_xor(rs, 16);
        rs += __shfl_xor(rs, 32);
        lreg[qf] = lreg[qf] * al + rs;
#pragma unroll
        for (int kt = 0; kt < 2; ++kt) {
          half4 h4, l4;
#pragma unroll
          for (int r = 0; r < 4; ++r) {
            const float pv = p[kt][r] * SPC;
            const _Float16 ph = (_Float16)pv;
            h4[r] = ph; l4[r] = (_Float16)(pv - (float)ph);
          }
          *(half4*)&Plh[w][rr][(kt << 4) + (rg << 2)] = h4;
          *(half4*)&Pll[w][rr][(kt << 4) + (rg << 2)] = l4;
        }
        float alr[4];
#pragma unroll
        for (int r = 0; r < 4; ++r) alr[r] = __shfl(al, (lane & 48) | ((rg << 2) + r));
#pragma unroll
        for (int dg = 0; dg < 4; ++dg)
#pragma unroll
          for (int r = 0; r < 4; ++r) oacc[qf][dg][r] *= alr[r];
        const half8 pah = *(const half8*)&Plh[w][rr][rg << 3];
        const half8 pal = *(const half8*)&Pll[w][rr][rg << 3];
        __builtin_amdgcn_s_setprio(1);
#pragma unroll
        for (int dg = 0; dg < 4; ++dg) {
          const half8 vfh2 = *(const half8*)&Vsh[cur][(dg << 4) + rr][rg << 3];
          const half8 vfl2 = *(const half8*)&Vsl[cur][(dg << 4) + rr][rg << 3];
          oacc[qf][dg] = __builtin_amdgcn_mfma_f32_16x16x32_f16(pah, vfh2, oacc[qf][dg], 0, 0, 0);
          oacc[qf][dg] = __builtin_amdgcn_mfma_f32_16x16x32_f16(pah, vfl2, oacc[qf][dg], 0, 0, 0);
          oacc[qf][dg] = __builtin_amdgcn_mfma_f32_16x16x32_f16(pal, vfh2, oacc[qf][dg], 0, 0, 0);
        }
        __builtin_amdgcn_s_setprio(0);
      }
    }
    if (havenext) {
      *(half8*)&Vsh[cur ^ 1][vr][vs] = nvh;
      *(half8*)&Vsl[cur ^ 1][vr][vs] = nvl;
    }
    __syncthreads();
  }
#pragma unroll
  for (int qf = 0; qf < 2; ++qf) {
    float li[4];
#pragma unroll
    for (int r = 0; r < 4; ++r)
      li[r] = __shfl(lreg[qf], (lane & 48) | ((rg << 2) + r));
#pragma unroll
    for (int dg = 0; dg < 4; ++dg)
#pragma unroll
      for (int r = 0; r < 4; ++r) {
        const int qloc = (rg << 2) + r;
        const float ov = oacc[qf][dg][r] / (li[r] * SPC);
        const _Float16 hh2 = (_Float16)ov;
        const size_t off = (tokbase + q0w + (qf << 4) + qloc) * DIM + hcol + (dg << 4) + rr;
        Oh[off] = hh2;
        Ol[off] = (_Float16)(ov - (float)hh2);
      }
  }
}

extern "C" void kernel_launch(void* const* d_in, const int* in_sizes, int n_in,
                              void* d_out, int out_size, void* d_ws, size_t ws_size,
                              hipStream_t stream) {
  (void)in_sizes; (void)n_in; (void)out_size; (void)ws_size;
  const float* x    = (const float*)d_in[0];
  const float* n1w  = (const float*)d_in[1];
  const float* n2w  = (const float*)d_in[2];
  const float* wq   = (const float*)d_in[3];
  const float* wk   = (const float*)d_in[4];
  const float* wv   = (const float*)d_in[5];
  const float* wo   = (const float*)d_in[6];
  const float* qnw  = (const float*)d_in[7];
  const float* knw  = (const float*)d_in[8];
  const float* gw   = (const float*)d_in[9];
  const float* moesrc[12] = {
    (const float*)d_in[10], (const float*)d_in[11],
    (const float*)d_in[12], (const float*)d_in[13], (const float*)d_in[14],
    (const float*)d_in[15], (const float*)d_in[16], (const float*)d_in[17], (const float*)d_in[18],
    (const float*)d_in[19], (const float*)d_in[20], (const float*)d_in[21]
  };
  float* outp = (float*)d_out;

  char* p = (char*)d_ws;
  auto alloc = [&](size_t bytes) { void* r = (void*)p; p += (bytes + 255) & ~(size_t)255; return r; };
  const size_t NC = (size_t)NTOK * DIM;
  _Float16* hh = (_Float16*)alloc(NC * 2);
  _Float16* hl = (_Float16*)alloc(NC * 2);
  _Float16* qh = (_Float16*)alloc(NC * 2);   // qh..vtl reused as MoE arena
  _Float16* ql = (_Float16*)alloc(NC * 2);
  _Float16* kh = (_Float16*)alloc(NC * 2);
  _Float16* kl = (_Float16*)alloc(NC * 2);
  _Float16* vth = (_Float16*)alloc(NC * 2);
  _Float16* vtl = (_Float16*)alloc(NC * 2);
  unsigned short* xfb = (unsigned short*)alloc(NC * 2);
  float* wts = (float*)alloc((size_t)NTOK * 4 * 4);
  _Float16* awh = (_Float16*)alloc((size_t)4 * 1024 * 1024 * 2);
  _Float16* awl = (_Float16*)alloc((size_t)4 * 1024 * 1024 * 2);
  unsigned short* moeW = (unsigned short*)alloc((size_t)28311552 * 2);
  int* idxP = (int*)alloc((size_t)9216 * 4);
  int* meta = (int*)alloc(512);
  int* work = (int*)alloc((size_t)4 * 8 * MAXI * 4);
  unsigned short* e0t = (unsigned short*)qh;    // 16 MB (qh+ql)
  unsigned short* e1a = (unsigned short*)kh;    // 16 MB (kh+kl)
  unsigned short* e2a = (unsigned short*)vth;   // 16 MB (vth+vtl), reused as e2c
  unsigned short* e1b = (unsigned short*)alloc((size_t)NTOK * 2048 * 2);
  unsigned short* e2b = (unsigned short*)alloc((size_t)NTOK * 2048 * 2);
  unsigned short* e3a = (unsigned short*)alloc((size_t)NTOK * 1024 * 2);
  unsigned short* e3b = (unsigned short*)alloc((size_t)NTOK * 2048 * 2);
  unsigned short* e2c = e2a;

  const size_t moff[12] = {0, 2097152, 4194304, 6291456, 8388608, 10485760,
                           12582912, 16777216, 20971520, 23068672, 24117248, 26214400};
  auto mw = [&](int i) -> const unsigned short* { return moeW + moff[i]; };

  // ---- weight conversions ----
  cvt_attn4_k<<<dim3(1024, 4), dim3(256), 0, stream>>>(wq, wk, wv, wo, awh, awl);
  cvt_moe_all_k<<<dim3(4096, 12), dim3(256), 0, stream>>>(
      moesrc[0], moesrc[1], moesrc[2], moesrc[3], moesrc[4], moesrc[5],
      moesrc[6], moesrc[7], moesrc[8], moesrc[9], moesrc[10], moesrc[11], moeW);
  const _Float16* woh = awh + (3 << 20); const _Float16* wol = awl + (3 << 20);

  // ---- attention path (fp16x2) ----
  rms_split_k<<<dim3(NTOK), dim3(256), 0, stream>>>(x, n1w, hh, hl);
  gemm_split_k<3><<<dim3(24, 32), dim3(256), 0, stream>>>(
      hh, hl, awh, awl, 1024, 3072, qh, ql, 1.0f / SW, nullptr, nullptr,
      kh, kl, vth, vtl, qnw, knw);
  attn_k<<<dim3(512), dim3(256), 0, stream>>>(qh, ql, kh, kl, vth, vtl, hh, hl);
  gemm_split_k<1><<<dim3(8, 32), dim3(256), 0, stream>>>(
      hh, hl, woh, wol, 1024, 1024, nullptr, nullptr, 1.0f / (SA * SW), x, outp,
      nullptr, nullptr, nullptr, nullptr, nullptr, nullptr);

  // ---- MoE (sparse top-2, dense work-list phases, scatter into outp) ----
  rmsgate_k<<<dim3(NTOK), dim3(256), 0, stream>>>(outp, n2w, gw, xfb, wts);

  MoeCfg cfg;
  const int nbn_tab[4][4] = {{16, 16, 16, 8},
                             {8, 16, 16, 16},
                             {0, 8, 16, 0},
                             {0, 0, 8, 8}};
  const int ks_tab[4][4]  = {{1, 1, 1, 1},
                             {2, 1, 1, 1},
                             {1, 2, 1, 1},
                             {1, 1, 2, 2}};
  for (int pp = 0; pp < 4; ++pp)
    for (int ee = 0; ee < 4; ++ee) { cfg.nbn[pp][ee] = nbn_tab[pp][ee]; cfg.ks[pp][ee] = ks_tab[pp][ee]; }

  route2_k<<<dim3(1), dim3(256), 0, stream>>>(wts, idxP, meta, work, cfg);

  auto mk = [&](const unsigned short* A, const unsigned short* B, unsigned short* outb,
                const unsigned short* other, int K, int nbn, int act, int ep, int gath, int ks) {
    SubOpP s; s.A = A; s.Bw = B; s.outb = outb; s.other = other;
    s.K = K; s.nbn = nbn; s.act = act; s.ep = ep; s.gath = gath; s.ks = ks;
    return s;
  };
  const SubOpP none = mk(nullptr, nullptr, nullptr, nullptr, 1024, 0, 0, 0, 0, 1);

  PhaseP p1;
  p1.op[0] = mk(xfb, mw(0), e0t, nullptr, 1024, 16, 1, 0, 1, 1);  // e0: gelu(x@up)
  p1.op[1] = mk(xfb, mw(3), e1a, nullptr, 1024, 16, 0, 0, 1, 1);  // e1: x@w2 raw
  p1.op[2] = mk(xfb, mw(5), e2a, nullptr, 1024, 16, 1, 0, 1, 1);  // e2: gelu(x@l1)
  p1.op[3] = mk(xfb, mw(9), e3a, nullptr, 1024, 8, 1, 0, 1, 1);   // e3: gelu(x@dn)
  gemm_moe_k<<<dim3(8, MAXI), dim3(256), 0, stream>>>(p1, meta, idxP, wts, outp, work);

  PhaseP p2;
  p2.op[0] = mk(e0t, mw(1), nullptr, nullptr, 2048, 8, 0, 2, 0, 2);  // e0 down -> outp
  p2.op[1] = mk(xfb, mw(2), e1b, e1a, 1024, 16, 0, 1, 1, 1);         // e1: silu(x@w1)*e1a
  p2.op[2] = mk(e2a, mw(6), e2b, nullptr, 2048, 16, 1, 0, 0, 1);     // e2: gelu(@l2)
  p2.op[3] = mk(e3a, mw(10), e3b, nullptr, 1024, 16, 1, 0, 0, 1);    // e3: gelu(@up)
  gemm_moe_k<<<dim3(8, MAXI), dim3(256), 0, stream>>>(p2, meta, idxP, wts, outp, work + 8 * MAXI);

  PhaseP p3;
  p3.op[0] = none;
  p3.op[1] = mk(e1b, mw(4), nullptr, nullptr, 2048, 8, 0, 2, 0, 2);  // e1 down -> outp
  p3.op[2] = mk(e2b, mw(7), e2c, nullptr, 2048, 16, 1, 0, 0, 1);     // e2: gelu(@l3)
  p3.op[3] = none;
  gemm_moe_k<<<dim3(8, MAXI), dim3(256), 0, stream>>>(p3, meta, idxP, wts, outp, work + 16 * MAXI);

  PhaseP p4;
  p4.op[0] = none;
  p4.op[1] = none;
  p4.op[2] = mk(e2c, mw(8), nullptr, nullptr, 2048, 8, 0, 2, 0, 2);  // e2 l4 -> outp
  p4.op[3] = mk(e3b, mw(11), nullptr, nullptr, 2048, 8, 0, 2, 0, 2); // e3 out -> outp
  gemm_moe_k<<<dim3(8, MAXI), dim3(256), 0, stream>>>(p4, meta, idxP, wts, outp, work + 24 * MAXI);
}